// Round 1
// baseline (2418.035 us; speedup 1.0000x reference)
//
#include <hip/hip_runtime.h>

typedef unsigned short u16;
typedef unsigned int u32;
typedef float f32x4 __attribute__((ext_vector_type(4)));
typedef __bf16 bf16x8 __attribute__((ext_vector_type(8)));

#define DEV __device__ __forceinline__

DEV u16 f2bf(float f) {
  u32 u = __builtin_bit_cast(u32, f);
  u += 0x7fffu + ((u >> 16) & 1u);
  return (u16)(u >> 16);
}
DEV float bf2f(u16 u) { return __builtin_bit_cast(float, (u32)u << 16); }
DEV float waveAllSum(float x) {
#pragma unroll
  for (int off = 32; off > 0; off >>= 1) x += __shfl_xor(x, off, 64);
  return x;
}
DEV float silu_f(float x) { return x / (1.f + __expf(-x)); }

// ---------------------------------------------------------------------------
// Generic NT GEMM: C[m,n] = sum_k A_bf16[m,k] * W_f32[n,k]
// M fixed = 2048 (grid.x=16). 128x128 tile, BK=64, 4 waves (2x2 of 64x64).
// W converted f32->bf16 during LDS staging. n-guard (n<N), k-guard on W (k<Kw).
// ---------------------------------------------------------------------------
__global__ __launch_bounds__(256) void gemm_kernel(
    const u16* __restrict__ A, int lda,
    const float* __restrict__ W, int ldw,
    float* __restrict__ C, int ldc,
    int N, int Ksteps, int Kw)
{
  __shared__ alignas(16) u16 As[128][72];
  __shared__ alignas(16) u16 Ws[128][72];
  const int tid = threadIdx.x;
  const int lane = tid & 63;
  const int wave = tid >> 6;
  const int wm = (wave >> 1) * 64;
  const int wn = (wave & 1) * 64;
  const int m0 = blockIdx.x * 128;
  const int n0 = blockIdx.y * 128;
  const int srow = tid >> 1;
  const int sseg = (tid & 1) * 32;
  const int rl = lane & 15;
  const int kq = (lane >> 4) * 8;

  f32x4 acc[4][4];
#pragma unroll
  for (int i = 0; i < 4; ++i)
#pragma unroll
    for (int j = 0; j < 4; ++j) acc[i][j] = (f32x4){0.f, 0.f, 0.f, 0.f};

  for (int kt = 0; kt < Ksteps; ++kt) {
    const int k0 = kt * 64;
    __syncthreads();
    // stage A (bf16, always fully valid: M=2048, lda>=K)
    {
      const u16* src = A + (size_t)(m0 + srow) * lda + k0 + sseg;
      uint4 v0 = *(const uint4*)(src + 0);
      uint4 v1 = *(const uint4*)(src + 8);
      uint4 v2 = *(const uint4*)(src + 16);
      uint4 v3 = *(const uint4*)(src + 24);
      *(uint4*)&As[srow][sseg + 0]  = v0;
      *(uint4*)&As[srow][sseg + 8]  = v1;
      *(uint4*)&As[srow][sseg + 16] = v2;
      *(uint4*)&As[srow][sseg + 24] = v3;
    }
    // stage W (f32 -> bf16)
    {
      const int n = n0 + srow;
      const int kbase = k0 + sseg;
      const float* src = W + (size_t)n * ldw + kbase;
      if (n < N && kbase + 32 <= Kw) {
#pragma unroll
        for (int g = 0; g < 4; ++g) {
          float4 a = *(const float4*)(src + g * 8);
          float4 b = *(const float4*)(src + g * 8 + 4);
          union { u16 u[8]; uint4 v; } p;
          p.u[0] = f2bf(a.x); p.u[1] = f2bf(a.y); p.u[2] = f2bf(a.z); p.u[3] = f2bf(a.w);
          p.u[4] = f2bf(b.x); p.u[5] = f2bf(b.y); p.u[6] = f2bf(b.z); p.u[7] = f2bf(b.w);
          *(uint4*)&Ws[srow][sseg + g * 8] = p.v;
        }
      } else {
#pragma unroll 4
        for (int g = 0; g < 32; ++g) {
          float v = (n < N && (kbase + g) < Kw) ? src[g] : 0.f;
          Ws[srow][sseg + g] = f2bf(v);
        }
      }
    }
    __syncthreads();
#pragma unroll
    for (int kk = 0; kk < 2; ++kk) {
      bf16x8 af[4], bfr[4];
#pragma unroll
      for (int i = 0; i < 4; ++i)
        af[i] = *(const bf16x8*)&As[wm + i * 16 + rl][kk * 32 + kq];
#pragma unroll
      for (int j = 0; j < 4; ++j)
        bfr[j] = *(const bf16x8*)&Ws[wn + j * 16 + rl][kk * 32 + kq];
#pragma unroll
      for (int i = 0; i < 4; ++i)
#pragma unroll
        for (int j = 0; j < 4; ++j)
          acc[i][j] = __builtin_amdgcn_mfma_f32_16x16x32_bf16(af[i], bfr[j], acc[i][j], 0, 0, 0);
    }
  }
  const int rq = (lane >> 4) * 4;
#pragma unroll
  for (int j = 0; j < 4; ++j) {
    const int n = n0 + wn + j * 16 + rl;
    if (n >= N) continue;
#pragma unroll
    for (int i = 0; i < 4; ++i) {
      const int mrow = m0 + wm + i * 16 + rq;
#pragma unroll
      for (int r = 0; r < 4; ++r)
        C[(size_t)(mrow + r) * ldc + n] = acc[i][j][r];
    }
  }
}

// ---------------------------------------------------------------------------
// Conditioning
// ---------------------------------------------------------------------------
__global__ __launch_bounds__(256) void cond_hc_kernel(
    const float* __restrict__ cfg_s, const float* __restrict__ w1,
    const float* __restrict__ b1, float* __restrict__ hc)
{
  const int b = blockIdx.x, c = threadIdx.x * 4;
  const float s = cfg_s[b];
  float4 w = *(const float4*)(w1 + c);
  float4 bb = *(const float4*)(b1 + c);
  float4 o;
  o.x = silu_f(s * w.x + bb.x);
  o.y = silu_f(s * w.y + bb.y);
  o.z = silu_f(s * w.z + bb.z);
  o.w = silu_f(s * w.w + bb.w);
  *(float4*)(hc + (size_t)b * 1024 + c) = o;
}

__global__ __launch_bounds__(64) void cond_sc_kernel(
    const float* __restrict__ hc, const float* __restrict__ w2,
    const float* __restrict__ b2, const float* __restrict__ ce,
    const int* __restrict__ y, float* __restrict__ sc)
{
  const int j = blockIdx.x, b = blockIdx.y, lane = threadIdx.x;
  const float4* wr = (const float4*)(w2 + (size_t)j * 1024);
  const float4* hr = (const float4*)(hc + (size_t)b * 1024);
  float acc = 0.f;
#pragma unroll
  for (int rep = 0; rep < 4; ++rep) {
    float4 w = wr[rep * 64 + lane];
    float4 h = hr[rep * 64 + lane];
    acc += w.x * h.x + w.y * h.y + w.z * h.z + w.w * h.w;
  }
  acc = waveAllSum(acc);
  if (lane == 0) {
    float v = ce[(size_t)y[b] * 1024 + j] + acc + b2[j];
    sc[(size_t)b * 1024 + j] = silu_f(v);
  }
}

// mods[b*ostride + j] = dot(sc[b,:], w[j,:]) + bias[j]   (grid.x = J, 1 wave)
__global__ __launch_bounds__(64) void modlin_kernel(
    const float* __restrict__ w, const float* __restrict__ bias,
    const float* __restrict__ sc, float* __restrict__ out, int ostride)
{
  const int j = blockIdx.x, lane = threadIdx.x;
  const float4* wr = (const float4*)(w + (size_t)j * 1024);
  float acc[8];
#pragma unroll
  for (int b = 0; b < 8; ++b) acc[b] = 0.f;
#pragma unroll
  for (int rep = 0; rep < 4; ++rep) {
    float4 wv = wr[rep * 64 + lane];
#pragma unroll
    for (int b = 0; b < 8; ++b) {
      float4 s = ((const float4*)(sc + (size_t)b * 1024))[rep * 64 + lane];
      acc[b] += wv.x * s.x + wv.y * s.y + wv.z * s.z + wv.w * s.w;
    }
  }
#pragma unroll
  for (int b = 0; b < 8; ++b) acc[b] = waveAllSum(acc[b]);
  if (lane == 0) {
    const float bb = bias[j];
#pragma unroll
    for (int b = 0; b < 8; ++b) out[(size_t)b * ostride + j] = acc[b] + bb;
  }
}

// ---------------------------------------------------------------------------
// Patch embed: xc[b,n,c] = sum_f patches * pw[c,f] + pb[c] + pos[n,c]
// ---------------------------------------------------------------------------
__global__ __launch_bounds__(256) void patch_kernel(
    const float* __restrict__ x, const float* __restrict__ pw,
    const float* __restrict__ pb, const float* __restrict__ pos,
    float* __restrict__ xc)
{
  const int n = blockIdx.x, b = blockIdx.y, tid = threadIdx.x;
  __shared__ float pv[16];
  if (tid < 16) {
    const int ci = tid >> 2, pi = (tid >> 1) & 1, pj = tid & 1;
    const int i = n >> 4, j = n & 15;
    pv[tid] = x[((size_t)(b * 4 + ci) * 32 + i * 2 + pi) * 32 + j * 2 + pj];
  }
  __syncthreads();
#pragma unroll
  for (int qq = 0; qq < 4; ++qq) {
    const int c = qq * 256 + tid;
    const float4* wr = (const float4*)(pw + (size_t)c * 16);
    float acc = pb[c] + pos[(size_t)n * 1024 + c];
#pragma unroll
    for (int g = 0; g < 4; ++g) {
      float4 w = wr[g];
      acc += w.x * pv[g * 4] + w.y * pv[g * 4 + 1] + w.z * pv[g * 4 + 2] + w.w * pv[g * 4 + 3];
    }
    xc[((size_t)b * 256 + n) * 1024 + c] = acc;
  }
}

// ---------------------------------------------------------------------------
// RMSNorm + adaLN modulate -> bf16
// ---------------------------------------------------------------------------
__global__ __launch_bounds__(256) void normmod_kernel(
    const float* __restrict__ xc, const float* __restrict__ w,
    const float* __restrict__ mods, int mult_off, int shift_off, int mstride,
    u16* __restrict__ out)
{
  const int m = blockIdx.x, b = m >> 8, tid = threadIdx.x;
  const float* row = xc + (size_t)m * 1024;
  float4 v = *(const float4*)(row + tid * 4);
  float ss = v.x * v.x + v.y * v.y + v.z * v.z + v.w * v.w;
  ss = waveAllSum(ss);
  __shared__ float red[4];
  if ((tid & 63) == 0) red[tid >> 6] = ss;
  __syncthreads();
  const float tot = red[0] + red[1] + red[2] + red[3];
  const float r = rsqrtf(tot * (1.f / 1024.f) + 1e-6f);
  const float* mb = mods + (size_t)b * mstride;
  const int c = tid * 4;
  float4 wv = *(const float4*)(w + c);
  float4 mu = *(const float4*)(mb + mult_off + c);
  float4 sh = *(const float4*)(mb + shift_off + c);
  union { u16 u[4]; uint2 v2; } pk;
  pk.u[0] = f2bf(v.x * r * wv.x * (1.f + mu.x) + sh.x);
  pk.u[1] = f2bf(v.y * r * wv.y * (1.f + mu.y) + sh.y);
  pk.u[2] = f2bf(v.z * r * wv.z * (1.f + mu.z) + sh.z);
  pk.u[3] = f2bf(v.w * r * wv.w * (1.f + mu.w) + sh.w);
  *(uint2*)(out + (size_t)m * 1024 + c) = pk.v2;
}

// ---------------------------------------------------------------------------
// q/k RMSNorm + RoPE + v copy; qkv[b,n, {q,k,v}, h, d] -> q/k/v [bh, n, d]
// ---------------------------------------------------------------------------
__global__ __launch_bounds__(64) void rope_kernel(
    const float* __restrict__ qkv, const float* __restrict__ qnw,
    const float* __restrict__ knw, float* __restrict__ qb,
    float* __restrict__ kb, float* __restrict__ vb)
{
  const int n = blockIdx.x;
  const int bh = blockIdx.y;
  const int b = bh >> 4, h = bh & 15;
  const int d = threadIdx.x;
  const size_t base = ((size_t)(b * 256 + n)) * 3072 + h * 64 + d;
  float qv = qkv[base];
  float kv = qkv[base + 1024];
  float vv = qkv[base + 2048];
  float qs = waveAllSum(qv * qv);
  float ks = waveAllSum(kv * kv);
  const float rq = rsqrtf(qs * (1.f / 64.f) + 1e-6f);
  const float rk = rsqrtf(ks * (1.f / 64.f) + 1e-6f);
  const float qn = qv * rq * qnw[d];
  const float kn = kv * rk * knw[d];
  const int i = d & 31;
  const float freq = __powf(10000.f, -(float)(2 * i) * (1.f / 64.f));
  const float ang = (float)n * freq;
  float sv, cv;
  sincosf(ang, &sv, &cv);
  const float qo = __shfl_xor(qn, 32, 64);
  const float ko = __shfl_xor(kn, 32, 64);
  const float rq2 = (d < 32) ? -qo : qo;
  const float rk2 = (d < 32) ? -ko : ko;
  const size_t ob = ((size_t)bh * 256 + n) * 64 + d;
  qb[ob] = qn * cv + rq2 * sv;
  kb[ob] = kn * cv + rk2 * sv;
  vb[ob] = vv;
}

// ---------------------------------------------------------------------------
// Attention: per (b,h) 256x256, flash-style online softmax, f32.
// grid (128 bh, 2 half), 128 threads: 1 q-row per thread.
// Output bf16 at o[b, n, h, d]  (== [B,N,C] rows for proj GEMM)
// ---------------------------------------------------------------------------
__global__ __launch_bounds__(128) void attn_kernel(
    const float* __restrict__ qb, const float* __restrict__ kb,
    const float* __restrict__ vb, u16* __restrict__ o)
{
  const int bh = blockIdx.x;
  const int half = blockIdx.y;
  const int tid = threadIdx.x;
  const int n = half * 128 + tid;
  __shared__ alignas(16) float Ks[32][64];
  __shared__ alignas(16) float Vs[32][64];
  float q[64];
  {
    const float* qr = qb + ((size_t)bh * 256 + n) * 64;
#pragma unroll
    for (int i = 0; i < 16; ++i) {
      float4 t = *(const float4*)(qr + i * 4);
      q[i * 4] = t.x; q[i * 4 + 1] = t.y; q[i * 4 + 2] = t.z; q[i * 4 + 3] = t.w;
    }
  }
  float oa[64];
#pragma unroll
  for (int i = 0; i < 64; ++i) oa[i] = 0.f;
  float m_run = -1e30f, l_run = 0.f;

  for (int c0 = 0; c0 < 256; c0 += 32) {
    __syncthreads();
    {
      const int r = tid >> 2, cs = (tid & 3) * 16;
      const float* ksrc = kb + ((size_t)bh * 256 + c0 + r) * 64 + cs;
      const float* vsrc = vb + ((size_t)bh * 256 + c0 + r) * 64 + cs;
#pragma unroll
      for (int i = 0; i < 4; ++i) *(float4*)&Ks[r][cs + i * 4] = *(const float4*)(ksrc + i * 4);
#pragma unroll
      for (int i = 0; i < 4; ++i) *(float4*)&Vs[r][cs + i * 4] = *(const float4*)(vsrc + i * 4);
    }
    __syncthreads();
    float s[32];
    float cmax = -1e30f;
#pragma unroll
    for (int kk = 0; kk < 32; ++kk) {
      float a0 = 0.f;
#pragma unroll
      for (int d = 0; d < 64; d += 4) {
        float4 kvv = *(const float4*)&Ks[kk][d];
        a0 += q[d] * kvv.x + q[d + 1] * kvv.y + q[d + 2] * kvv.z + q[d + 3] * kvv.w;
      }
      s[kk] = a0 * 0.125f;
      cmax = fmaxf(cmax, s[kk]);
    }
    const float m_new = fmaxf(m_run, cmax);
    const float corr = __expf(m_run - m_new);
    l_run *= corr;
#pragma unroll
    for (int i = 0; i < 64; ++i) oa[i] *= corr;
#pragma unroll
    for (int kk = 0; kk < 32; ++kk) {
      const float p = __expf(s[kk] - m_new);
      l_run += p;
#pragma unroll
      for (int d = 0; d < 64; d += 4) {
        float4 vv = *(const float4*)&Vs[kk][d];
        oa[d] += p * vv.x; oa[d + 1] += p * vv.y; oa[d + 2] += p * vv.z; oa[d + 3] += p * vv.w;
      }
    }
    m_run = m_new;
  }
  const float inv = 1.f / l_run;
  const int b = bh >> 4, h = bh & 15;
  u16* dst = o + (((size_t)b * 256 + n) * 16 + h) * 64;
#pragma unroll
  for (int d = 0; d < 64; d += 8) {
    union { u16 u[8]; uint4 v; } pk;
#pragma unroll
    for (int i = 0; i < 8; ++i) pk.u[i] = f2bf(oa[d + i] * inv);
    *(uint4*)(dst + d) = pk.v;
  }
}

// ---------------------------------------------------------------------------
// Residual: xc += g[b,c] * (gout + bias)
// ---------------------------------------------------------------------------
__global__ __launch_bounds__(256) void resid_kernel(
    float* __restrict__ xc, const float* __restrict__ gout,
    const float* __restrict__ bias, const float* __restrict__ mods,
    int g_off, int mstride)
{
  const int m = blockIdx.x, b = m >> 8;
  const int c = threadIdx.x * 4;
  float4 xv = *(float4*)(xc + (size_t)m * 1024 + c);
  float4 gv = *(const float4*)(gout + (size_t)m * 1024 + c);
  float4 mg = *(const float4*)(mods + (size_t)b * mstride + g_off + c);
  float bx = 0.f, by = 0.f, bz = 0.f, bw = 0.f;
  if (bias) {
    float4 bb = *(const float4*)(bias + c);
    bx = bb.x; by = bb.y; bz = bb.z; bw = bb.w;
  }
  xv.x += mg.x * (gv.x + bx);
  xv.y += mg.y * (gv.y + by);
  xv.z += mg.z * (gv.z + bz);
  xv.w += mg.w * (gv.w + bw);
  *(float4*)(xc + (size_t)m * 1024 + c) = xv;
}

// ---------------------------------------------------------------------------
// SwiGLU: h1 = bf16(silu(h1a) * h1b), zero-pad cols [2730,2752)
// ---------------------------------------------------------------------------
__global__ __launch_bounds__(256) void swiglu_kernel(
    const float* __restrict__ h1a, const float* __restrict__ h1b,
    u16* __restrict__ h1)
{
  const int m = blockIdx.x;
  const size_t rb = (size_t)m * 2752;
  for (int j0 = threadIdx.x * 4; j0 < 2752; j0 += 1024) {
    float4 a = *(const float4*)(h1a + rb + j0);
    float4 bq = *(const float4*)(h1b + rb + j0);
    float av[4] = {a.x, a.y, a.z, a.w};
    float bv[4] = {bq.x, bq.y, bq.z, bq.w};
    union { u16 u[4]; uint2 v; } pk;
#pragma unroll
    for (int i = 0; i < 4; ++i) {
      float val = 0.f;
      if (j0 + i < 2730) val = silu_f(av[i]) * bv[i];
      pk.u[i] = f2bf(val);
    }
    *(uint2*)(h1 + rb + j0) = pk.v;
  }
}

// ---------------------------------------------------------------------------
// Final LayerNorm (no affine) + modulate -> bf16
// ---------------------------------------------------------------------------
__global__ __launch_bounds__(256) void lnmod_kernel(
    const float* __restrict__ xc, const float* __restrict__ fmods,
    u16* __restrict__ out)
{
  const int m = blockIdx.x, b = m >> 8, tid = threadIdx.x;
  const float* row = xc + (size_t)m * 1024;
  float4 v = *(const float4*)(row + tid * 4);
  float s1 = v.x + v.y + v.z + v.w;
  float s2 = v.x * v.x + v.y * v.y + v.z * v.z + v.w * v.w;
  s1 = waveAllSum(s1);
  s2 = waveAllSum(s2);
  __shared__ float r1[4], r2[4];
  if ((tid & 63) == 0) { r1[tid >> 6] = s1; r2[tid >> 6] = s2; }
  __syncthreads();
  const float t1 = r1[0] + r1[1] + r1[2] + r1[3];
  const float t2 = r2[0] + r2[1] + r2[2] + r2[3];
  const float mean = t1 * (1.f / 1024.f);
  const float var = t2 * (1.f / 1024.f) - mean * mean;
  const float rr = rsqrtf(var + 1e-5f);
  const float* mb = fmods + (size_t)b * 2048;
  const int c = tid * 4;
  float4 sh = *(const float4*)(mb + c);
  float4 sl = *(const float4*)(mb + 1024 + c);
  union { u16 u[4]; uint2 v2; } pk;
  pk.u[0] = f2bf((v.x - mean) * rr * (1.f + sl.x) + sh.x);
  pk.u[1] = f2bf((v.y - mean) * rr * (1.f + sl.y) + sh.y);
  pk.u[2] = f2bf((v.z - mean) * rr * (1.f + sl.z) + sh.z);
  pk.u[3] = f2bf((v.w - mean) * rr * (1.f + sl.w) + sh.w);
  *(uint2*)(out + (size_t)m * 1024 + c) = pk.v2;
}

// ---------------------------------------------------------------------------
// Final linear (16 outputs) + unpatchify
// ---------------------------------------------------------------------------
__global__ __launch_bounds__(256) void final_kernel(
    const u16* __restrict__ xfin, const float* __restrict__ w,
    const float* __restrict__ bias, float* __restrict__ out)
{
  const int tid = threadIdx.x;
  const int m = blockIdx.x * 16 + (tid >> 4);
  const int j = tid & 15;
  const u16* xr = xfin + (size_t)m * 1024;
  const float* wr = w + (size_t)j * 1024;
  float acc = 0.f;
  for (int k = 0; k < 1024; k += 8) {
    uint4 xv = *(const uint4*)(xr + k);
    const u16* xu = (const u16*)&xv;
    float4 w0 = *(const float4*)(wr + k);
    float4 w1 = *(const float4*)(wr + k + 4);
    acc += bf2f(xu[0]) * w0.x + bf2f(xu[1]) * w0.y + bf2f(xu[2]) * w0.z + bf2f(xu[3]) * w0.w;
    acc += bf2f(xu[4]) * w1.x + bf2f(xu[5]) * w1.y + bf2f(xu[6]) * w1.z + bf2f(xu[7]) * w1.w;
  }
  acc += bias[j];
  const int b = m >> 8, n = m & 255;
  const int i = n >> 4, jj = n & 15;
  const int pi = (j >> 3) & 1, pj = (j >> 2) & 1, oc = j & 3;
  out[((size_t)(b * 4 + oc) * 32 + i * 2 + pi) * 32 + jj * 2 + pj] = acc;
}

// ---------------------------------------------------------------------------
extern "C" void kernel_launch(void* const* d_in, const int* in_sizes, int n_in,
                              void* d_out, int out_size, void* d_ws, size_t ws_size,
                              hipStream_t stream) {
  const float* x       = (const float*)d_in[0];
  const int*   y       = (const int*)  d_in[1];
  const float* cfg_s   = (const float*)d_in[2];
  const float* patch_w = (const float*)d_in[3];
  const float* patch_b = (const float*)d_in[4];
  const float* pos_e   = (const float*)d_in[5];
  const float* class_e = (const float*)d_in[6];
  const float* cfg_w1  = (const float*)d_in[7];
  const float* cfg_b1  = (const float*)d_in[8];
  const float* cfg_w2  = (const float*)d_in[9];
  const float* cfg_b2  = (const float*)d_in[10];
  const float* n1w     = (const float*)d_in[11];
  const float* n2w     = (const float*)d_in[12];
  const float* qkvw    = (const float*)d_in[13];
  const float* projw   = (const float*)d_in[14];
  const float* projb   = (const float*)d_in[15];
  const float* qnw     = (const float*)d_in[16];
  const float* knw     = (const float*)d_in[17];
  const float* w1      = (const float*)d_in[18];
  const float* w2      = (const float*)d_in[19];
  const float* w3      = (const float*)d_in[20];
  const float* adaw    = (const float*)d_in[21];
  const float* adab    = (const float*)d_in[22];
  const float* finaw   = (const float*)d_in[23];
  const float* finab   = (const float*)d_in[24];
  const float* flw     = (const float*)d_in[25];
  const float* flb     = (const float*)d_in[26];
  (void)in_sizes; (void)n_in; (void)out_size;

  char* ws = (char*)d_ws;
  const size_t MB = 1024 * 1024;
  float* hc    = (float*)(ws);
  float* sc    = (float*)(ws + 32 * 1024);
  float* mods  = (float*)(ws + 64 * 1024);                 // 4*8*6144 f32 = 768KB
  float* fmods = (float*)(ws + 64 * 1024 + 786432);        // 8*2048 f32
  float* xc    = (float*)(ws + 1 * MB);                    // 8MB
  u16*   xm    = (u16*)  (ws + 9 * MB);                    // 4MB (also xfin)
  float* g1    = (float*)(ws + 14 * MB);                   // 24MB: qkv / projout / h1a / mlpout
  float* qb    = (float*)(ws + 38 * MB);                   // 8MB (h1b spans qb..vb)
  float* kb    = (float*)(ws + 46 * MB);
  float* vb    = (float*)(ws + 54 * MB);
  u16*   g3    = (u16*)  (ws + 62 * MB);                   // o_buf 4MB / h1 bf16 ~10.8MB
  if (ws_size < 62 * MB + (size_t)2048 * 2752 * 2) return; // needs ~73MB

  cond_hc_kernel<<<8, 256, 0, stream>>>(cfg_s, cfg_w1, cfg_b1, hc);
  cond_sc_kernel<<<dim3(1024, 8), 64, 0, stream>>>(hc, cfg_w2, cfg_b2, class_e, y, sc);
  for (int d = 0; d < 4; ++d)
    modlin_kernel<<<6144, 64, 0, stream>>>(adaw + (size_t)d * 6144 * 1024,
                                           adab + (size_t)d * 6144, sc,
                                           mods + (size_t)d * 8 * 6144, 6144);
  modlin_kernel<<<2048, 64, 0, stream>>>(finaw, finab, sc, fmods, 2048);
  patch_kernel<<<dim3(256, 8), 256, 0, stream>>>(x, patch_w, patch_b, pos_e, xc);

  for (int d = 0; d < 4; ++d) {
    const float* md = mods + (size_t)d * 8 * 6144;
    normmod_kernel<<<2048, 256, 0, stream>>>(xc, n1w + d * 1024, md, 1024, 0, 6144, xm);
    gemm_kernel<<<dim3(16, 24), 256, 0, stream>>>(xm, 1024, qkvw + (size_t)d * 3072 * 1024, 1024,
                                                  g1, 3072, 3072, 16, 1024);
    rope_kernel<<<dim3(256, 128), 64, 0, stream>>>(g1, qnw + d * 64, knw + d * 64, qb, kb, vb);
    attn_kernel<<<dim3(128, 2), 128, 0, stream>>>(qb, kb, vb, g3);
    gemm_kernel<<<dim3(16, 8), 256, 0, stream>>>(g3, 1024, projw + (size_t)d * 1024 * 1024, 1024,
                                                 g1, 1024, 1024, 16, 1024);
    resid_kernel<<<2048, 256, 0, stream>>>(xc, g1, projb + d * 1024, md, 2 * 1024, 6144);
    normmod_kernel<<<2048, 256, 0, stream>>>(xc, n2w + d * 1024, md, 4 * 1024, 3 * 1024, 6144, xm);
    gemm_kernel<<<dim3(16, 22), 256, 0, stream>>>(xm, 1024, w1 + (size_t)d * 2730 * 1024, 1024,
                                                  g1, 2752, 2730, 16, 1024);
    gemm_kernel<<<dim3(16, 22), 256, 0, stream>>>(xm, 1024, w3 + (size_t)d * 2730 * 1024, 1024,
                                                  qb, 2752, 2730, 16, 1024);
    swiglu_kernel<<<2048, 256, 0, stream>>>(g1, qb, g3);
    gemm_kernel<<<dim3(16, 8), 256, 0, stream>>>(g3, 2752, w2 + (size_t)d * 1024 * 2730, 2730,
                                                 g1, 1024, 1024, 43, 2730);
    resid_kernel<<<2048, 256, 0, stream>>>(xc, g1, nullptr, md, 5 * 1024, 6144);
  }

  lnmod_kernel<<<2048, 256, 0, stream>>>(xc, fmods, xm);
  final_kernel<<<128, 256, 0, stream>>>(xm, flw, flb, (float*)d_out);
}

// Round 2
// 1524.316 us; speedup vs baseline: 1.5863x; 1.5863x over previous
//
#include <hip/hip_runtime.h>

typedef unsigned short u16;
typedef unsigned int u32;
typedef float f32x4 __attribute__((ext_vector_type(4)));
typedef __bf16 bf16x8 __attribute__((ext_vector_type(8)));

#define DEV __device__ __forceinline__

DEV u16 f2bf(float f) {
  u32 u = __builtin_bit_cast(u32, f);
  u += 0x7fffu + ((u >> 16) & 1u);
  return (u16)(u >> 16);
}
DEV float bf2f(u16 u) { return __builtin_bit_cast(float, (u32)u << 16); }
DEV float waveAllSum(float x) {
#pragma unroll
  for (int off = 32; off > 0; off >>= 1) x += __shfl_xor(x, off, 64);
  return x;
}
DEV float silu_f(float x) { return x / (1.f + __expf(-x)); }

// ---------------------------------------------------------------------------
// Generic NT GEMM: C[m,n] = sum_k A_bf16[m,k] * W_f32[n,k]
// 1D grid with XCD-aware swizzle (nwg % 8 == 0 for all launches).
// 128x128 tile, BK=64, 4 waves. W converted f32->bf16 during LDS staging.
// ---------------------------------------------------------------------------
__global__ __launch_bounds__(256) void gemm_kernel(
    const u16* __restrict__ A, int lda,
    const float* __restrict__ W, int ldw,
    float* __restrict__ C, int ldc,
    int N, int Ksteps, int Kw, int nbx)
{
  __shared__ alignas(16) u16 As[128][72];
  __shared__ alignas(16) u16 Ws[128][72];
  const int tid = threadIdx.x;
  const int lane = tid & 63;
  const int wave = tid >> 6;
  const int wm = (wave >> 1) * 64;
  const int wn = (wave & 1) * 64;
  // XCD swizzle: consecutive idx (sharing W panels) stay on one XCD
  const int nwg = gridDim.x;
  const int cpx = nwg >> 3;
  const int f = blockIdx.x;
  const int idx = (f & 7) * cpx + (f >> 3);
  const int m0 = (idx % nbx) * 128;
  const int n0 = (idx / nbx) * 128;
  const int srow = tid >> 1;
  const int sseg = (tid & 1) * 32;
  const int rl = lane & 15;
  const int kq = (lane >> 4) * 8;

  f32x4 acc[4][4];
#pragma unroll
  for (int i = 0; i < 4; ++i)
#pragma unroll
    for (int j = 0; j < 4; ++j) acc[i][j] = (f32x4){0.f, 0.f, 0.f, 0.f};

  for (int kt = 0; kt < Ksteps; ++kt) {
    const int k0 = kt * 64;
    __syncthreads();
    {
      const u16* src = A + (size_t)(m0 + srow) * lda + k0 + sseg;
      uint4 v0 = *(const uint4*)(src + 0);
      uint4 v1 = *(const uint4*)(src + 8);
      uint4 v2 = *(const uint4*)(src + 16);
      uint4 v3 = *(const uint4*)(src + 24);
      *(uint4*)&As[srow][sseg + 0]  = v0;
      *(uint4*)&As[srow][sseg + 8]  = v1;
      *(uint4*)&As[srow][sseg + 16] = v2;
      *(uint4*)&As[srow][sseg + 24] = v3;
    }
    {
      const int n = n0 + srow;
      const int kbase = k0 + sseg;
      const float* src = W + (size_t)n * ldw + kbase;
      if (n < N && kbase + 32 <= Kw) {
#pragma unroll
        for (int g = 0; g < 4; ++g) {
          float4 a = *(const float4*)(src + g * 8);
          float4 b = *(const float4*)(src + g * 8 + 4);
          union { u16 u[8]; uint4 v; } p;
          p.u[0] = f2bf(a.x); p.u[1] = f2bf(a.y); p.u[2] = f2bf(a.z); p.u[3] = f2bf(a.w);
          p.u[4] = f2bf(b.x); p.u[5] = f2bf(b.y); p.u[6] = f2bf(b.z); p.u[7] = f2bf(b.w);
          *(uint4*)&Ws[srow][sseg + g * 8] = p.v;
        }
      } else {
#pragma unroll 4
        for (int g = 0; g < 32; ++g) {
          float v = (n < N && (kbase + g) < Kw) ? src[g] : 0.f;
          Ws[srow][sseg + g] = f2bf(v);
        }
      }
    }
    __syncthreads();
#pragma unroll
    for (int kk = 0; kk < 2; ++kk) {
      bf16x8 af[4], bfr[4];
#pragma unroll
      for (int i = 0; i < 4; ++i)
        af[i] = *(const bf16x8*)&As[wm + i * 16 + rl][kk * 32 + kq];
#pragma unroll
      for (int j = 0; j < 4; ++j)
        bfr[j] = *(const bf16x8*)&Ws[wn + j * 16 + rl][kk * 32 + kq];
#pragma unroll
      for (int i = 0; i < 4; ++i)
#pragma unroll
        for (int j = 0; j < 4; ++j)
          acc[i][j] = __builtin_amdgcn_mfma_f32_16x16x32_bf16(af[i], bfr[j], acc[i][j], 0, 0, 0);
    }
  }
  const int rq = (lane >> 4) * 4;
#pragma unroll
  for (int j = 0; j < 4; ++j) {
    const int n = n0 + wn + j * 16 + rl;
    if (n >= N) continue;
#pragma unroll
    for (int i = 0; i < 4; ++i) {
      const int mrow = m0 + wm + i * 16 + rq;
#pragma unroll
      for (int r = 0; r < 4; ++r)
        C[(size_t)(mrow + r) * ldc + n] = acc[i][j][r];
    }
  }
}

// ---------------------------------------------------------------------------
// Conditioning
// ---------------------------------------------------------------------------
__global__ __launch_bounds__(256) void cond_hc_kernel(
    const float* __restrict__ cfg_s, const float* __restrict__ w1,
    const float* __restrict__ b1, float* __restrict__ hc)
{
  const int b = blockIdx.x, c = threadIdx.x * 4;
  const float s = cfg_s[b];
  float4 w = *(const float4*)(w1 + c);
  float4 bb = *(const float4*)(b1 + c);
  float4 o;
  o.x = silu_f(s * w.x + bb.x);
  o.y = silu_f(s * w.y + bb.y);
  o.z = silu_f(s * w.z + bb.z);
  o.w = silu_f(s * w.w + bb.w);
  *(float4*)(hc + (size_t)b * 1024 + c) = o;
}

__global__ __launch_bounds__(64) void cond_sc_kernel(
    const float* __restrict__ hc, const float* __restrict__ w2,
    const float* __restrict__ b2, const float* __restrict__ ce,
    const int* __restrict__ y, float* __restrict__ sc)
{
  const int j = blockIdx.x, b = blockIdx.y, lane = threadIdx.x;
  const float4* wr = (const float4*)(w2 + (size_t)j * 1024);
  const float4* hr = (const float4*)(hc + (size_t)b * 1024);
  float acc = 0.f;
#pragma unroll
  for (int rep = 0; rep < 4; ++rep) {
    float4 w = wr[rep * 64 + lane];
    float4 h = hr[rep * 64 + lane];
    acc += w.x * h.x + w.y * h.y + w.z * h.z + w.w * h.w;
  }
  acc = waveAllSum(acc);
  if (lane == 0) {
    float v = ce[(size_t)y[b] * 1024 + j] + acc + b2[j];
    sc[(size_t)b * 1024 + j] = silu_f(v);
  }
}

__global__ __launch_bounds__(64) void modlin_kernel(
    const float* __restrict__ w, const float* __restrict__ bias,
    const float* __restrict__ sc, float* __restrict__ out, int ostride)
{
  const int j = blockIdx.x, lane = threadIdx.x;
  const float4* wr = (const float4*)(w + (size_t)j * 1024);
  float acc[8];
#pragma unroll
  for (int b = 0; b < 8; ++b) acc[b] = 0.f;
#pragma unroll
  for (int rep = 0; rep < 4; ++rep) {
    float4 wv = wr[rep * 64 + lane];
#pragma unroll
    for (int b = 0; b < 8; ++b) {
      float4 s = ((const float4*)(sc + (size_t)b * 1024))[rep * 64 + lane];
      acc[b] += wv.x * s.x + wv.y * s.y + wv.z * s.z + wv.w * s.w;
    }
  }
#pragma unroll
  for (int b = 0; b < 8; ++b) acc[b] = waveAllSum(acc[b]);
  if (lane == 0) {
    const float bb = bias[j];
#pragma unroll
    for (int b = 0; b < 8; ++b) out[(size_t)b * ostride + j] = acc[b] + bb;
  }
}

// ---------------------------------------------------------------------------
// Patch embed
// ---------------------------------------------------------------------------
__global__ __launch_bounds__(256) void patch_kernel(
    const float* __restrict__ x, const float* __restrict__ pw,
    const float* __restrict__ pb, const float* __restrict__ pos,
    float* __restrict__ xc)
{
  const int n = blockIdx.x, b = blockIdx.y, tid = threadIdx.x;
  __shared__ float pv[16];
  if (tid < 16) {
    const int ci = tid >> 2, pi = (tid >> 1) & 1, pj = tid & 1;
    const int i = n >> 4, j = n & 15;
    pv[tid] = x[((size_t)(b * 4 + ci) * 32 + i * 2 + pi) * 32 + j * 2 + pj];
  }
  __syncthreads();
#pragma unroll
  for (int qq = 0; qq < 4; ++qq) {
    const int c = qq * 256 + tid;
    const float4* wr = (const float4*)(pw + (size_t)c * 16);
    float acc = pb[c] + pos[(size_t)n * 1024 + c];
#pragma unroll
    for (int g = 0; g < 4; ++g) {
      float4 w = wr[g];
      acc += w.x * pv[g * 4] + w.y * pv[g * 4 + 1] + w.z * pv[g * 4 + 2] + w.w * pv[g * 4 + 3];
    }
    xc[((size_t)b * 256 + n) * 1024 + c] = acc;
  }
}

// ---------------------------------------------------------------------------
// RMSNorm + adaLN modulate -> bf16
// ---------------------------------------------------------------------------
__global__ __launch_bounds__(256) void normmod_kernel(
    const float* __restrict__ xc, const float* __restrict__ w,
    const float* __restrict__ mods, int mult_off, int shift_off, int mstride,
    u16* __restrict__ out)
{
  const int m = blockIdx.x, b = m >> 8, tid = threadIdx.x;
  const float* row = xc + (size_t)m * 1024;
  float4 v = *(const float4*)(row + tid * 4);
  float ss = v.x * v.x + v.y * v.y + v.z * v.z + v.w * v.w;
  ss = waveAllSum(ss);
  __shared__ float red[4];
  if ((tid & 63) == 0) red[tid >> 6] = ss;
  __syncthreads();
  const float tot = red[0] + red[1] + red[2] + red[3];
  const float r = rsqrtf(tot * (1.f / 1024.f) + 1e-6f);
  const float* mb = mods + (size_t)b * mstride;
  const int c = tid * 4;
  float4 wv = *(const float4*)(w + c);
  float4 mu = *(const float4*)(mb + mult_off + c);
  float4 sh = *(const float4*)(mb + shift_off + c);
  union { u16 u[4]; uint2 v2; } pk;
  pk.u[0] = f2bf(v.x * r * wv.x * (1.f + mu.x) + sh.x);
  pk.u[1] = f2bf(v.y * r * wv.y * (1.f + mu.y) + sh.y);
  pk.u[2] = f2bf(v.z * r * wv.z * (1.f + mu.z) + sh.z);
  pk.u[3] = f2bf(v.w * r * wv.w * (1.f + mu.w) + sh.w);
  *(uint2*)(out + (size_t)m * 1024 + c) = pk.v2;
}

// ---------------------------------------------------------------------------
// q/k RMSNorm + RoPE + v copy -> bf16 [bh, n, d]
// ---------------------------------------------------------------------------
__global__ __launch_bounds__(256) void rope_kernel(
    const float* __restrict__ qkv, const float* __restrict__ qnw,
    const float* __restrict__ knw, u16* __restrict__ qb,
    u16* __restrict__ kb, u16* __restrict__ vb)
{
  const int idx = blockIdx.x * 4 + (threadIdx.x >> 6);
  const int n = idx & 255;
  const int bh = idx >> 8;
  const int b = bh >> 4, h = bh & 15;
  const int d = threadIdx.x & 63;
  const size_t base = ((size_t)(b * 256 + n)) * 3072 + h * 64 + d;
  float qv = qkv[base];
  float kv = qkv[base + 1024];
  float vv = qkv[base + 2048];
  float qs = waveAllSum(qv * qv);
  float ks = waveAllSum(kv * kv);
  const float rq = rsqrtf(qs * (1.f / 64.f) + 1e-6f);
  const float rk = rsqrtf(ks * (1.f / 64.f) + 1e-6f);
  const float qn = qv * rq * qnw[d];
  const float kn = kv * rk * knw[d];
  const int i = d & 31;
  const float freq = __powf(10000.f, -(float)(2 * i) * (1.f / 64.f));
  const float ang = (float)n * freq;
  float sv, cv;
  sincosf(ang, &sv, &cv);
  const float qo = __shfl_xor(qn, 32, 64);
  const float ko = __shfl_xor(kn, 32, 64);
  const float rq2 = (d < 32) ? -qo : qo;
  const float rk2 = (d < 32) ? -ko : ko;
  const size_t ob = ((size_t)bh * 256 + n) * 64 + d;
  qb[ob] = f2bf(qn * cv + rq2 * sv);
  kb[ob] = f2bf(kn * cv + rk2 * sv);
  vb[ob] = f2bf(vv);
}

// ---------------------------------------------------------------------------
// MFMA attention: grid (bh=128, qtile=4), 256 thr (4 waves x 16 q-rows).
// K staged [128][72] bf16; V transposed [64][136]; per-wave P slab [16][136].
// Online softmax over 2 K-tiles. Output bf16 at o[b,n,h,d].
// ---------------------------------------------------------------------------
__global__ __launch_bounds__(256) void attn_kernel(
    const u16* __restrict__ qb, const u16* __restrict__ kb,
    const u16* __restrict__ vb, u16* __restrict__ o)
{
  __shared__ alignas(16) u16 Kt[128][72];
  __shared__ alignas(16) u16 Vtt[64][136];
  __shared__ alignas(16) u16 Pw[4][16][136];
  const int bh = blockIdx.x;
  const int qbase = blockIdx.y * 64;
  const int tid = threadIdx.x;
  const int lane = tid & 63;
  const int wave = tid >> 6;
  const int rl = lane & 15;
  const int kq = (lane >> 4) * 8;
  const int rowg = (lane >> 4) * 4;

  const int q0 = qbase + wave * 16;
  const u16* qsrc = qb + ((size_t)bh * 256 + q0 + rl) * 64 + kq;
  const bf16x8 a0 = *(const bf16x8*)(qsrc);
  const bf16x8 a1 = *(const bf16x8*)(qsrc + 32);

  float m[4], l[4];
  f32x4 oacc[4];
#pragma unroll
  for (int r = 0; r < 4; ++r) { m[r] = -1e30f; l[r] = 0.f; }
#pragma unroll
  for (int dt = 0; dt < 4; ++dt) oacc[dt] = (f32x4){0.f, 0.f, 0.f, 0.f};

  for (int kt = 0; kt < 2; ++kt) {
    __syncthreads();
    // stage K tile (coalesced)
#pragma unroll
    for (int c = 0; c < 4; ++c) {
      const int flat = c * 256 + tid;
      const int row = flat >> 3;
      const int col = (flat & 7) * 8;
      uint4 v = *(const uint4*)(kb + ((size_t)bh * 256 + kt * 128 + row) * 64 + col);
      *(uint4*)&Kt[row][col] = v;
    }
    // stage V^T (pack 2 rows per u32)
    {
      const int tt = tid & 63;
      const int dh = tid >> 6;
      const int r0 = tt * 2;
      const u16* s0 = vb + ((size_t)bh * 256 + kt * 128 + r0) * 64 + dh * 16;
      const u16* s1 = s0 + 64;
#pragma unroll
      for (int g = 0; g < 2; ++g) {
        uint4 A = *(const uint4*)(s0 + g * 8);
        uint4 B = *(const uint4*)(s1 + g * 8);
        const u32 aw[4] = {A.x, A.y, A.z, A.w};
        const u32 bw[4] = {B.x, B.y, B.z, B.w};
#pragma unroll
        for (int q = 0; q < 4; ++q) {
          const int d2 = dh * 16 + g * 8 + q * 2;
          const u32 lo = (aw[q] & 0xffffu) | (bw[q] << 16);
          const u32 hi = (aw[q] >> 16) | (bw[q] & 0xffff0000u);
          *(u32*)&Vtt[d2][r0] = lo;
          *(u32*)&Vtt[d2 + 1][r0] = hi;
        }
      }
    }
    __syncthreads();

    // S = Q K^T over this 128-col tile
    f32x4 sacc[8];
#pragma unroll
    for (int t = 0; t < 8; ++t) sacc[t] = (f32x4){0.f, 0.f, 0.f, 0.f};
#pragma unroll
    for (int t = 0; t < 8; ++t) {
      bf16x8 k0 = *(const bf16x8*)&Kt[t * 16 + rl][kq];
      bf16x8 k1 = *(const bf16x8*)&Kt[t * 16 + rl][32 + kq];
      sacc[t] = __builtin_amdgcn_mfma_f32_16x16x32_bf16(a0, k0, sacc[t], 0, 0, 0);
      sacc[t] = __builtin_amdgcn_mfma_f32_16x16x32_bf16(a1, k1, sacc[t], 0, 0, 0);
    }
    // row max across in-lane tiles then across 16 lanes
    float cmax[4];
#pragma unroll
    for (int r = 0; r < 4; ++r) cmax[r] = sacc[0][r];
#pragma unroll
    for (int t = 1; t < 8; ++t)
#pragma unroll
      for (int r = 0; r < 4; ++r) cmax[r] = fmaxf(cmax[r], sacc[t][r]);
#pragma unroll
    for (int off = 1; off < 16; off <<= 1)
#pragma unroll
      for (int r = 0; r < 4; ++r) cmax[r] = fmaxf(cmax[r], __shfl_xor(cmax[r], off, 64));
    // online rescale
#pragma unroll
    for (int r = 0; r < 4; ++r) {
      const float mn = fmaxf(m[r], cmax[r]);
      const float corr = __expf((m[r] - mn) * 0.125f);
      l[r] *= corr;
#pragma unroll
      for (int dt = 0; dt < 4; ++dt) oacc[dt][r] *= corr;
      m[r] = mn;
    }
    float lsum[4] = {0.f, 0.f, 0.f, 0.f};
#pragma unroll
    for (int t = 0; t < 8; ++t)
#pragma unroll
      for (int r = 0; r < 4; ++r) {
        const float p = __expf((sacc[t][r] - m[r]) * 0.125f);
        lsum[r] += p;
        Pw[wave][rowg + r][t * 16 + rl] = f2bf(p);
      }
#pragma unroll
    for (int off = 1; off < 16; off <<= 1)
#pragma unroll
      for (int r = 0; r < 4; ++r) lsum[r] += __shfl_xor(lsum[r], off, 64);
#pragma unroll
    for (int r = 0; r < 4; ++r) l[r] += lsum[r];
    // PV
#pragma unroll
    for (int ks = 0; ks < 4; ++ks) {
      bf16x8 pa = *(const bf16x8*)&Pw[wave][rl][ks * 32 + kq];
#pragma unroll
      for (int dt = 0; dt < 4; ++dt) {
        bf16x8 vf = *(const bf16x8*)&Vtt[dt * 16 + rl][ks * 32 + kq];
        oacc[dt] = __builtin_amdgcn_mfma_f32_16x16x32_bf16(pa, vf, oacc[dt], 0, 0, 0);
      }
    }
  }
  const int b = bh >> 4, h = bh & 15;
#pragma unroll
  for (int r = 0; r < 4; ++r) {
    const float inv = 1.f / l[r];
    const int qrow = q0 + rowg + r;
    u16* dst = o + (((size_t)b * 256 + qrow) * 16 + h) * 64 + rl;
#pragma unroll
    for (int dt = 0; dt < 4; ++dt)
      dst[dt * 16] = f2bf(oacc[dt][r] * inv);
  }
}

// ---------------------------------------------------------------------------
// Residual: xc += g[b,c] * (gout + bias)
// ---------------------------------------------------------------------------
__global__ __launch_bounds__(256) void resid_kernel(
    float* __restrict__ xc, const float* __restrict__ gout,
    const float* __restrict__ bias, const float* __restrict__ mods,
    int g_off, int mstride)
{
  const int m = blockIdx.x, b = m >> 8;
  const int c = threadIdx.x * 4;
  float4 xv = *(float4*)(xc + (size_t)m * 1024 + c);
  float4 gv = *(const float4*)(gout + (size_t)m * 1024 + c);
  float4 mg = *(const float4*)(mods + (size_t)b * mstride + g_off + c);
  float bx = 0.f, by = 0.f, bz = 0.f, bw = 0.f;
  if (bias) {
    float4 bb = *(const float4*)(bias + c);
    bx = bb.x; by = bb.y; bz = bb.z; bw = bb.w;
  }
  xv.x += mg.x * (gv.x + bx);
  xv.y += mg.y * (gv.y + by);
  xv.z += mg.z * (gv.z + bz);
  xv.w += mg.w * (gv.w + bw);
  *(float4*)(xc + (size_t)m * 1024 + c) = xv;
}

// ---------------------------------------------------------------------------
// SwiGLU: h1 = bf16(silu(h1a) * h1b), zero-pad cols [2730,2752)
// ---------------------------------------------------------------------------
__global__ __launch_bounds__(256) void swiglu_kernel(
    const float* __restrict__ h1a, const float* __restrict__ h1b,
    u16* __restrict__ h1)
{
  const int m = blockIdx.x;
  const size_t rb = (size_t)m * 2752;
  for (int j0 = threadIdx.x * 4; j0 < 2752; j0 += 1024) {
    float4 a = *(const float4*)(h1a + rb + j0);
    float4 bq = *(const float4*)(h1b + rb + j0);
    float av[4] = {a.x, a.y, a.z, a.w};
    float bv[4] = {bq.x, bq.y, bq.z, bq.w};
    union { u16 u[4]; uint2 v; } pk;
#pragma unroll
    for (int i = 0; i < 4; ++i) {
      float val = 0.f;
      if (j0 + i < 2730) val = silu_f(av[i]) * bv[i];
      pk.u[i] = f2bf(val);
    }
    *(uint2*)(h1 + rb + j0) = pk.v;
  }
}

// ---------------------------------------------------------------------------
// Final LayerNorm + modulate -> bf16
// ---------------------------------------------------------------------------
__global__ __launch_bounds__(256) void lnmod_kernel(
    const float* __restrict__ xc, const float* __restrict__ fmods,
    u16* __restrict__ out)
{
  const int m = blockIdx.x, b = m >> 8, tid = threadIdx.x;
  const float* row = xc + (size_t)m * 1024;
  float4 v = *(const float4*)(row + tid * 4);
  float s1 = v.x + v.y + v.z + v.w;
  float s2 = v.x * v.x + v.y * v.y + v.z * v.z + v.w * v.w;
  s1 = waveAllSum(s1);
  s2 = waveAllSum(s2);
  __shared__ float r1[4], r2[4];
  if ((tid & 63) == 0) { r1[tid >> 6] = s1; r2[tid >> 6] = s2; }
  __syncthreads();
  const float t1 = r1[0] + r1[1] + r1[2] + r1[3];
  const float t2 = r2[0] + r2[1] + r2[2] + r2[3];
  const float mean = t1 * (1.f / 1024.f);
  const float var = t2 * (1.f / 1024.f) - mean * mean;
  const float rr = rsqrtf(var + 1e-5f);
  const float* mb = fmods + (size_t)b * 2048;
  const int c = tid * 4;
  float4 sh = *(const float4*)(mb + c);
  float4 sl = *(const float4*)(mb + 1024 + c);
  union { u16 u[4]; uint2 v2; } pk;
  pk.u[0] = f2bf((v.x - mean) * rr * (1.f + sl.x) + sh.x);
  pk.u[1] = f2bf((v.y - mean) * rr * (1.f + sl.y) + sh.y);
  pk.u[2] = f2bf((v.z - mean) * rr * (1.f + sl.z) + sh.z);
  pk.u[3] = f2bf((v.w - mean) * rr * (1.f + sl.w) + sh.w);
  *(uint2*)(out + (size_t)m * 1024 + c) = pk.v2;
}

// ---------------------------------------------------------------------------
// Final linear (16 outputs) + unpatchify
// ---------------------------------------------------------------------------
__global__ __launch_bounds__(256) void final_kernel(
    const u16* __restrict__ xfin, const float* __restrict__ w,
    const float* __restrict__ bias, float* __restrict__ out)
{
  const int tid = threadIdx.x;
  const int m = blockIdx.x * 16 + (tid >> 4);
  const int j = tid & 15;
  const u16* xr = xfin + (size_t)m * 1024;
  const float* wr = w + (size_t)j * 1024;
  float acc = 0.f;
  for (int k = 0; k < 1024; k += 8) {
    uint4 xv = *(const uint4*)(xr + k);
    const u16* xu = (const u16*)&xv;
    float4 w0 = *(const float4*)(wr + k);
    float4 w1 = *(const float4*)(wr + k + 4);
    acc += bf2f(xu[0]) * w0.x + bf2f(xu[1]) * w0.y + bf2f(xu[2]) * w0.z + bf2f(xu[3]) * w0.w;
    acc += bf2f(xu[4]) * w1.x + bf2f(xu[5]) * w1.y + bf2f(xu[6]) * w1.z + bf2f(xu[7]) * w1.w;
  }
  acc += bias[j];
  const int b = m >> 8, n = m & 255;
  const int i = n >> 4, jj = n & 15;
  const int pi = (j >> 3) & 1, pj = (j >> 2) & 1, oc = j & 3;
  out[((size_t)(b * 4 + oc) * 32 + i * 2 + pi) * 32 + jj * 2 + pj] = acc;
}

// ---------------------------------------------------------------------------
extern "C" void kernel_launch(void* const* d_in, const int* in_sizes, int n_in,
                              void* d_out, int out_size, void* d_ws, size_t ws_size,
                              hipStream_t stream) {
  const float* x       = (const float*)d_in[0];
  const int*   y       = (const int*)  d_in[1];
  const float* cfg_s   = (const float*)d_in[2];
  const float* patch_w = (const float*)d_in[3];
  const float* patch_b = (const float*)d_in[4];
  const float* pos_e   = (const float*)d_in[5];
  const float* class_e = (const float*)d_in[6];
  const float* cfg_w1  = (const float*)d_in[7];
  const float* cfg_b1  = (const float*)d_in[8];
  const float* cfg_w2  = (const float*)d_in[9];
  const float* cfg_b2  = (const float*)d_in[10];
  const float* n1w     = (const float*)d_in[11];
  const float* n2w     = (const float*)d_in[12];
  const float* qkvw    = (const float*)d_in[13];
  const float* projw   = (const float*)d_in[14];
  const float* projb   = (const float*)d_in[15];
  const float* qnw     = (const float*)d_in[16];
  const float* knw     = (const float*)d_in[17];
  const float* w1      = (const float*)d_in[18];
  const float* w2      = (const float*)d_in[19];
  const float* w3      = (const float*)d_in[20];
  const float* adaw    = (const float*)d_in[21];
  const float* adab    = (const float*)d_in[22];
  const float* finaw   = (const float*)d_in[23];
  const float* finab   = (const float*)d_in[24];
  const float* flw     = (const float*)d_in[25];
  const float* flb     = (const float*)d_in[26];
  (void)in_sizes; (void)n_in; (void)out_size;

  char* ws = (char*)d_ws;
  const size_t MB = 1024 * 1024;
  float* hc    = (float*)(ws);
  float* sc    = (float*)(ws + 32 * 1024);
  float* mods  = (float*)(ws + 64 * 1024);
  float* fmods = (float*)(ws + 64 * 1024 + 786432);
  float* xc    = (float*)(ws + 1 * MB);        // 8MB
  u16*   xm    = (u16*)  (ws + 9 * MB);        // 4MB, also attn output o_buf
  float* zoneA = (float*)(ws + 13 * MB);       // 24MB: qkv f32 / h1a
  float* zoneB = (float*)(ws + 37 * MB);       // 24MB: projout / h1b / mlpout
  u16*   qbuf  = (u16*)  (ws + 61 * MB);       // 4MB
  u16*   kbuf  = (u16*)  (ws + 65 * MB);       // 4MB
  u16*   vbuf  = (u16*)  (ws + 69 * MB);       // 4MB
  u16*   h1    = (u16*)  (ws + 61 * MB);       // 11.3MB, overlaps q/k/v (dead)
  if (ws_size < 73 * MB) return;

  cond_hc_kernel<<<8, 256, 0, stream>>>(cfg_s, cfg_w1, cfg_b1, hc);
  cond_sc_kernel<<<dim3(1024, 8), 64, 0, stream>>>(hc, cfg_w2, cfg_b2, class_e, y, sc);
  for (int d = 0; d < 4; ++d)
    modlin_kernel<<<6144, 64, 0, stream>>>(adaw + (size_t)d * 6144 * 1024,
                                           adab + (size_t)d * 6144, sc,
                                           mods + (size_t)d * 8 * 6144, 6144);
  modlin_kernel<<<2048, 64, 0, stream>>>(finaw, finab, sc, fmods, 2048);
  patch_kernel<<<dim3(256, 8), 256, 0, stream>>>(x, patch_w, patch_b, pos_e, xc);

  for (int d = 0; d < 4; ++d) {
    const float* md = mods + (size_t)d * 8 * 6144;
    normmod_kernel<<<2048, 256, 0, stream>>>(xc, n1w + d * 1024, md, 1024, 0, 6144, xm);
    gemm_kernel<<<16 * 24, 256, 0, stream>>>(xm, 1024, qkvw + (size_t)d * 3072 * 1024, 1024,
                                             zoneA, 3072, 3072, 16, 1024, 16);
    rope_kernel<<<8192, 256, 0, stream>>>(zoneA, qnw + d * 64, knw + d * 64, qbuf, kbuf, vbuf);
    attn_kernel<<<dim3(128, 4), 256, 0, stream>>>(qbuf, kbuf, vbuf, xm);
    gemm_kernel<<<16 * 8, 256, 0, stream>>>(xm, 1024, projw + (size_t)d * 1024 * 1024, 1024,
                                            zoneB, 1024, 1024, 16, 1024, 16);
    resid_kernel<<<2048, 256, 0, stream>>>(xc, zoneB, projb + d * 1024, md, 2 * 1024, 6144);
    normmod_kernel<<<2048, 256, 0, stream>>>(xc, n2w + d * 1024, md, 4 * 1024, 3 * 1024, 6144, xm);
    gemm_kernel<<<16 * 22, 256, 0, stream>>>(xm, 1024, w1 + (size_t)d * 2730 * 1024, 1024,
                                             zoneA, 2752, 2730, 16, 1024, 16);
    gemm_kernel<<<16 * 22, 256, 0, stream>>>(xm, 1024, w3 + (size_t)d * 2730 * 1024, 1024,
                                             zoneB, 2752, 2730, 16, 1024, 16);
    swiglu_kernel<<<2048, 256, 0, stream>>>(zoneA, zoneB, h1);
    gemm_kernel<<<16 * 8, 256, 0, stream>>>(h1, 2752, w2 + (size_t)d * 1024 * 2730, 2730,
                                            zoneB, 1024, 1024, 43, 2730, 16);
    resid_kernel<<<2048, 256, 0, stream>>>(xc, zoneB, nullptr, md, 5 * 1024, 6144);
  }

  lnmod_kernel<<<2048, 256, 0, stream>>>(xc, fmods, xm);
  final_kernel<<<128, 256, 0, stream>>>(xm, flw, flb, (float*)d_out);
}

// Round 3
// 1028.052 us; speedup vs baseline: 2.3521x; 1.4827x over previous
//
#include <hip/hip_runtime.h>

typedef unsigned short u16;
typedef unsigned int u32;
typedef float f32x4 __attribute__((ext_vector_type(4)));
typedef __bf16 bf16x8 __attribute__((ext_vector_type(8)));

#define DEV __device__ __forceinline__

DEV u16 f2bf(float f) {
  u32 u = __builtin_bit_cast(u32, f);
  u += 0x7fffu + ((u >> 16) & 1u);
  return (u16)(u >> 16);
}
DEV float bf2f(u16 u) { return __builtin_bit_cast(float, (u32)u << 16); }
DEV float waveAllSum(float x) {
#pragma unroll
  for (int off = 32; off > 0; off >>= 1) x += __shfl_xor(x, off, 64);
  return x;
}
DEV float silu_f(float x) { return x / (1.f + __expf(-x)); }

DEV void gll16(const void* g, void* l) {
  __builtin_amdgcn_global_load_lds(
      (const __attribute__((address_space(1))) void*)g,
      (__attribute__((address_space(3))) void*)l, 16, 0, 0);
}

DEV void stage_tile(const u16* Ab, int lda, const u16* Wb, int ldw,
                    u16 (*As)[64], u16 (*Ws)[64], int wave, int lane, int k0) {
  const int lrow = lane >> 3;
  const int lcol = (lane & 7) * 8;
  const int rbase = wave * 32 + lrow;
#pragma unroll
  for (int c = 0; c < 4; ++c)
    gll16(Ab + (size_t)(rbase + c * 8) * lda + k0 + lcol, &As[rbase + c * 8][lcol]);
#pragma unroll
  for (int c = 0; c < 4; ++c)
    gll16(Wb + (size_t)(rbase + c * 8) * ldw + k0 + lcol, &Ws[rbase + c * 8][lcol]);
}

// ---------------------------------------------------------------------------
// GEMM v2: C[m,n] = sum_k A_bf16[m,k] * W_bf16[n,k]; all shapes padded, no
// guards. 128x128 tile, BK=64, 4 waves, double-buffered global_load_lds with
// counted vmcnt (2-phase pipeline). Optional fused residual epilogue:
// RX[m*1024+n] += gmods[b*6144+n] * (acc + bias[n]).
// ---------------------------------------------------------------------------
__global__ __launch_bounds__(256, 2) void gemm_bf_kernel(
    const u16* __restrict__ A, int lda,
    const u16* __restrict__ W, int ldw,
    float* __restrict__ C, int ldc,
    int Ksteps, int nbx,
    float* __restrict__ RX, const float* __restrict__ gmods,
    const float* __restrict__ bias)
{
  __shared__ alignas(16) u16 As[2][128][64];
  __shared__ alignas(16) u16 Ws[2][128][64];
  const int tid = threadIdx.x;
  const int lane = tid & 63;
  const int wave = tid >> 6;
  const int nwg = gridDim.x;
  const int cpx = nwg >> 3;
  const int fb = blockIdx.x;
  const int idx = (fb & 7) * cpx + (fb >> 3);
  const int m0 = (idx % nbx) * 128;
  const int n0 = (idx / nbx) * 128;
  const int wm = (wave >> 1) * 64;
  const int wn = (wave & 1) * 64;
  const int rl = lane & 15;
  const int kq = (lane >> 4) * 8;
  const u16* Abase = A + (size_t)m0 * lda;
  const u16* Wbase = W + (size_t)n0 * ldw;

  f32x4 acc[4][4];
#pragma unroll
  for (int i = 0; i < 4; ++i)
#pragma unroll
    for (int j = 0; j < 4; ++j) acc[i][j] = (f32x4){0.f, 0.f, 0.f, 0.f};

  stage_tile(Abase, lda, Wbase, ldw, As[0], Ws[0], wave, lane, 0);

  for (int kt = 0; kt < Ksteps; ++kt) {
    const int buf = kt & 1;
    if (kt + 1 < Ksteps) {
      stage_tile(Abase, lda, Wbase, ldw, As[buf ^ 1], Ws[buf ^ 1], wave, lane, (kt + 1) * 64);
      asm volatile("s_waitcnt vmcnt(8)" ::: "memory");
    } else {
      asm volatile("s_waitcnt vmcnt(0)" ::: "memory");
    }
    __builtin_amdgcn_s_barrier();
    __builtin_amdgcn_sched_barrier(0);
#pragma unroll
    for (int kk = 0; kk < 2; ++kk) {
      bf16x8 af[4], bw[4];
#pragma unroll
      for (int i = 0; i < 4; ++i)
        af[i] = *(const bf16x8*)&As[buf][wm + i * 16 + rl][kk * 32 + kq];
#pragma unroll
      for (int j = 0; j < 4; ++j)
        bw[j] = *(const bf16x8*)&Ws[buf][wn + j * 16 + rl][kk * 32 + kq];
#pragma unroll
      for (int i = 0; i < 4; ++i)
#pragma unroll
        for (int j = 0; j < 4; ++j)
          acc[i][j] = __builtin_amdgcn_mfma_f32_16x16x32_bf16(af[i], bw[j], acc[i][j], 0, 0, 0);
    }
    __builtin_amdgcn_sched_barrier(0);
    __builtin_amdgcn_s_barrier();
  }

  const int rq = (lane >> 4) * 4;
  if (RX) {
    const int b = m0 >> 8;
    const float* gm = gmods + (size_t)b * 6144;
#pragma unroll
    for (int j = 0; j < 4; ++j) {
      const int n = n0 + wn + j * 16 + rl;
      const float g = gm[n];
      const float bv = bias ? bias[n] : 0.f;
#pragma unroll
      for (int i = 0; i < 4; ++i) {
        const int mrow = m0 + wm + i * 16 + rq;
#pragma unroll
        for (int r = 0; r < 4; ++r) {
          float* p = RX + (size_t)(mrow + r) * 1024 + n;
          *p += g * (acc[i][j][r] + bv);
        }
      }
    }
  } else {
#pragma unroll
    for (int j = 0; j < 4; ++j) {
      const int n = n0 + wn + j * 16 + rl;
#pragma unroll
      for (int i = 0; i < 4; ++i) {
        const int mrow = m0 + wm + i * 16 + rq;
#pragma unroll
        for (int r = 0; r < 4; ++r)
          C[(size_t)(mrow + r) * ldc + n] = acc[i][j][r];
      }
    }
  }
}

// ---------------------------------------------------------------------------
// Legacy GEMM (fallback when workspace < 96MB): inline f32->bf16 W staging.
// ---------------------------------------------------------------------------
__global__ __launch_bounds__(256) void gemm_legacy_kernel(
    const u16* __restrict__ A, int lda,
    const float* __restrict__ W, int ldw,
    float* __restrict__ C, int ldc,
    int N, int Ksteps, int Kw, int nbx)
{
  __shared__ alignas(16) u16 As[128][72];
  __shared__ alignas(16) u16 Ws[128][72];
  const int tid = threadIdx.x;
  const int lane = tid & 63;
  const int wave = tid >> 6;
  const int wm = (wave >> 1) * 64;
  const int wn = (wave & 1) * 64;
  const int nwg = gridDim.x;
  const int cpx = nwg >> 3;
  const int f = blockIdx.x;
  const int idx = (f & 7) * cpx + (f >> 3);
  const int m0 = (idx % nbx) * 128;
  const int n0 = (idx / nbx) * 128;
  const int srow = tid >> 1;
  const int sseg = (tid & 1) * 32;
  const int rl = lane & 15;
  const int kq = (lane >> 4) * 8;

  f32x4 acc[4][4];
#pragma unroll
  for (int i = 0; i < 4; ++i)
#pragma unroll
    for (int j = 0; j < 4; ++j) acc[i][j] = (f32x4){0.f, 0.f, 0.f, 0.f};

  for (int kt = 0; kt < Ksteps; ++kt) {
    const int k0 = kt * 64;
    __syncthreads();
    {
      const u16* src = A + (size_t)(m0 + srow) * lda + k0 + sseg;
      uint4 v0 = *(const uint4*)(src + 0);
      uint4 v1 = *(const uint4*)(src + 8);
      uint4 v2 = *(const uint4*)(src + 16);
      uint4 v3 = *(const uint4*)(src + 24);
      *(uint4*)&As[srow][sseg + 0]  = v0;
      *(uint4*)&As[srow][sseg + 8]  = v1;
      *(uint4*)&As[srow][sseg + 16] = v2;
      *(uint4*)&As[srow][sseg + 24] = v3;
    }
    {
      const int n = n0 + srow;
      const int kbase = k0 + sseg;
      const float* src = W + (size_t)n * ldw + kbase;
      if (n < N && kbase + 32 <= Kw) {
#pragma unroll
        for (int g = 0; g < 4; ++g) {
          float4 a = *(const float4*)(src + g * 8);
          float4 b = *(const float4*)(src + g * 8 + 4);
          union { u16 u[8]; uint4 v; } p;
          p.u[0] = f2bf(a.x); p.u[1] = f2bf(a.y); p.u[2] = f2bf(a.z); p.u[3] = f2bf(a.w);
          p.u[4] = f2bf(b.x); p.u[5] = f2bf(b.y); p.u[6] = f2bf(b.z); p.u[7] = f2bf(b.w);
          *(uint4*)&Ws[srow][sseg + g * 8] = p.v;
        }
      } else {
#pragma unroll 4
        for (int g = 0; g < 32; ++g) {
          float v = (n < N && (kbase + g) < Kw) ? src[g] : 0.f;
          Ws[srow][sseg + g] = f2bf(v);
        }
      }
    }
    __syncthreads();
#pragma unroll
    for (int kk = 0; kk < 2; ++kk) {
      bf16x8 af[4], bfr[4];
#pragma unroll
      for (int i = 0; i < 4; ++i)
        af[i] = *(const bf16x8*)&As[wm + i * 16 + rl][kk * 32 + kq];
#pragma unroll
      for (int j = 0; j < 4; ++j)
        bfr[j] = *(const bf16x8*)&Ws[wn + j * 16 + rl][kk * 32 + kq];
#pragma unroll
      for (int i = 0; i < 4; ++i)
#pragma unroll
        for (int j = 0; j < 4; ++j)
          acc[i][j] = __builtin_amdgcn_mfma_f32_16x16x32_bf16(af[i], bfr[j], acc[i][j], 0, 0, 0);
    }
  }
  const int rq = (lane >> 4) * 4;
#pragma unroll
  for (int j = 0; j < 4; ++j) {
    const int n = n0 + wn + j * 16 + rl;
    if (n >= N) continue;
#pragma unroll
    for (int i = 0; i < 4; ++i) {
      const int mrow = m0 + wm + i * 16 + rq;
#pragma unroll
      for (int r = 0; r < 4; ++r)
        C[(size_t)(mrow + r) * ldc + n] = acc[i][j][r];
    }
  }
}

// ---------------------------------------------------------------------------
// Weight conversion: qkv | proj | w13 (w1 rows 0-2729, zeros, w3 rows 2752-5481,
// zeros) into bf16 WB. Separate kernel pads w2 [1024][2730]->[1024][2752].
// ---------------------------------------------------------------------------
__global__ __launch_bounds__(256) void convw_kernel(
    const float* __restrict__ qkvw, const float* __restrict__ projw,
    const float* __restrict__ w1, const float* __restrict__ w3,
    u16* __restrict__ WB)
{
  const int NQ = 3145728, NP = 1048576;
  const int TOT = 2457600;  // (NQ + NP + 5504*1024) / 4
  for (int g = blockIdx.x * 256 + threadIdx.x; g < TOT; g += gridDim.x * 256) {
    const int idx = g * 4;
    float4 v;
    if (idx < NQ) v = *(const float4*)(qkvw + idx);
    else if (idx < NQ + NP) v = *(const float4*)(projw + (idx - NQ));
    else {
      const int rel = idx - NQ - NP;
      const int r = rel >> 10;
      if (r < 2730) v = *(const float4*)(w1 + rel);
      else if (r < 2752) v = (float4){0.f, 0.f, 0.f, 0.f};
      else if (r < 5482) v = *(const float4*)(w3 + (rel - 2818048));
      else v = (float4){0.f, 0.f, 0.f, 0.f};
    }
    union { u16 u[4]; uint2 q; } p;
    p.u[0] = f2bf(v.x); p.u[1] = f2bf(v.y); p.u[2] = f2bf(v.z); p.u[3] = f2bf(v.w);
    *(uint2*)(WB + idx) = p.q;
  }
}

__global__ __launch_bounds__(256) void convw2_kernel(
    const float* __restrict__ w2, u16* __restrict__ WB2)
{
  const int r = blockIdx.x;
  const float* src = w2 + (size_t)r * 2730;
  u16* dst = WB2 + (size_t)r * 2752;
  for (int c = threadIdx.x * 4; c < 2752; c += 1024) {
    union { u16 u[4]; uint2 q; } p;
#pragma unroll
    for (int i = 0; i < 4; ++i) {
      const int cc = c + i;
      p.u[i] = (cc < 2730) ? f2bf(src[cc]) : (u16)0;
    }
    *(uint2*)(dst + c) = p.q;
  }
}

// ---------------------------------------------------------------------------
// Conditioning
// ---------------------------------------------------------------------------
__global__ __launch_bounds__(256) void cond_hc_kernel(
    const float* __restrict__ cfg_s, const float* __restrict__ w1,
    const float* __restrict__ b1, float* __restrict__ hc)
{
  const int b = blockIdx.x, c = threadIdx.x * 4;
  const float s = cfg_s[b];
  float4 w = *(const float4*)(w1 + c);
  float4 bb = *(const float4*)(b1 + c);
  float4 o;
  o.x = silu_f(s * w.x + bb.x);
  o.y = silu_f(s * w.y + bb.y);
  o.z = silu_f(s * w.z + bb.z);
  o.w = silu_f(s * w.w + bb.w);
  *(float4*)(hc + (size_t)b * 1024 + c) = o;
}

__global__ __launch_bounds__(64) void cond_sc_kernel(
    const float* __restrict__ hc, const float* __restrict__ w2,
    const float* __restrict__ b2, const float* __restrict__ ce,
    const int* __restrict__ y, float* __restrict__ sc)
{
  const int j = blockIdx.x, b = blockIdx.y, lane = threadIdx.x;
  const float4* wr = (const float4*)(w2 + (size_t)j * 1024);
  const float4* hr = (const float4*)(hc + (size_t)b * 1024);
  float acc = 0.f;
#pragma unroll
  for (int rep = 0; rep < 4; ++rep) {
    float4 w = wr[rep * 64 + lane];
    float4 h = hr[rep * 64 + lane];
    acc += w.x * h.x + w.y * h.y + w.z * h.z + w.w * h.w;
  }
  acc = waveAllSum(acc);
  if (lane == 0) {
    float v = ce[(size_t)y[b] * 1024 + j] + acc + b2[j];
    sc[(size_t)b * 1024 + j] = silu_f(v);
  }
}

__global__ __launch_bounds__(64) void modlin_kernel(
    const float* __restrict__ w, const float* __restrict__ bias,
    const float* __restrict__ sc, float* __restrict__ out, int ostride)
{
  const int j = blockIdx.x, lane = threadIdx.x;
  const float4* wr = (const float4*)(w + (size_t)j * 1024);
  float acc[8];
#pragma unroll
  for (int b = 0; b < 8; ++b) acc[b] = 0.f;
#pragma unroll
  for (int rep = 0; rep < 4; ++rep) {
    float4 wv = wr[rep * 64 + lane];
#pragma unroll
    for (int b = 0; b < 8; ++b) {
      float4 s = ((const float4*)(sc + (size_t)b * 1024))[rep * 64 + lane];
      acc[b] += wv.x * s.x + wv.y * s.y + wv.z * s.z + wv.w * s.w;
    }
  }
#pragma unroll
  for (int b = 0; b < 8; ++b) acc[b] = waveAllSum(acc[b]);
  if (lane == 0) {
    const float bb = bias[j];
#pragma unroll
    for (int b = 0; b < 8; ++b) out[(size_t)b * ostride + j] = acc[b] + bb;
  }
}

// ---------------------------------------------------------------------------
// Patch embed
// ---------------------------------------------------------------------------
__global__ __launch_bounds__(256) void patch_kernel(
    const float* __restrict__ x, const float* __restrict__ pw,
    const float* __restrict__ pb, const float* __restrict__ pos,
    float* __restrict__ xc)
{
  const int n = blockIdx.x, b = blockIdx.y, tid = threadIdx.x;
  __shared__ float pv[16];
  if (tid < 16) {
    const int ci = tid >> 2, pi = (tid >> 1) & 1, pj = tid & 1;
    const int i = n >> 4, j = n & 15;
    pv[tid] = x[((size_t)(b * 4 + ci) * 32 + i * 2 + pi) * 32 + j * 2 + pj];
  }
  __syncthreads();
#pragma unroll
  for (int qq = 0; qq < 4; ++qq) {
    const int c = qq * 256 + tid;
    const float4* wr = (const float4*)(pw + (size_t)c * 16);
    float acc = pb[c] + pos[(size_t)n * 1024 + c];
#pragma unroll
    for (int g = 0; g < 4; ++g) {
      float4 w = wr[g];
      acc += w.x * pv[g * 4] + w.y * pv[g * 4 + 1] + w.z * pv[g * 4 + 2] + w.w * pv[g * 4 + 3];
    }
    xc[((size_t)b * 256 + n) * 1024 + c] = acc;
  }
}

// ---------------------------------------------------------------------------
// RMSNorm + adaLN modulate -> bf16
// ---------------------------------------------------------------------------
__global__ __launch_bounds__(256) void normmod_kernel(
    const float* __restrict__ xc, const float* __restrict__ w,
    const float* __restrict__ mods, int mult_off, int shift_off, int mstride,
    u16* __restrict__ out)
{
  const int m = blockIdx.x, b = m >> 8, tid = threadIdx.x;
  const float* row = xc + (size_t)m * 1024;
  float4 v = *(const float4*)(row + tid * 4);
  float ss = v.x * v.x + v.y * v.y + v.z * v.z + v.w * v.w;
  ss = waveAllSum(ss);
  __shared__ float red[4];
  if ((tid & 63) == 0) red[tid >> 6] = ss;
  __syncthreads();
  const float tot = red[0] + red[1] + red[2] + red[3];
  const float r = rsqrtf(tot * (1.f / 1024.f) + 1e-6f);
  const float* mb = mods + (size_t)b * mstride;
  const int c = tid * 4;
  float4 wv = *(const float4*)(w + c);
  float4 mu = *(const float4*)(mb + mult_off + c);
  float4 sh = *(const float4*)(mb + shift_off + c);
  union { u16 u[4]; uint2 v2; } pk;
  pk.u[0] = f2bf(v.x * r * wv.x * (1.f + mu.x) + sh.x);
  pk.u[1] = f2bf(v.y * r * wv.y * (1.f + mu.y) + sh.y);
  pk.u[2] = f2bf(v.z * r * wv.z * (1.f + mu.z) + sh.z);
  pk.u[3] = f2bf(v.w * r * wv.w * (1.f + mu.w) + sh.w);
  *(uint2*)(out + (size_t)m * 1024 + c) = pk.v2;
}

// ---------------------------------------------------------------------------
// q/k RMSNorm + RoPE + v copy -> bf16 [bh, n, d]
// ---------------------------------------------------------------------------
__global__ __launch_bounds__(256) void rope_kernel(
    const float* __restrict__ qkv, const float* __restrict__ qnw,
    const float* __restrict__ knw, u16* __restrict__ qb,
    u16* __restrict__ kb, u16* __restrict__ vb)
{
  const int idx = blockIdx.x * 4 + (threadIdx.x >> 6);
  const int n = idx & 255;
  const int bh = idx >> 8;
  const int b = bh >> 4, h = bh & 15;
  const int d = threadIdx.x & 63;
  const size_t base = ((size_t)(b * 256 + n)) * 3072 + h * 64 + d;
  float qv = qkv[base];
  float kv = qkv[base + 1024];
  float vv = qkv[base + 2048];
  float qs = waveAllSum(qv * qv);
  float ks = waveAllSum(kv * kv);
  const float rq = rsqrtf(qs * (1.f / 64.f) + 1e-6f);
  const float rk = rsqrtf(ks * (1.f / 64.f) + 1e-6f);
  const float qn = qv * rq * qnw[d];
  const float kn = kv * rk * knw[d];
  const int i = d & 31;
  const float freq = __powf(10000.f, -(float)(2 * i) * (1.f / 64.f));
  const float ang = (float)n * freq;
  float sv, cv;
  sincosf(ang, &sv, &cv);
  const float qo = __shfl_xor(qn, 32, 64);
  const float ko = __shfl_xor(kn, 32, 64);
  const float rq2 = (d < 32) ? -qo : qo;
  const float rk2 = (d < 32) ? -ko : ko;
  const size_t ob = ((size_t)bh * 256 + n) * 64 + d;
  qb[ob] = f2bf(qn * cv + rq2 * sv);
  kb[ob] = f2bf(kn * cv + rk2 * sv);
  vb[ob] = f2bf(vv);
}

// ---------------------------------------------------------------------------
// MFMA attention (unchanged from round 1)
// ---------------------------------------------------------------------------
__global__ __launch_bounds__(256) void attn_kernel(
    const u16* __restrict__ qb, const u16* __restrict__ kb,
    const u16* __restrict__ vb, u16* __restrict__ o)
{
  __shared__ alignas(16) u16 Kt[128][72];
  __shared__ alignas(16) u16 Vtt[64][136];
  __shared__ alignas(16) u16 Pw[4][16][136];
  const int bh = blockIdx.x;
  const int qbase = blockIdx.y * 64;
  const int tid = threadIdx.x;
  const int lane = tid & 63;
  const int wave = tid >> 6;
  const int rl = lane & 15;
  const int kq = (lane >> 4) * 8;
  const int rowg = (lane >> 4) * 4;

  const int q0 = qbase + wave * 16;
  const u16* qsrc = qb + ((size_t)bh * 256 + q0 + rl) * 64 + kq;
  const bf16x8 a0 = *(const bf16x8*)(qsrc);
  const bf16x8 a1 = *(const bf16x8*)(qsrc + 32);

  float m[4], l[4];
  f32x4 oacc[4];
#pragma unroll
  for (int r = 0; r < 4; ++r) { m[r] = -1e30f; l[r] = 0.f; }
#pragma unroll
  for (int dt = 0; dt < 4; ++dt) oacc[dt] = (f32x4){0.f, 0.f, 0.f, 0.f};

  for (int kt = 0; kt < 2; ++kt) {
    __syncthreads();
#pragma unroll
    for (int c = 0; c < 4; ++c) {
      const int flat = c * 256 + tid;
      const int row = flat >> 3;
      const int col = (flat & 7) * 8;
      uint4 v = *(const uint4*)(kb + ((size_t)bh * 256 + kt * 128 + row) * 64 + col);
      *(uint4*)&Kt[row][col] = v;
    }
    {
      const int tt = tid & 63;
      const int dh = tid >> 6;
      const int r0 = tt * 2;
      const u16* s0 = vb + ((size_t)bh * 256 + kt * 128 + r0) * 64 + dh * 16;
      const u16* s1 = s0 + 64;
#pragma unroll
      for (int g = 0; g < 2; ++g) {
        uint4 A = *(const uint4*)(s0 + g * 8);
        uint4 B = *(const uint4*)(s1 + g * 8);
        const u32 aw[4] = {A.x, A.y, A.z, A.w};
        const u32 bw[4] = {B.x, B.y, B.z, B.w};
#pragma unroll
        for (int q = 0; q < 4; ++q) {
          const int d2 = dh * 16 + g * 8 + q * 2;
          const u32 lo = (aw[q] & 0xffffu) | (bw[q] << 16);
          const u32 hi = (aw[q] >> 16) | (bw[q] & 0xffff0000u);
          *(u32*)&Vtt[d2][r0] = lo;
          *(u32*)&Vtt[d2 + 1][r0] = hi;
        }
      }
    }
    __syncthreads();

    f32x4 sacc[8];
#pragma unroll
    for (int t = 0; t < 8; ++t) sacc[t] = (f32x4){0.f, 0.f, 0.f, 0.f};
#pragma unroll
    for (int t = 0; t < 8; ++t) {
      bf16x8 k0 = *(const bf16x8*)&Kt[t * 16 + rl][kq];
      bf16x8 k1 = *(const bf16x8*)&Kt[t * 16 + rl][32 + kq];
      sacc[t] = __builtin_amdgcn_mfma_f32_16x16x32_bf16(a0, k0, sacc[t], 0, 0, 0);
      sacc[t] = __builtin_amdgcn_mfma_f32_16x16x32_bf16(a1, k1, sacc[t], 0, 0, 0);
    }
    float cmax[4];
#pragma unroll
    for (int r = 0; r < 4; ++r) cmax[r] = sacc[0][r];
#pragma unroll
    for (int t = 1; t < 8; ++t)
#pragma unroll
      for (int r = 0; r < 4; ++r) cmax[r] = fmaxf(cmax[r], sacc[t][r]);
#pragma unroll
    for (int off = 1; off < 16; off <<= 1)
#pragma unroll
      for (int r = 0; r < 4; ++r) cmax[r] = fmaxf(cmax[r], __shfl_xor(cmax[r], off, 64));
#pragma unroll
    for (int r = 0; r < 4; ++r) {
      const float mn = fmaxf(m[r], cmax[r]);
      const float corr = __expf((m[r] - mn) * 0.125f);
      l[r] *= corr;
#pragma unroll
      for (int dt = 0; dt < 4; ++dt) oacc[dt][r] *= corr;
      m[r] = mn;
    }
    float lsum[4] = {0.f, 0.f, 0.f, 0.f};
#pragma unroll
    for (int t = 0; t < 8; ++t)
#pragma unroll
      for (int r = 0; r < 4; ++r) {
        const float p = __expf((sacc[t][r] - m[r]) * 0.125f);
        lsum[r] += p;
        Pw[wave][rowg + r][t * 16 + rl] = f2bf(p);
      }
#pragma unroll
    for (int off = 1; off < 16; off <<= 1)
#pragma unroll
      for (int r = 0; r < 4; ++r) lsum[r] += __shfl_xor(lsum[r], off, 64);
#pragma unroll
    for (int r = 0; r < 4; ++r) l[r] += lsum[r];
#pragma unroll
    for (int ks = 0; ks < 4; ++ks) {
      bf16x8 pa = *(const bf16x8*)&Pw[wave][rl][ks * 32 + kq];
#pragma unroll
      for (int dt = 0; dt < 4; ++dt) {
        bf16x8 vf = *(const bf16x8*)&Vtt[dt * 16 + rl][ks * 32 + kq];
        oacc[dt] = __builtin_amdgcn_mfma_f32_16x16x32_bf16(pa, vf, oacc[dt], 0, 0, 0);
      }
    }
  }
  const int b = bh >> 4, h = bh & 15;
#pragma unroll
  for (int r = 0; r < 4; ++r) {
    const float inv = 1.f / l[r];
    const int qrow = q0 + rowg + r;
    u16* dst = o + (((size_t)b * 256 + qrow) * 16 + h) * 64 + rl;
#pragma unroll
    for (int dt = 0; dt < 4; ++dt)
      dst[dt * 16] = f2bf(oacc[dt][r] * inv);
  }
}

// ---------------------------------------------------------------------------
// Residual (legacy path only)
// ---------------------------------------------------------------------------
__global__ __launch_bounds__(256) void resid_kernel(
    float* __restrict__ xc, const float* __restrict__ gout,
    const float* __restrict__ bias, const float* __restrict__ mods,
    int g_off, int mstride)
{
  const int m = blockIdx.x, b = m >> 8;
  const int c = threadIdx.x * 4;
  float4 xv = *(float4*)(xc + (size_t)m * 1024 + c);
  float4 gv = *(const float4*)(gout + (size_t)m * 1024 + c);
  float4 mg = *(const float4*)(mods + (size_t)b * mstride + g_off + c);
  float bx = 0.f, by = 0.f, bz = 0.f, bw = 0.f;
  if (bias) {
    float4 bb = *(const float4*)(bias + c);
    bx = bb.x; by = bb.y; bz = bb.z; bw = bb.w;
  }
  xv.x += mg.x * (gv.x + bx);
  xv.y += mg.y * (gv.y + by);
  xv.z += mg.z * (gv.z + bz);
  xv.w += mg.w * (gv.w + bw);
  *(float4*)(xc + (size_t)m * 1024 + c) = xv;
}

// ---------------------------------------------------------------------------
// SwiGLU (a,b pointers + row stride): h1 = bf16(silu(a) * b)
// ---------------------------------------------------------------------------
__global__ __launch_bounds__(256) void swiglu_kernel(
    const float* __restrict__ a, const float* __restrict__ b,
    int stride, u16* __restrict__ h1)
{
  const int m = blockIdx.x;
  const size_t ra = (size_t)m * stride;
  const size_t rh = (size_t)m * 2752;
  for (int j0 = threadIdx.x * 4; j0 < 2752; j0 += 1024) {
    float4 av4 = *(const float4*)(a + ra + j0);
    float4 bv4 = *(const float4*)(b + ra + j0);
    float av[4] = {av4.x, av4.y, av4.z, av4.w};
    float bv[4] = {bv4.x, bv4.y, bv4.z, bv4.w};
    union { u16 u[4]; uint2 v; } pk;
#pragma unroll
    for (int i = 0; i < 4; ++i) {
      float val = 0.f;
      if (j0 + i < 2730) val = silu_f(av[i]) * bv[i];
      pk.u[i] = f2bf(val);
    }
    *(uint2*)(h1 + rh + j0) = pk.v;
  }
}

// ---------------------------------------------------------------------------
// Final LayerNorm + modulate -> bf16
// ---------------------------------------------------------------------------
__global__ __launch_bounds__(256) void lnmod_kernel(
    const float* __restrict__ xc, const float* __restrict__ fmods,
    u16* __restrict__ out)
{
  const int m = blockIdx.x, b = m >> 8, tid = threadIdx.x;
  const float* row = xc + (size_t)m * 1024;
  float4 v = *(const float4*)(row + tid * 4);
  float s1 = v.x + v.y + v.z + v.w;
  float s2 = v.x * v.x + v.y * v.y + v.z * v.z + v.w * v.w;
  s1 = waveAllSum(s1);
  s2 = waveAllSum(s2);
  __shared__ float r1[4], r2[4];
  if ((tid & 63) == 0) { r1[tid >> 6] = s1; r2[tid >> 6] = s2; }
  __syncthreads();
  const float t1 = r1[0] + r1[1] + r1[2] + r1[3];
  const float t2 = r2[0] + r2[1] + r2[2] + r2[3];
  const float mean = t1 * (1.f / 1024.f);
  const float var = t2 * (1.f / 1024.f) - mean * mean;
  const float rr = rsqrtf(var + 1e-5f);
  const float* mb = fmods + (size_t)b * 2048;
  const int c = tid * 4;
  float4 sh = *(const float4*)(mb + c);
  float4 sl = *(const float4*)(mb + 1024 + c);
  union { u16 u[4]; uint2 v2; } pk;
  pk.u[0] = f2bf((v.x - mean) * rr * (1.f + sl.x) + sh.x);
  pk.u[1] = f2bf((v.y - mean) * rr * (1.f + sl.y) + sh.y);
  pk.u[2] = f2bf((v.z - mean) * rr * (1.f + sl.z) + sh.z);
  pk.u[3] = f2bf((v.w - mean) * rr * (1.f + sl.w) + sh.w);
  *(uint2*)(out + (size_t)m * 1024 + c) = pk.v2;
}

// ---------------------------------------------------------------------------
// Final linear (16 outputs) + unpatchify
// ---------------------------------------------------------------------------
__global__ __launch_bounds__(256) void final_kernel(
    const u16* __restrict__ xfin, const float* __restrict__ w,
    const float* __restrict__ bias, float* __restrict__ out)
{
  const int tid = threadIdx.x;
  const int m = blockIdx.x * 16 + (tid >> 4);
  const int j = tid & 15;
  const u16* xr = xfin + (size_t)m * 1024;
  const float* wr = w + (size_t)j * 1024;
  float acc = 0.f;
  for (int k = 0; k < 1024; k += 8) {
    uint4 xv = *(const uint4*)(xr + k);
    const u16* xu = (const u16*)&xv;
    float4 w0 = *(const float4*)(wr + k);
    float4 w1 = *(const float4*)(wr + k + 4);
    acc += bf2f(xu[0]) * w0.x + bf2f(xu[1]) * w0.y + bf2f(xu[2]) * w0.z + bf2f(xu[3]) * w0.w;
    acc += bf2f(xu[4]) * w1.x + bf2f(xu[5]) * w1.y + bf2f(xu[6]) * w1.z + bf2f(xu[7]) * w1.w;
  }
  acc += bias[j];
  const int b = m >> 8, n = m & 255;
  const int i = n >> 4, jj = n & 15;
  const int pi = (j >> 3) & 1, pj = (j >> 2) & 1, oc = j & 3;
  out[((size_t)(b * 4 + oc) * 32 + i * 2 + pi) * 32 + jj * 2 + pj] = acc;
}

// ---------------------------------------------------------------------------
extern "C" void kernel_launch(void* const* d_in, const int* in_sizes, int n_in,
                              void* d_out, int out_size, void* d_ws, size_t ws_size,
                              hipStream_t stream) {
  const float* x       = (const float*)d_in[0];
  const int*   y       = (const int*)  d_in[1];
  const float* cfg_s   = (const float*)d_in[2];
  const float* patch_w = (const float*)d_in[3];
  const float* patch_b = (const float*)d_in[4];
  const float* pos_e   = (const float*)d_in[5];
  const float* class_e = (const float*)d_in[6];
  const float* cfg_w1  = (const float*)d_in[7];
  const float* cfg_b1  = (const float*)d_in[8];
  const float* cfg_w2  = (const float*)d_in[9];
  const float* cfg_b2  = (const float*)d_in[10];
  const float* n1w     = (const float*)d_in[11];
  const float* n2w     = (const float*)d_in[12];
  const float* qkvw    = (const float*)d_in[13];
  const float* projw   = (const float*)d_in[14];
  const float* projb   = (const float*)d_in[15];
  const float* qnw     = (const float*)d_in[16];
  const float* knw     = (const float*)d_in[17];
  const float* w1      = (const float*)d_in[18];
  const float* w2      = (const float*)d_in[19];
  const float* w3      = (const float*)d_in[20];
  const float* adaw    = (const float*)d_in[21];
  const float* adab    = (const float*)d_in[22];
  const float* finaw   = (const float*)d_in[23];
  const float* finab   = (const float*)d_in[24];
  const float* flw     = (const float*)d_in[25];
  const float* flb     = (const float*)d_in[26];
  (void)in_sizes; (void)n_in; (void)out_size;

  char* ws = (char*)d_ws;
  const size_t MB = 1024 * 1024;
  float* hc    = (float*)(ws);
  float* sc    = (float*)(ws + 32 * 1024);
  float* mods  = (float*)(ws + 64 * 1024);             // 4*8*6144 f32 = 768KB
  float* fmods = (float*)(ws + 64 * 1024 + 786432);    // 8*2048 f32
  float* xc    = (float*)(ws + 1 * MB);                // 8MB
  u16*   xm    = (u16*)  (ws + 9 * MB);                // 4MB (normmod out / attn out)
  float* zone  = (float*)(ws + 13 * MB);               // 45MB: qkv f32 / h1ab f32
  u16*   qbuf  = (u16*)  (ws + 58 * MB);               // 4MB
  u16*   kbuf  = (u16*)  (ws + 62 * MB);               // 4MB
  u16*   vbuf  = (u16*)  (ws + 66 * MB);               // 4MB
  u16*   h1    = (u16*)  (ws + 58 * MB);               // 11.3MB (q/k/v dead)
  u16*   WB    = (u16*)  (ws + 70 * MB);               // 25.3MB bf16 weights
  const bool pre = ws_size >= 96 * MB;
  if (ws_size < 73 * MB) return;

  cond_hc_kernel<<<8, 256, 0, stream>>>(cfg_s, cfg_w1, cfg_b1, hc);
  cond_sc_kernel<<<dim3(1024, 8), 64, 0, stream>>>(hc, cfg_w2, cfg_b2, class_e, y, sc);
  for (int d = 0; d < 4; ++d)
    modlin_kernel<<<6144, 64, 0, stream>>>(adaw + (size_t)d * 6144 * 1024,
                                           adab + (size_t)d * 6144, sc,
                                           mods + (size_t)d * 8 * 6144, 6144);
  modlin_kernel<<<2048, 64, 0, stream>>>(finaw, finab, sc, fmods, 2048);
  patch_kernel<<<dim3(256, 8), 256, 0, stream>>>(x, patch_w, patch_b, pos_e, xc);

  if (pre) {
    for (int d = 0; d < 4; ++d) {
      const float* md = mods + (size_t)d * 8 * 6144;
      convw_kernel<<<9600, 256, 0, stream>>>(qkvw + (size_t)d * 3145728,
                                             projw + (size_t)d * 1048576,
                                             w1 + (size_t)d * 2795520,
                                             w3 + (size_t)d * 2795520, WB);
      convw2_kernel<<<1024, 256, 0, stream>>>(w2 + (size_t)d * 2795520, WB + 9830400);
      normmod_kernel<<<2048, 256, 0, stream>>>(xc, n1w + d * 1024, md, 1024, 0, 6144, xm);
      gemm_bf_kernel<<<384, 256, 0, stream>>>(xm, 1024, WB, 1024, zone, 3072, 16, 16,
                                              nullptr, nullptr, nullptr);
      rope_kernel<<<8192, 256, 0, stream>>>(zone, qnw + d * 64, knw + d * 64, qbuf, kbuf, vbuf);
      attn_kernel<<<dim3(128, 4), 256, 0, stream>>>(qbuf, kbuf, vbuf, xm);
      gemm_bf_kernel<<<128, 256, 0, stream>>>(xm, 1024, WB + 3145728, 1024, nullptr, 0, 16, 16,
                                              xc, md + 2048, projb + d * 1024);
      normmod_kernel<<<2048, 256, 0, stream>>>(xc, n2w + d * 1024, md, 4096, 3072, 6144, xm);
      gemm_bf_kernel<<<688, 256, 0, stream>>>(xm, 1024, WB + 4194304, 1024, zone, 5504, 16, 16,
                                              nullptr, nullptr, nullptr);
      swiglu_kernel<<<2048, 256, 0, stream>>>(zone, zone + 2752, 5504, h1);
      gemm_bf_kernel<<<128, 256, 0, stream>>>(h1, 2752, WB + 9830400, 2752, nullptr, 0, 43, 16,
                                              xc, md + 5120, nullptr);
    }
  } else {
    float* zone2 = zone + (size_t)2048 * 2752;  // second half of zone
    for (int d = 0; d < 4; ++d) {
      const float* md = mods + (size_t)d * 8 * 6144;
      normmod_kernel<<<2048, 256, 0, stream>>>(xc, n1w + d * 1024, md, 1024, 0, 6144, xm);
      gemm_legacy_kernel<<<384, 256, 0, stream>>>(xm, 1024, qkvw + (size_t)d * 3145728, 1024,
                                                  zone, 3072, 3072, 16, 1024, 16);
      rope_kernel<<<8192, 256, 0, stream>>>(zone, qnw + d * 64, knw + d * 64, qbuf, kbuf, vbuf);
      attn_kernel<<<dim3(128, 4), 256, 0, stream>>>(qbuf, kbuf, vbuf, xm);
      gemm_legacy_kernel<<<128, 256, 0, stream>>>(xm, 1024, projw + (size_t)d * 1048576, 1024,
                                                  zone, 1024, 1024, 16, 1024, 16);
      resid_kernel<<<2048, 256, 0, stream>>>(xc, zone, projb + d * 1024, md, 2048, 6144);
      normmod_kernel<<<2048, 256, 0, stream>>>(xc, n2w + d * 1024, md, 4096, 3072, 6144, xm);
      gemm_legacy_kernel<<<352, 256, 0, stream>>>(xm, 1024, w1 + (size_t)d * 2795520, 1024,
                                                  zone, 2752, 2730, 16, 1024, 16);
      gemm_legacy_kernel<<<352, 256, 0, stream>>>(xm, 1024, w3 + (size_t)d * 2795520, 1024,
                                                  zone2, 2752, 2730, 16, 1024, 16);
      swiglu_kernel<<<2048, 256, 0, stream>>>(zone, zone2, 2752, h1);
      gemm_legacy_kernel<<<128, 256, 0, stream>>>(h1, 2752, w2 + (size_t)d * 2795520, 2730,
                                                  zone, 1024, 1024, 43, 2730, 16);
      resid_kernel<<<2048, 256, 0, stream>>>(xc, zone, nullptr, md, 5120, 6144);
    }
  }

  lnmod_kernel<<<2048, 256, 0, stream>>>(xc, fmods, xm);
  final_kernel<<<128, 256, 0, stream>>>(xm, flw, flb, (float*)d_out);
}

// Round 4
// 839.838 us; speedup vs baseline: 2.8792x; 1.2241x over previous
//
#include <hip/hip_runtime.h>

typedef unsigned short u16;
typedef unsigned int u32;
typedef float f32x4 __attribute__((ext_vector_type(4)));
typedef __bf16 bf16x8 __attribute__((ext_vector_type(8)));

#define DEV __device__ __forceinline__

DEV u16 f2bf(float f) {
  u32 u = __builtin_bit_cast(u32, f);
  u += 0x7fffu + ((u >> 16) & 1u);
  return (u16)(u >> 16);
}
DEV float bf2f(u16 u) { return __builtin_bit_cast(float, (u32)u << 16); }
DEV float waveAllSum(float x) {
#pragma unroll
  for (int off = 32; off > 0; off >>= 1) x += __shfl_xor(x, off, 64);
  return x;
}
DEV float silu_f(float x) { return x / (1.f + __expf(-x)); }

DEV void gll16(const void* g, void* l) {
  __builtin_amdgcn_global_load_lds(
      (const __attribute__((address_space(1))) void*)g,
      (__attribute__((address_space(3))) void*)l, 16, 0, 0);
}

// Stage one BK=64 K-slab of A (BM rows) and W (128 rows) into linear LDS.
// Global source col is XOR-swizzled by (row&7) at 16B granularity so that the
// (linear-dest) LDS image is the swizzled layout; readers apply the same XOR.
template<int BM>
DEV void stage_tile(const u16* Ab, int lda, const u16* Wb, int ldw,
                    u16 (*As)[64], u16 (*Ws)[64], int wave, int lane, int k0) {
  const int lrow = lane >> 3;
  const int lcolD = (lane & 7) * 8;
  const int lcolS = ((lane & 7) ^ lrow) * 8;  // row&7 == lrow for all staged rows
  const int rba = wave * (BM / 4) + lrow;
#pragma unroll
  for (int c = 0; c < BM / 32; ++c)
    gll16(Ab + (size_t)(rba + c * 8) * lda + k0 + lcolS, &As[rba + c * 8][lcolD]);
  const int rbw = wave * 32 + lrow;
#pragma unroll
  for (int c = 0; c < 4; ++c)
    gll16(Wb + (size_t)(rbw + c * 8) * ldw + k0 + lcolS, &Ws[rbw + c * 8][lcolD]);
}

// ---------------------------------------------------------------------------
// GEMM: C[m,n] = sum_k A_bf16[m,k] * W_bf16[n,k]; padded shapes, no guards.
// BM x 128 tile, BK=64, 4 waves, double-buffered global_load_lds, counted
// vmcnt. T2 XOR-swizzle via pre-swizzled global source (rule #21).
// Optional fused residual: RX[m*1024+n] += gmods[b*6144+n]*(acc+bias[n]).
// ---------------------------------------------------------------------------
template<int BM>
__global__ __launch_bounds__(256, (BM == 128 ? 2 : 3)) void gemm_t(
    const u16* __restrict__ A, int lda,
    const u16* __restrict__ W, int ldw,
    float* __restrict__ C, int ldc,
    int Ksteps, int nbx,
    float* __restrict__ RX, const float* __restrict__ gmods,
    const float* __restrict__ bias)
{
  constexpr int MI = BM / 32;   // 16-row acc tiles per wave (m dir)
  __shared__ alignas(16) u16 As[2][BM][64];
  __shared__ alignas(16) u16 Ws[2][128][64];
  const int tid = threadIdx.x;
  const int lane = tid & 63;
  const int wave = tid >> 6;
  const int nwg = gridDim.x;
  const int cpx = nwg >> 3;
  const int fb = blockIdx.x;
  const int idx = (fb & 7) * cpx + (fb >> 3);
  const int m0 = (idx % nbx) * BM;
  const int n0 = (idx / nbx) * 128;
  const int wm = (wave >> 1) * (BM / 2);
  const int wn = (wave & 1) * 64;
  const int rl = lane & 15;
  const int swz = rl & 7;
  const u16* Abase = A + (size_t)m0 * lda;
  const u16* Wbase = W + (size_t)n0 * ldw;

  f32x4 acc[MI][4];
#pragma unroll
  for (int i = 0; i < MI; ++i)
#pragma unroll
    for (int j = 0; j < 4; ++j) acc[i][j] = (f32x4){0.f, 0.f, 0.f, 0.f};

  stage_tile<BM>(Abase, lda, Wbase, ldw, As[0], Ws[0], wave, lane, 0);

  for (int kt = 0; kt < Ksteps; ++kt) {
    const int buf = kt & 1;
    if (kt + 1 < Ksteps) {
      stage_tile<BM>(Abase, lda, Wbase, ldw, As[buf ^ 1], Ws[buf ^ 1], wave, lane, (kt + 1) * 64);
      if constexpr (BM == 128)
        asm volatile("s_waitcnt vmcnt(8)" ::: "memory");
      else
        asm volatile("s_waitcnt vmcnt(6)" ::: "memory");
    } else {
      asm volatile("s_waitcnt vmcnt(0)" ::: "memory");
    }
    __builtin_amdgcn_s_barrier();
    __builtin_amdgcn_sched_barrier(0);
#pragma unroll
    for (int kk = 0; kk < 2; ++kk) {
      const int cs = ((kk * 4 + (lane >> 4)) ^ swz) * 8;  // swizzled u16 col
      bf16x8 af[MI], bw[4];
#pragma unroll
      for (int i = 0; i < MI; ++i)
        af[i] = *(const bf16x8*)&As[buf][wm + i * 16 + rl][cs];
#pragma unroll
      for (int j = 0; j < 4; ++j)
        bw[j] = *(const bf16x8*)&Ws[buf][wn + j * 16 + rl][cs];
#pragma unroll
      for (int i = 0; i < MI; ++i)
#pragma unroll
        for (int j = 0; j < 4; ++j)
          acc[i][j] = __builtin_amdgcn_mfma_f32_16x16x32_bf16(af[i], bw[j], acc[i][j], 0, 0, 0);
    }
    __builtin_amdgcn_sched_barrier(0);
    __builtin_amdgcn_s_barrier();
  }

  const int rq = (lane >> 4) * 4;
  if (RX) {
    const int b = m0 >> 8;
    const float* gm = gmods + (size_t)b * 6144;
#pragma unroll
    for (int j = 0; j < 4; ++j) {
      const int n = n0 + wn + j * 16 + rl;
      const float g = gm[n];
      const float bv = bias ? bias[n] : 0.f;
#pragma unroll
      for (int i = 0; i < MI; ++i) {
        const int mrow = m0 + wm + i * 16 + rq;
#pragma unroll
        for (int r = 0; r < 4; ++r) {
          float* p = RX + (size_t)(mrow + r) * 1024 + n;
          *p += g * (acc[i][j][r] + bv);
        }
      }
    }
  } else {
#pragma unroll
    for (int j = 0; j < 4; ++j) {
      const int n = n0 + wn + j * 16 + rl;
#pragma unroll
      for (int i = 0; i < MI; ++i) {
        const int mrow = m0 + wm + i * 16 + rq;
#pragma unroll
        for (int r = 0; r < 4; ++r)
          C[(size_t)(mrow + r) * ldc + n] = acc[i][j][r];
      }
    }
  }
}

// ---------------------------------------------------------------------------
// Legacy GEMM (fallback when workspace < 96MB): inline f32->bf16 W staging.
// ---------------------------------------------------------------------------
__global__ __launch_bounds__(256) void gemm_legacy_kernel(
    const u16* __restrict__ A, int lda,
    const float* __restrict__ W, int ldw,
    float* __restrict__ C, int ldc,
    int N, int Ksteps, int Kw, int nbx)
{
  __shared__ alignas(16) u16 As[128][72];
  __shared__ alignas(16) u16 Ws[128][72];
  const int tid = threadIdx.x;
  const int lane = tid & 63;
  const int wave = tid >> 6;
  const int wm = (wave >> 1) * 64;
  const int wn = (wave & 1) * 64;
  const int nwg = gridDim.x;
  const int cpx = nwg >> 3;
  const int f = blockIdx.x;
  const int idx = (f & 7) * cpx + (f >> 3);
  const int m0 = (idx % nbx) * 128;
  const int n0 = (idx / nbx) * 128;
  const int srow = tid >> 1;
  const int sseg = (tid & 1) * 32;
  const int rl = lane & 15;
  const int kq = (lane >> 4) * 8;

  f32x4 acc[4][4];
#pragma unroll
  for (int i = 0; i < 4; ++i)
#pragma unroll
    for (int j = 0; j < 4; ++j) acc[i][j] = (f32x4){0.f, 0.f, 0.f, 0.f};

  for (int kt = 0; kt < Ksteps; ++kt) {
    const int k0 = kt * 64;
    __syncthreads();
    {
      const u16* src = A + (size_t)(m0 + srow) * lda + k0 + sseg;
      uint4 v0 = *(const uint4*)(src + 0);
      uint4 v1 = *(const uint4*)(src + 8);
      uint4 v2 = *(const uint4*)(src + 16);
      uint4 v3 = *(const uint4*)(src + 24);
      *(uint4*)&As[srow][sseg + 0]  = v0;
      *(uint4*)&As[srow][sseg + 8]  = v1;
      *(uint4*)&As[srow][sseg + 16] = v2;
      *(uint4*)&As[srow][sseg + 24] = v3;
    }
    {
      const int n = n0 + srow;
      const int kbase = k0 + sseg;
      const float* src = W + (size_t)n * ldw + kbase;
      if (n < N && kbase + 32 <= Kw) {
#pragma unroll
        for (int g = 0; g < 4; ++g) {
          float4 a = *(const float4*)(src + g * 8);
          float4 b = *(const float4*)(src + g * 8 + 4);
          union { u16 u[8]; uint4 v; } p;
          p.u[0] = f2bf(a.x); p.u[1] = f2bf(a.y); p.u[2] = f2bf(a.z); p.u[3] = f2bf(a.w);
          p.u[4] = f2bf(b.x); p.u[5] = f2bf(b.y); p.u[6] = f2bf(b.z); p.u[7] = f2bf(b.w);
          *(uint4*)&Ws[srow][sseg + g * 8] = p.v;
        }
      } else {
#pragma unroll 4
        for (int g = 0; g < 32; ++g) {
          float v = (n < N && (kbase + g) < Kw) ? src[g] : 0.f;
          Ws[srow][sseg + g] = f2bf(v);
        }
      }
    }
    __syncthreads();
#pragma unroll
    for (int kk = 0; kk < 2; ++kk) {
      bf16x8 af[4], bfr[4];
#pragma unroll
      for (int i = 0; i < 4; ++i)
        af[i] = *(const bf16x8*)&As[wm + i * 16 + rl][kk * 32 + kq];
#pragma unroll
      for (int j = 0; j < 4; ++j)
        bfr[j] = *(const bf16x8*)&Ws[wn + j * 16 + rl][kk * 32 + kq];
#pragma unroll
      for (int i = 0; i < 4; ++i)
#pragma unroll
        for (int j = 0; j < 4; ++j)
          acc[i][j] = __builtin_amdgcn_mfma_f32_16x16x32_bf16(af[i], bfr[j], acc[i][j], 0, 0, 0);
    }
  }
  const int rq = (lane >> 4) * 4;
#pragma unroll
  for (int j = 0; j < 4; ++j) {
    const int n = n0 + wn + j * 16 + rl;
    if (n >= N) continue;
#pragma unroll
    for (int i = 0; i < 4; ++i) {
      const int mrow = m0 + wm + i * 16 + rq;
#pragma unroll
      for (int r = 0; r < 4; ++r)
        C[(size_t)(mrow + r) * ldc + n] = acc[i][j][r];
    }
  }
}

// ---------------------------------------------------------------------------
// Weight conversion: qkv | proj | w13 (w1 rows 0-2729, zeros, w3 rows
// 2752-5481, zeros) into bf16 WB; convw2 pads w2 [1024][2730]->[1024][2752].
// ---------------------------------------------------------------------------
__global__ __launch_bounds__(256) void convw_kernel(
    const float* __restrict__ qkvw, const float* __restrict__ projw,
    const float* __restrict__ w1, const float* __restrict__ w3,
    u16* __restrict__ WB)
{
  const int NQ = 3145728, NP = 1048576;
  const int TOT = 2457600;
  for (int g = blockIdx.x * 256 + threadIdx.x; g < TOT; g += gridDim.x * 256) {
    const int idx = g * 4;
    float4 v;
    if (idx < NQ) v = *(const float4*)(qkvw + idx);
    else if (idx < NQ + NP) v = *(const float4*)(projw + (idx - NQ));
    else {
      const int rel = idx - NQ - NP;
      const int r = rel >> 10;
      if (r < 2730) v = *(const float4*)(w1 + rel);
      else if (r < 2752) v = (float4){0.f, 0.f, 0.f, 0.f};
      else if (r < 5482) v = *(const float4*)(w3 + (rel - 2818048));
      else v = (float4){0.f, 0.f, 0.f, 0.f};
    }
    union { u16 u[4]; uint2 q; } p;
    p.u[0] = f2bf(v.x); p.u[1] = f2bf(v.y); p.u[2] = f2bf(v.z); p.u[3] = f2bf(v.w);
    *(uint2*)(WB + idx) = p.q;
  }
}

__global__ __launch_bounds__(256) void convw2_kernel(
    const float* __restrict__ w2, u16* __restrict__ WB2)
{
  const int r = blockIdx.x;
  const float* src = w2 + (size_t)r * 2730;
  u16* dst = WB2 + (size_t)r * 2752;
  for (int c = threadIdx.x * 4; c < 2752; c += 1024) {
    union { u16 u[4]; uint2 q; } p;
#pragma unroll
    for (int i = 0; i < 4; ++i) {
      const int cc = c + i;
      p.u[i] = (cc < 2730) ? f2bf(src[cc]) : (u16)0;
    }
    *(uint2*)(dst + c) = p.q;
  }
}

// ---------------------------------------------------------------------------
// Conditioning
// ---------------------------------------------------------------------------
__global__ __launch_bounds__(256) void cond_hc_kernel(
    const float* __restrict__ cfg_s, const float* __restrict__ w1,
    const float* __restrict__ b1, float* __restrict__ hc)
{
  const int b = blockIdx.x, c = threadIdx.x * 4;
  const float s = cfg_s[b];
  float4 w = *(const float4*)(w1 + c);
  float4 bb = *(const float4*)(b1 + c);
  float4 o;
  o.x = silu_f(s * w.x + bb.x);
  o.y = silu_f(s * w.y + bb.y);
  o.z = silu_f(s * w.z + bb.z);
  o.w = silu_f(s * w.w + bb.w);
  *(float4*)(hc + (size_t)b * 1024 + c) = o;
}

__global__ __launch_bounds__(64) void cond_sc_kernel(
    const float* __restrict__ hc, const float* __restrict__ w2,
    const float* __restrict__ b2, const float* __restrict__ ce,
    const int* __restrict__ y, float* __restrict__ sc)
{
  const int j = blockIdx.x, b = blockIdx.y, lane = threadIdx.x;
  const float4* wr = (const float4*)(w2 + (size_t)j * 1024);
  const float4* hr = (const float4*)(hc + (size_t)b * 1024);
  float acc = 0.f;
#pragma unroll
  for (int rep = 0; rep < 4; ++rep) {
    float4 w = wr[rep * 64 + lane];
    float4 h = hr[rep * 64 + lane];
    acc += w.x * h.x + w.y * h.y + w.z * h.z + w.w * h.w;
  }
  acc = waveAllSum(acc);
  if (lane == 0) {
    float v = ce[(size_t)y[b] * 1024 + j] + acc + b2[j];
    sc[(size_t)b * 1024 + j] = silu_f(v);
  }
}

__global__ __launch_bounds__(64) void modlin_kernel(
    const float* __restrict__ w, const float* __restrict__ bias,
    const float* __restrict__ sc, float* __restrict__ out, int ostride)
{
  const int j = blockIdx.x, lane = threadIdx.x;
  const float4* wr = (const float4*)(w + (size_t)j * 1024);
  float acc[8];
#pragma unroll
  for (int b = 0; b < 8; ++b) acc[b] = 0.f;
#pragma unroll
  for (int rep = 0; rep < 4; ++rep) {
    float4 wv = wr[rep * 64 + lane];
#pragma unroll
    for (int b = 0; b < 8; ++b) {
      float4 s = ((const float4*)(sc + (size_t)b * 1024))[rep * 64 + lane];
      acc[b] += wv.x * s.x + wv.y * s.y + wv.z * s.z + wv.w * s.w;
    }
  }
#pragma unroll
  for (int b = 0; b < 8; ++b) acc[b] = waveAllSum(acc[b]);
  if (lane == 0) {
    const float bb = bias[j];
#pragma unroll
    for (int b = 0; b < 8; ++b) out[(size_t)b * ostride + j] = acc[b] + bb;
  }
}

// ---------------------------------------------------------------------------
// Patch embed
// ---------------------------------------------------------------------------
__global__ __launch_bounds__(256) void patch_kernel(
    const float* __restrict__ x, const float* __restrict__ pw,
    const float* __restrict__ pb, const float* __restrict__ pos,
    float* __restrict__ xc)
{
  const int n = blockIdx.x, b = blockIdx.y, tid = threadIdx.x;
  __shared__ float pv[16];
  if (tid < 16) {
    const int ci = tid >> 2, pi = (tid >> 1) & 1, pj = tid & 1;
    const int i = n >> 4, j = n & 15;
    pv[tid] = x[((size_t)(b * 4 + ci) * 32 + i * 2 + pi) * 32 + j * 2 + pj];
  }
  __syncthreads();
#pragma unroll
  for (int qq = 0; qq < 4; ++qq) {
    const int c = qq * 256 + tid;
    const float4* wr = (const float4*)(pw + (size_t)c * 16);
    float acc = pb[c] + pos[(size_t)n * 1024 + c];
#pragma unroll
    for (int g = 0; g < 4; ++g) {
      float4 w = wr[g];
      acc += w.x * pv[g * 4] + w.y * pv[g * 4 + 1] + w.z * pv[g * 4 + 2] + w.w * pv[g * 4 + 3];
    }
    xc[((size_t)b * 256 + n) * 1024 + c] = acc;
  }
}

// ---------------------------------------------------------------------------
// RMSNorm + adaLN modulate -> bf16
// ---------------------------------------------------------------------------
__global__ __launch_bounds__(256) void normmod_kernel(
    const float* __restrict__ xc, const float* __restrict__ w,
    const float* __restrict__ mods, int mult_off, int shift_off, int mstride,
    u16* __restrict__ out)
{
  const int m = blockIdx.x, b = m >> 8, tid = threadIdx.x;
  const float* row = xc + (size_t)m * 1024;
  float4 v = *(const float4*)(row + tid * 4);
  float ss = v.x * v.x + v.y * v.y + v.z * v.z + v.w * v.w;
  ss = waveAllSum(ss);
  __shared__ float red[4];
  if ((tid & 63) == 0) red[tid >> 6] = ss;
  __syncthreads();
  const float tot = red[0] + red[1] + red[2] + red[3];
  const float r = rsqrtf(tot * (1.f / 1024.f) + 1e-6f);
  const float* mb = mods + (size_t)b * mstride;
  const int c = tid * 4;
  float4 wv = *(const float4*)(w + c);
  float4 mu = *(const float4*)(mb + mult_off + c);
  float4 sh = *(const float4*)(mb + shift_off + c);
  union { u16 u[4]; uint2 v2; } pk;
  pk.u[0] = f2bf(v.x * r * wv.x * (1.f + mu.x) + sh.x);
  pk.u[1] = f2bf(v.y * r * wv.y * (1.f + mu.y) + sh.y);
  pk.u[2] = f2bf(v.z * r * wv.z * (1.f + mu.z) + sh.z);
  pk.u[3] = f2bf(v.w * r * wv.w * (1.f + mu.w) + sh.w);
  *(uint2*)(out + (size_t)m * 1024 + c) = pk.v2;
}

// ---------------------------------------------------------------------------
// q/k RMSNorm + RoPE + v copy -> bf16 [bh, n, d]
// ---------------------------------------------------------------------------
__global__ __launch_bounds__(256) void rope_kernel(
    const float* __restrict__ qkv, const float* __restrict__ qnw,
    const float* __restrict__ knw, u16* __restrict__ qb,
    u16* __restrict__ kb, u16* __restrict__ vb)
{
  const int idx = blockIdx.x * 4 + (threadIdx.x >> 6);
  const int n = idx & 255;
  const int bh = idx >> 8;
  const int b = bh >> 4, h = bh & 15;
  const int d = threadIdx.x & 63;
  const size_t base = ((size_t)(b * 256 + n)) * 3072 + h * 64 + d;
  float qv = qkv[base];
  float kv = qkv[base + 1024];
  float vv = qkv[base + 2048];
  float qs = waveAllSum(qv * qv);
  float ks = waveAllSum(kv * kv);
  const float rq = rsqrtf(qs * (1.f / 64.f) + 1e-6f);
  const float rk = rsqrtf(ks * (1.f / 64.f) + 1e-6f);
  const float qn = qv * rq * qnw[d];
  const float kn = kv * rk * knw[d];
  const int i = d & 31;
  const float freq = __powf(10000.f, -(float)(2 * i) * (1.f / 64.f));
  const float ang = (float)n * freq;
  float sv, cv;
  sincosf(ang, &sv, &cv);
  const float qo = __shfl_xor(qn, 32, 64);
  const float ko = __shfl_xor(kn, 32, 64);
  const float rq2 = (d < 32) ? -qo : qo;
  const float rk2 = (d < 32) ? -ko : ko;
  const size_t ob = ((size_t)bh * 256 + n) * 64 + d;
  qb[ob] = f2bf(qn * cv + rq2 * sv);
  kb[ob] = f2bf(kn * cv + rk2 * sv);
  vb[ob] = f2bf(vv);
}

// ---------------------------------------------------------------------------
// MFMA attention
// ---------------------------------------------------------------------------
__global__ __launch_bounds__(256) void attn_kernel(
    const u16* __restrict__ qb, const u16* __restrict__ kb,
    const u16* __restrict__ vb, u16* __restrict__ o)
{
  __shared__ alignas(16) u16 Kt[128][72];
  __shared__ alignas(16) u16 Vtt[64][136];
  __shared__ alignas(16) u16 Pw[4][16][136];
  const int bh = blockIdx.x;
  const int qbase = blockIdx.y * 64;
  const int tid = threadIdx.x;
  const int lane = tid & 63;
  const int wave = tid >> 6;
  const int rl = lane & 15;
  const int kq = (lane >> 4) * 8;
  const int rowg = (lane >> 4) * 4;

  const int q0 = qbase + wave * 16;
  const u16* qsrc = qb + ((size_t)bh * 256 + q0 + rl) * 64 + kq;
  const bf16x8 a0 = *(const bf16x8*)(qsrc);
  const bf16x8 a1 = *(const bf16x8*)(qsrc + 32);

  float m[4], l[4];
  f32x4 oacc[4];
#pragma unroll
  for (int r = 0; r < 4; ++r) { m[r] = -1e30f; l[r] = 0.f; }
#pragma unroll
  for (int dt = 0; dt < 4; ++dt) oacc[dt] = (f32x4){0.f, 0.f, 0.f, 0.f};

  for (int kt = 0; kt < 2; ++kt) {
    __syncthreads();
#pragma unroll
    for (int c = 0; c < 4; ++c) {
      const int flat = c * 256 + tid;
      const int row = flat >> 3;
      const int col = (flat & 7) * 8;
      uint4 v = *(const uint4*)(kb + ((size_t)bh * 256 + kt * 128 + row) * 64 + col);
      *(uint4*)&Kt[row][col] = v;
    }
    {
      const int tt = tid & 63;
      const int dh = tid >> 6;
      const int r0 = tt * 2;
      const u16* s0 = vb + ((size_t)bh * 256 + kt * 128 + r0) * 64 + dh * 16;
      const u16* s1 = s0 + 64;
#pragma unroll
      for (int g = 0; g < 2; ++g) {
        uint4 A = *(const uint4*)(s0 + g * 8);
        uint4 B = *(const uint4*)(s1 + g * 8);
        const u32 aw[4] = {A.x, A.y, A.z, A.w};
        const u32 bw[4] = {B.x, B.y, B.z, B.w};
#pragma unroll
        for (int q = 0; q < 4; ++q) {
          const int d2 = dh * 16 + g * 8 + q * 2;
          const u32 lo = (aw[q] & 0xffffu) | (bw[q] << 16);
          const u32 hi = (aw[q] >> 16) | (bw[q] & 0xffff0000u);
          *(u32*)&Vtt[d2][r0] = lo;
          *(u32*)&Vtt[d2 + 1][r0] = hi;
        }
      }
    }
    __syncthreads();

    f32x4 sacc[8];
#pragma unroll
    for (int t = 0; t < 8; ++t) sacc[t] = (f32x4){0.f, 0.f, 0.f, 0.f};
#pragma unroll
    for (int t = 0; t < 8; ++t) {
      bf16x8 k0 = *(const bf16x8*)&Kt[t * 16 + rl][kq];
      bf16x8 k1 = *(const bf16x8*)&Kt[t * 16 + rl][32 + kq];
      sacc[t] = __builtin_amdgcn_mfma_f32_16x16x32_bf16(a0, k0, sacc[t], 0, 0, 0);
      sacc[t] = __builtin_amdgcn_mfma_f32_16x16x32_bf16(a1, k1, sacc[t], 0, 0, 0);
    }
    float cmax[4];
#pragma unroll
    for (int r = 0; r < 4; ++r) cmax[r] = sacc[0][r];
#pragma unroll
    for (int t = 1; t < 8; ++t)
#pragma unroll
      for (int r = 0; r < 4; ++r) cmax[r] = fmaxf(cmax[r], sacc[t][r]);
#pragma unroll
    for (int off = 1; off < 16; off <<= 1)
#pragma unroll
      for (int r = 0; r < 4; ++r) cmax[r] = fmaxf(cmax[r], __shfl_xor(cmax[r], off, 64));
#pragma unroll
    for (int r = 0; r < 4; ++r) {
      const float mn = fmaxf(m[r], cmax[r]);
      const float corr = __expf((m[r] - mn) * 0.125f);
      l[r] *= corr;
#pragma unroll
      for (int dt = 0; dt < 4; ++dt) oacc[dt][r] *= corr;
      m[r] = mn;
    }
    float lsum[4] = {0.f, 0.f, 0.f, 0.f};
#pragma unroll
    for (int t = 0; t < 8; ++t)
#pragma unroll
      for (int r = 0; r < 4; ++r) {
        const float p = __expf((sacc[t][r] - m[r]) * 0.125f);
        lsum[r] += p;
        Pw[wave][rowg + r][t * 16 + rl] = f2bf(p);
      }
#pragma unroll
    for (int off = 1; off < 16; off <<= 1)
#pragma unroll
      for (int r = 0; r < 4; ++r) lsum[r] += __shfl_xor(lsum[r], off, 64);
#pragma unroll
    for (int r = 0; r < 4; ++r) l[r] += lsum[r];
#pragma unroll
    for (int ks = 0; ks < 4; ++ks) {
      bf16x8 pa = *(const bf16x8*)&Pw[wave][rl][ks * 32 + kq];
#pragma unroll
      for (int dt = 0; dt < 4; ++dt) {
        bf16x8 vf = *(const bf16x8*)&Vtt[dt * 16 + rl][ks * 32 + kq];
        oacc[dt] = __builtin_amdgcn_mfma_f32_16x16x32_bf16(pa, vf, oacc[dt], 0, 0, 0);
      }
    }
  }
  const int b = bh >> 4, h = bh & 15;
#pragma unroll
  for (int r = 0; r < 4; ++r) {
    const float inv = 1.f / l[r];
    const int qrow = q0 + rowg + r;
    u16* dst = o + (((size_t)b * 256 + qrow) * 16 + h) * 64 + rl;
#pragma unroll
    for (int dt = 0; dt < 4; ++dt)
      dst[dt * 16] = f2bf(oacc[dt][r] * inv);
  }
}

// ---------------------------------------------------------------------------
// Residual (legacy path only)
// ---------------------------------------------------------------------------
__global__ __launch_bounds__(256) void resid_kernel(
    float* __restrict__ xc, const float* __restrict__ gout,
    const float* __restrict__ bias, const float* __restrict__ mods,
    int g_off, int mstride)
{
  const int m = blockIdx.x, b = m >> 8;
  const int c = threadIdx.x * 4;
  float4 xv = *(float4*)(xc + (size_t)m * 1024 + c);
  float4 gv = *(const float4*)(gout + (size_t)m * 1024 + c);
  float4 mg = *(const float4*)(mods + (size_t)b * mstride + g_off + c);
  float bx = 0.f, by = 0.f, bz = 0.f, bw = 0.f;
  if (bias) {
    float4 bb = *(const float4*)(bias + c);
    bx = bb.x; by = bb.y; bz = bb.z; bw = bb.w;
  }
  xv.x += mg.x * (gv.x + bx);
  xv.y += mg.y * (gv.y + by);
  xv.z += mg.z * (gv.z + bz);
  xv.w += mg.w * (gv.w + bw);
  *(float4*)(xc + (size_t)m * 1024 + c) = xv;
}

// ---------------------------------------------------------------------------
// SwiGLU: h1 = bf16(silu(a) * b)
// ---------------------------------------------------------------------------
__global__ __launch_bounds__(256) void swiglu_kernel(
    const float* __restrict__ a, const float* __restrict__ b,
    int stride, u16* __restrict__ h1)
{
  const int m = blockIdx.x;
  const size_t ra = (size_t)m * stride;
  const size_t rh = (size_t)m * 2752;
  for (int j0 = threadIdx.x * 4; j0 < 2752; j0 += 1024) {
    float4 av4 = *(const float4*)(a + ra + j0);
    float4 bv4 = *(const float4*)(b + ra + j0);
    float av[4] = {av4.x, av4.y, av4.z, av4.w};
    float bv[4] = {bv4.x, bv4.y, bv4.z, bv4.w};
    union { u16 u[4]; uint2 v; } pk;
#pragma unroll
    for (int i = 0; i < 4; ++i) {
      float val = 0.f;
      if (j0 + i < 2730) val = silu_f(av[i]) * bv[i];
      pk.u[i] = f2bf(val);
    }
    *(uint2*)(h1 + rh + j0) = pk.v;
  }
}

// ---------------------------------------------------------------------------
// Final LayerNorm + modulate -> bf16
// ---------------------------------------------------------------------------
__global__ __launch_bounds__(256) void lnmod_kernel(
    const float* __restrict__ xc, const float* __restrict__ fmods,
    u16* __restrict__ out)
{
  const int m = blockIdx.x, b = m >> 8, tid = threadIdx.x;
  const float* row = xc + (size_t)m * 1024;
  float4 v = *(const float4*)(row + tid * 4);
  float s1 = v.x + v.y + v.z + v.w;
  float s2 = v.x * v.x + v.y * v.y + v.z * v.z + v.w * v.w;
  s1 = waveAllSum(s1);
  s2 = waveAllSum(s2);
  __shared__ float r1[4], r2[4];
  if ((tid & 63) == 0) { r1[tid >> 6] = s1; r2[tid >> 6] = s2; }
  __syncthreads();
  const float t1 = r1[0] + r1[1] + r1[2] + r1[3];
  const float t2 = r2[0] + r2[1] + r2[2] + r2[3];
  const float mean = t1 * (1.f / 1024.f);
  const float var = t2 * (1.f / 1024.f) - mean * mean;
  const float rr = rsqrtf(var + 1e-5f);
  const float* mb = fmods + (size_t)b * 2048;
  const int c = tid * 4;
  float4 sh = *(const float4*)(mb + c);
  float4 sl = *(const float4*)(mb + 1024 + c);
  union { u16 u[4]; uint2 v2; } pk;
  pk.u[0] = f2bf((v.x - mean) * rr * (1.f + sl.x) + sh.x);
  pk.u[1] = f2bf((v.y - mean) * rr * (1.f + sl.y) + sh.y);
  pk.u[2] = f2bf((v.z - mean) * rr * (1.f + sl.z) + sh.z);
  pk.u[3] = f2bf((v.w - mean) * rr * (1.f + sl.w) + sh.w);
  *(uint2*)(out + (size_t)m * 1024 + c) = pk.v2;
}

// ---------------------------------------------------------------------------
// Final linear (16 outputs) + unpatchify
// ---------------------------------------------------------------------------
__global__ __launch_bounds__(256) void final_kernel(
    const u16* __restrict__ xfin, const float* __restrict__ w,
    const float* __restrict__ bias, float* __restrict__ out)
{
  const int tid = threadIdx.x;
  const int m = blockIdx.x * 16 + (tid >> 4);
  const int j = tid & 15;
  const u16* xr = xfin + (size_t)m * 1024;
  const float* wr = w + (size_t)j * 1024;
  float acc = 0.f;
  for (int k = 0; k < 1024; k += 8) {
    uint4 xv = *(const uint4*)(xr + k);
    const u16* xu = (const u16*)&xv;
    float4 w0 = *(const float4*)(wr + k);
    float4 w1 = *(const float4*)(wr + k + 4);
    acc += bf2f(xu[0]) * w0.x + bf2f(xu[1]) * w0.y + bf2f(xu[2]) * w0.z + bf2f(xu[3]) * w0.w;
    acc += bf2f(xu[4]) * w1.x + bf2f(xu[5]) * w1.y + bf2f(xu[6]) * w1.z + bf2f(xu[7]) * w1.w;
  }
  acc += bias[j];
  const int b = m >> 8, n = m & 255;
  const int i = n >> 4, jj = n & 15;
  const int pi = (j >> 3) & 1, pj = (j >> 2) & 1, oc = j & 3;
  out[((size_t)(b * 4 + oc) * 32 + i * 2 + pi) * 32 + jj * 2 + pj] = acc;
}

// ---------------------------------------------------------------------------
extern "C" void kernel_launch(void* const* d_in, const int* in_sizes, int n_in,
                              void* d_out, int out_size, void* d_ws, size_t ws_size,
                              hipStream_t stream) {
  const float* x       = (const float*)d_in[0];
  const int*   y       = (const int*)  d_in[1];
  const float* cfg_s   = (const float*)d_in[2];
  const float* patch_w = (const float*)d_in[3];
  const float* patch_b = (const float*)d_in[4];
  const float* pos_e   = (const float*)d_in[5];
  const float* class_e = (const float*)d_in[6];
  const float* cfg_w1  = (const float*)d_in[7];
  const float* cfg_b1  = (const float*)d_in[8];
  const float* cfg_w2  = (const float*)d_in[9];
  const float* cfg_b2  = (const float*)d_in[10];
  const float* n1w     = (const float*)d_in[11];
  const float* n2w     = (const float*)d_in[12];
  const float* qkvw    = (const float*)d_in[13];
  const float* projw   = (const float*)d_in[14];
  const float* projb   = (const float*)d_in[15];
  const float* qnw     = (const float*)d_in[16];
  const float* knw     = (const float*)d_in[17];
  const float* w1      = (const float*)d_in[18];
  const float* w2      = (const float*)d_in[19];
  const float* w3      = (const float*)d_in[20];
  const float* adaw    = (const float*)d_in[21];
  const float* adab    = (const float*)d_in[22];
  const float* finaw   = (const float*)d_in[23];
  const float* finab   = (const float*)d_in[24];
  const float* flw     = (const float*)d_in[25];
  const float* flb     = (const float*)d_in[26];
  (void)in_sizes; (void)n_in; (void)out_size;

  char* ws = (char*)d_ws;
  const size_t MB = 1024 * 1024;
  float* hc    = (float*)(ws);
  float* sc    = (float*)(ws + 32 * 1024);
  float* mods  = (float*)(ws + 64 * 1024);             // 4*8*6144 f32 = 768KB
  float* fmods = (float*)(ws + 64 * 1024 + 786432);    // 8*2048 f32
  float* xc    = (float*)(ws + 1 * MB);                // 8MB
  u16*   xm    = (u16*)  (ws + 9 * MB);                // 4MB (normmod out / attn out)
  float* zone  = (float*)(ws + 13 * MB);               // 45MB: qkv f32 / h1ab f32
  u16*   qbuf  = (u16*)  (ws + 58 * MB);               // 4MB
  u16*   kbuf  = (u16*)  (ws + 62 * MB);               // 4MB
  u16*   vbuf  = (u16*)  (ws + 66 * MB);               // 4MB
  u16*   h1    = (u16*)  (ws + 58 * MB);               // 11.3MB (q/k/v dead)
  u16*   WB    = (u16*)  (ws + 70 * MB);               // 25.3MB bf16 weights
  const bool pre = ws_size >= 96 * MB;
  if (ws_size < 73 * MB) return;

  cond_hc_kernel<<<8, 256, 0, stream>>>(cfg_s, cfg_w1, cfg_b1, hc);
  cond_sc_kernel<<<dim3(1024, 8), 64, 0, stream>>>(hc, cfg_w2, cfg_b2, class_e, y, sc);
  for (int d = 0; d < 4; ++d)
    modlin_kernel<<<6144, 64, 0, stream>>>(adaw + (size_t)d * 6144 * 1024,
                                           adab + (size_t)d * 6144, sc,
                                           mods + (size_t)d * 8 * 6144, 6144);
  modlin_kernel<<<2048, 64, 0, stream>>>(finaw, finab, sc, fmods, 2048);
  patch_kernel<<<dim3(256, 8), 256, 0, stream>>>(x, patch_w, patch_b, pos_e, xc);

  if (pre) {
    for (int d = 0; d < 4; ++d) {
      const float* md = mods + (size_t)d * 8 * 6144;
      convw_kernel<<<9600, 256, 0, stream>>>(qkvw + (size_t)d * 3145728,
                                             projw + (size_t)d * 1048576,
                                             w1 + (size_t)d * 2795520,
                                             w3 + (size_t)d * 2795520, WB);
      convw2_kernel<<<1024, 256, 0, stream>>>(w2 + (size_t)d * 2795520, WB + 9830400);
      normmod_kernel<<<2048, 256, 0, stream>>>(xc, n1w + d * 1024, md, 1024, 0, 6144, xm);
      gemm_t<64><<<768, 256, 0, stream>>>(xm, 1024, WB, 1024, zone, 3072, 16, 32,
                                          nullptr, nullptr, nullptr);
      rope_kernel<<<8192, 256, 0, stream>>>(zone, qnw + d * 64, knw + d * 64, qbuf, kbuf, vbuf);
      attn_kernel<<<dim3(128, 4), 256, 0, stream>>>(qbuf, kbuf, vbuf, xm);
      gemm_t<64><<<256, 256, 0, stream>>>(xm, 1024, WB + 3145728, 1024, nullptr, 0, 16, 32,
                                          xc, md + 2048, projb + d * 1024);
      normmod_kernel<<<2048, 256, 0, stream>>>(xc, n2w + d * 1024, md, 4096, 3072, 6144, xm);
      gemm_t<128><<<688, 256, 0, stream>>>(xm, 1024, WB + 4194304, 1024, zone, 5504, 16, 16,
                                           nullptr, nullptr, nullptr);
      swiglu_kernel<<<2048, 256, 0, stream>>>(zone, zone + 2752, 5504, h1);
      gemm_t<64><<<256, 256, 0, stream>>>(h1, 2752, WB + 9830400, 2752, nullptr, 0, 43, 32,
                                          xc, md + 5120, nullptr);
    }
  } else {
    float* zone2 = zone + (size_t)2048 * 2752;
    for (int d = 0; d < 4; ++d) {
      const float* md = mods + (size_t)d * 8 * 6144;
      normmod_kernel<<<2048, 256, 0, stream>>>(xc, n1w + d * 1024, md, 1024, 0, 6144, xm);
      gemm_legacy_kernel<<<384, 256, 0, stream>>>(xm, 1024, qkvw + (size_t)d * 3145728, 1024,
                                                  zone, 3072, 3072, 16, 1024, 16);
      rope_kernel<<<8192, 256, 0, stream>>>(zone, qnw + d * 64, knw + d * 64, qbuf, kbuf, vbuf);
      attn_kernel<<<dim3(128, 4), 256, 0, stream>>>(qbuf, kbuf, vbuf, xm);
      gemm_legacy_kernel<<<128, 256, 0, stream>>>(xm, 1024, projw + (size_t)d * 1048576, 1024,
                                                  zone, 1024, 1024, 16, 1024, 16);
      resid_kernel<<<2048, 256, 0, stream>>>(xc, zone, projb + d * 1024, md, 2048, 6144);
      normmod_kernel<<<2048, 256, 0, stream>>>(xc, n2w + d * 1024, md, 4096, 3072, 6144, xm);
      gemm_legacy_kernel<<<352, 256, 0, stream>>>(xm, 1024, w1 + (size_t)d * 2795520, 1024,
                                                  zone, 2752, 2730, 16, 1024, 16);
      gemm_legacy_kernel<<<352, 256, 0, stream>>>(xm, 1024, w3 + (size_t)d * 2795520, 1024,
                                                  zone2, 2752, 2730, 16, 1024, 16);
      swiglu_kernel<<<2048, 256, 0, stream>>>(zone, zone2, 2752, h1);
      gemm_legacy_kernel<<<128, 256, 0, stream>>>(h1, 2752, w2 + (size_t)d * 2795520, 2730,
                                                  zone, 1024, 1024, 43, 2730, 16);
      resid_kernel<<<2048, 256, 0, stream>>>(xc, zone, nullptr, md, 5120, 6144);
    }
  }

  lnmod_kernel<<<2048, 256, 0, stream>>>(xc, fmods, xm);
  final_kernel<<<128, 256, 0, stream>>>(xm, flw, flb, (float*)d_out);
}

// Round 5
// 790.869 us; speedup vs baseline: 3.0574x; 1.0619x over previous
//
#include <hip/hip_runtime.h>

typedef unsigned short u16;
typedef unsigned int u32;
typedef float f32x4 __attribute__((ext_vector_type(4)));
typedef __bf16 bf16x8 __attribute__((ext_vector_type(8)));

#define DEV __device__ __forceinline__

DEV u16 f2bf(float f) {
  u32 u = __builtin_bit_cast(u32, f);
  u += 0x7fffu + ((u >> 16) & 1u);
  return (u16)(u >> 16);
}
DEV float bf2f(u16 u) { return __builtin_bit_cast(float, (u32)u << 16); }
DEV float waveAllSum(float x) {
#pragma unroll
  for (int off = 32; off > 0; off >>= 1) x += __shfl_xor(x, off, 64);
  return x;
}
DEV float silu_f(float x) { return x / (1.f + __expf(-x)); }

DEV void gll16(const void* g, void* l) {
  __builtin_amdgcn_global_load_lds(
      (const __attribute__((address_space(1))) void*)g,
      (__attribute__((address_space(3))) void*)l, 16, 0, 0);
}

// Stage one BK=64 K-slab of A (BM rows) and W (128 rows) into linear LDS.
// Global source col XOR-swizzled by (row&7) at 16B granularity (rule #21).
template<int BM>
DEV void stage_tile(const u16* Ab, int lda, const u16* Wb, int ldw,
                    u16 (*As)[64], u16 (*Ws)[64], int wave, int lane, int k0) {
  const int lrow = lane >> 3;
  const int lcolD = (lane & 7) * 8;
  const int lcolS = ((lane & 7) ^ lrow) * 8;
  const int rba = wave * (BM / 4) + lrow;
#pragma unroll
  for (int c = 0; c < BM / 32; ++c)
    gll16(Ab + (size_t)(rba + c * 8) * lda + k0 + lcolS, &As[rba + c * 8][lcolD]);
  const int rbw = wave * 32 + lrow;
#pragma unroll
  for (int c = 0; c < 4; ++c)
    gll16(Wb + (size_t)(rbw + c * 8) * ldw + k0 + lcolS, &Ws[rbw + c * 8][lcolD]);
}

// ---------------------------------------------------------------------------
// GEMM: out = A_bf16[m,k] * W_bf16[n,k]^T; padded shapes, no guards.
// BM x 128 tile, BK=64, 4 waves, dbuf global_load_lds, counted vmcnt, T2
// swizzle. EPI: 1 = residual RX += gm*(acc+bias); 2 = qk-RMSNorm+RoPE+v
// scatter to q/k/v bf16; 3 = SwiGLU pair-fuse -> h1 bf16 (w1/w3 interleaved
// in 16-unit groups).
// ---------------------------------------------------------------------------
template<int BM, int EPI>
__global__ __launch_bounds__(256, (BM == 128 ? 2 : 3)) void gemm_t(
    const u16* __restrict__ A, int lda,
    const u16* __restrict__ W, int ldw,
    int Ksteps, int nbx,
    float* __restrict__ RX, const float* __restrict__ gmods,
    const float* __restrict__ bias,
    u16* __restrict__ ob0, u16* __restrict__ ob1, u16* __restrict__ ob2,
    const float* __restrict__ nw_q, const float* __restrict__ nw_k)
{
  constexpr int MI = BM / 32;
  __shared__ alignas(16) u16 As[2][BM][64];
  __shared__ alignas(16) u16 Ws[2][128][64];
  const int tid = threadIdx.x;
  const int lane = tid & 63;
  const int wave = tid >> 6;
  const int nwg = gridDim.x;
  const int cpx = nwg >> 3;
  const int fb = blockIdx.x;
  const int idx = (fb & 7) * cpx + (fb >> 3);
  const int m0 = (idx % nbx) * BM;
  const int n0 = (idx / nbx) * 128;
  const int wm = (wave >> 1) * (BM / 2);
  const int wn = (wave & 1) * 64;
  const int rl = lane & 15;
  const int swz = rl & 7;
  const u16* Abase = A + (size_t)m0 * lda;
  const u16* Wbase = W + (size_t)n0 * ldw;

  f32x4 acc[MI][4];
#pragma unroll
  for (int i = 0; i < MI; ++i)
#pragma unroll
    for (int j = 0; j < 4; ++j) acc[i][j] = (f32x4){0.f, 0.f, 0.f, 0.f};

  stage_tile<BM>(Abase, lda, Wbase, ldw, As[0], Ws[0], wave, lane, 0);

  for (int kt = 0; kt < Ksteps; ++kt) {
    const int buf = kt & 1;
    if (kt + 1 < Ksteps) {
      stage_tile<BM>(Abase, lda, Wbase, ldw, As[buf ^ 1], Ws[buf ^ 1], wave, lane, (kt + 1) * 64);
      if constexpr (BM == 128)
        asm volatile("s_waitcnt vmcnt(8)" ::: "memory");
      else
        asm volatile("s_waitcnt vmcnt(6)" ::: "memory");
    } else {
      asm volatile("s_waitcnt vmcnt(0)" ::: "memory");
    }
    __builtin_amdgcn_s_barrier();
    __builtin_amdgcn_sched_barrier(0);
#pragma unroll
    for (int kk = 0; kk < 2; ++kk) {
      const int cs = ((kk * 4 + (lane >> 4)) ^ swz) * 8;
      bf16x8 af[MI], bw[4];
#pragma unroll
      for (int i = 0; i < MI; ++i)
        af[i] = *(const bf16x8*)&As[buf][wm + i * 16 + rl][cs];
#pragma unroll
      for (int j = 0; j < 4; ++j)
        bw[j] = *(const bf16x8*)&Ws[buf][wn + j * 16 + rl][cs];
#pragma unroll
      for (int i = 0; i < MI; ++i)
#pragma unroll
        for (int j = 0; j < 4; ++j)
          acc[i][j] = __builtin_amdgcn_mfma_f32_16x16x32_bf16(af[i], bw[j], acc[i][j], 0, 0, 0);
    }
    __builtin_amdgcn_sched_barrier(0);
    __builtin_amdgcn_s_barrier();
  }

  const int rq = (lane >> 4) * 4;
  if constexpr (EPI == 1) {
    const int b = m0 >> 8;
    const float* gm = gmods + (size_t)b * 6144;
#pragma unroll
    for (int j = 0; j < 4; ++j) {
      const int n = n0 + wn + j * 16 + rl;
      const float g = gm[n];
      const float bv = bias ? bias[n] : 0.f;
#pragma unroll
      for (int i = 0; i < MI; ++i) {
        const int mrow = m0 + wm + i * 16 + rq;
#pragma unroll
        for (int r = 0; r < 4; ++r) {
          float* p = RX + (size_t)(mrow + r) * 1024 + n;
          *p += g * (acc[i][j][r] + bv);
        }
      }
    }
  } else if constexpr (EPI == 2) {
    // wave tile = one head (64 cols); region by n0: 0=q,1=k,2=v
    const int region = n0 >> 10;
    const int h = ((n0 + wn) >> 6) & 15;
    const int bh = (m0 >> 8) * 16 + h;
    if (region == 2) {
#pragma unroll
      for (int i = 0; i < MI; ++i)
#pragma unroll
        for (int r = 0; r < 4; ++r) {
          const int token = (m0 + wm + i * 16 + rq + r) & 255;
          u16* dst = ob2 + ((size_t)bh * 256 + token) * 64 + rl;
#pragma unroll
          for (int j = 0; j < 4; ++j) dst[j * 16] = f2bf(acc[i][j][r]);
        }
    } else {
      const float* nw = region ? nw_k : nw_q;
      u16* obuf = region ? ob1 : ob0;
      float wv[4];
#pragma unroll
      for (int j = 0; j < 4; ++j) wv[j] = nw[j * 16 + rl];
      const float f0 = __powf(10000.f, -(float)(2 * rl) * (1.f / 64.f));
      const float f1 = __powf(10000.f, -(float)(2 * (16 + rl)) * (1.f / 64.f));
#pragma unroll
      for (int i = 0; i < MI; ++i) {
        float ss[4];
#pragma unroll
        for (int r = 0; r < 4; ++r)
          ss[r] = acc[i][0][r] * acc[i][0][r] + acc[i][1][r] * acc[i][1][r] +
                  acc[i][2][r] * acc[i][2][r] + acc[i][3][r] * acc[i][3][r];
#pragma unroll
        for (int off = 1; off < 16; off <<= 1)
#pragma unroll
          for (int r = 0; r < 4; ++r) ss[r] += __shfl_xor(ss[r], off, 64);
#pragma unroll
        for (int r = 0; r < 4; ++r) {
          const int token = (m0 + wm + i * 16 + rq + r) & 255;
          const float rms = rsqrtf(ss[r] * (1.f / 64.f) + 1e-6f);
          float nv[4];
#pragma unroll
          for (int j = 0; j < 4; ++j) nv[j] = acc[i][j][r] * rms * wv[j];
          float s0, c0, s1, c1;
          __sincosf((float)token * f0, &s0, &c0);
          __sincosf((float)token * f1, &s1, &c1);
          u16* dst = obuf + ((size_t)bh * 256 + token) * 64 + rl;
          dst[0]  = f2bf(nv[0] * c0 - nv[2] * s0);
          dst[16] = f2bf(nv[1] * c1 - nv[3] * s1);
          dst[32] = f2bf(nv[2] * c0 + nv[0] * s0);
          dst[48] = f2bf(nv[3] * c1 + nv[1] * s1);
        }
      }
    }
  } else if constexpr (EPI == 3) {
    // w1/w3 interleaved in 16-unit groups: j even = w1, j odd = w3, same unit
    const int ubase = ((n0 + wn) >> 1) + rl;
#pragma unroll
    for (int i = 0; i < MI; ++i)
#pragma unroll
      for (int r = 0; r < 4; ++r) {
        const int row = m0 + wm + i * 16 + rq + r;
        u16* dst = ob0 + (size_t)row * 2752 + ubase;
#pragma unroll
        for (int p = 0; p < 2; ++p) {
          const float a = acc[i][2 * p][r];
          const float b3 = acc[i][2 * p + 1][r];
          dst[p * 16] = f2bf(silu_f(a) * b3);
        }
      }
  }
}

// ---------------------------------------------------------------------------
// Legacy GEMM (fallback when workspace < 140MB): inline f32->bf16 W staging.
// ---------------------------------------------------------------------------
__global__ __launch_bounds__(256) void gemm_legacy_kernel(
    const u16* __restrict__ A, int lda,
    const float* __restrict__ W, int ldw,
    float* __restrict__ C, int ldc,
    int N, int Ksteps, int Kw, int nbx)
{
  __shared__ alignas(16) u16 As[128][72];
  __shared__ alignas(16) u16 Ws[128][72];
  const int tid = threadIdx.x;
  const int lane = tid & 63;
  const int wave = tid >> 6;
  const int wm = (wave >> 1) * 64;
  const int wn = (wave & 1) * 64;
  const int nwg = gridDim.x;
  const int cpx = nwg >> 3;
  const int f = blockIdx.x;
  const int idx = (f & 7) * cpx + (f >> 3);
  const int m0 = (idx % nbx) * 128;
  const int n0 = (idx / nbx) * 128;
  const int srow = tid >> 1;
  const int sseg = (tid & 1) * 32;
  const int rl = lane & 15;
  const int kq = (lane >> 4) * 8;

  f32x4 acc[4][4];
#pragma unroll
  for (int i = 0; i < 4; ++i)
#pragma unroll
    for (int j = 0; j < 4; ++j) acc[i][j] = (f32x4){0.f, 0.f, 0.f, 0.f};

  for (int kt = 0; kt < Ksteps; ++kt) {
    const int k0 = kt * 64;
    __syncthreads();
    {
      const u16* src = A + (size_t)(m0 + srow) * lda + k0 + sseg;
      uint4 v0 = *(const uint4*)(src + 0);
      uint4 v1 = *(const uint4*)(src + 8);
      uint4 v2 = *(const uint4*)(src + 16);
      uint4 v3 = *(const uint4*)(src + 24);
      *(uint4*)&As[srow][sseg + 0]  = v0;
      *(uint4*)&As[srow][sseg + 8]  = v1;
      *(uint4*)&As[srow][sseg + 16] = v2;
      *(uint4*)&As[srow][sseg + 24] = v3;
    }
    {
      const int n = n0 + srow;
      const int kbase = k0 + sseg;
      const float* src = W + (size_t)n * ldw + kbase;
      if (n < N && kbase + 32 <= Kw) {
#pragma unroll
        for (int g = 0; g < 4; ++g) {
          float4 a = *(const float4*)(src + g * 8);
          float4 b = *(const float4*)(src + g * 8 + 4);
          union { u16 u[8]; uint4 v; } p;
          p.u[0] = f2bf(a.x); p.u[1] = f2bf(a.y); p.u[2] = f2bf(a.z); p.u[3] = f2bf(a.w);
          p.u[4] = f2bf(b.x); p.u[5] = f2bf(b.y); p.u[6] = f2bf(b.z); p.u[7] = f2bf(b.w);
          *(uint4*)&Ws[srow][sseg + g * 8] = p.v;
        }
      } else {
#pragma unroll 4
        for (int g = 0; g < 32; ++g) {
          float v = (n < N && (kbase + g) < Kw) ? src[g] : 0.f;
          Ws[srow][sseg + g] = f2bf(v);
        }
      }
    }
    __syncthreads();
#pragma unroll
    for (int kk = 0; kk < 2; ++kk) {
      bf16x8 af[4], bfr[4];
#pragma unroll
      for (int i = 0; i < 4; ++i)
        af[i] = *(const bf16x8*)&As[wm + i * 16 + rl][kk * 32 + kq];
#pragma unroll
      for (int j = 0; j < 4; ++j)
        bfr[j] = *(const bf16x8*)&Ws[wn + j * 16 + rl][kk * 32 + kq];
#pragma unroll
      for (int i = 0; i < 4; ++i)
#pragma unroll
        for (int j = 0; j < 4; ++j)
          acc[i][j] = __builtin_amdgcn_mfma_f32_16x16x32_bf16(af[i], bfr[j], acc[i][j], 0, 0, 0);
    }
  }
  const int rq = (lane >> 4) * 4;
#pragma unroll
  for (int j = 0; j < 4; ++j) {
    const int n = n0 + wn + j * 16 + rl;
    if (n >= N) continue;
#pragma unroll
    for (int i = 0; i < 4; ++i) {
      const int mrow = m0 + wm + i * 16 + rq;
#pragma unroll
      for (int r = 0; r < 4; ++r)
        C[(size_t)(mrow + r) * ldc + n] = acc[i][j][r];
    }
  }
}

// ---------------------------------------------------------------------------
// Weight conversion (upfront, all layers):
//   convA: qkv|proj straight f32->bf16
//   convB: w13 interleaved rows (32t..+15 = w1 units 16t.., +16..31 = w3), pad 0
//   convC: w2 [1024][2730] -> [1024][2752] pad
// ---------------------------------------------------------------------------
__global__ __launch_bounds__(256) void convA_kernel(
    const float* __restrict__ qkvw, const float* __restrict__ projw,
    u16* __restrict__ dst)
{
  for (int g = blockIdx.x * 256 + threadIdx.x; g < 1048576; g += gridDim.x * 256) {
    const int idx = g * 4;
    float4 v = (idx < 3145728) ? *(const float4*)(qkvw + idx)
                               : *(const float4*)(projw + (idx - 3145728));
    union { u16 u[4]; uint2 q; } p;
    p.u[0] = f2bf(v.x); p.u[1] = f2bf(v.y); p.u[2] = f2bf(v.z); p.u[3] = f2bf(v.w);
    *(uint2*)(dst + idx) = p.q;
  }
}

__global__ __launch_bounds__(256) void convB_kernel(
    const float* __restrict__ w1, const float* __restrict__ w3,
    u16* __restrict__ dst)
{
  const int rW = blockIdx.x;
  const int t = rW >> 5, s = rW & 31;
  const int unit = 16 * t + (s & 15);
  const float* src = ((s < 16) ? w1 : w3) + (size_t)unit * 1024;
  u16* drow = dst + (size_t)rW * 1024;
  const int c = threadIdx.x * 4;
  union { u16 u[4]; uint2 q; } p;
  if (unit < 2730) {
    float4 v = *(const float4*)(src + c);
    p.u[0] = f2bf(v.x); p.u[1] = f2bf(v.y); p.u[2] = f2bf(v.z); p.u[3] = f2bf(v.w);
  } else {
    p.u[0] = p.u[1] = p.u[2] = p.u[3] = 0;
  }
  *(uint2*)(drow + c) = p.q;
}

__global__ __launch_bounds__(256) void convC_kernel(
    const float* __restrict__ w2, u16* __restrict__ dst)
{
  const int r = blockIdx.x;
  const float* src = w2 + (size_t)r * 2730;
  u16* drow = dst + (size_t)r * 2752;
  for (int c = threadIdx.x * 4; c < 2752; c += 1024) {
    union { u16 u[4]; uint2 q; } p;
#pragma unroll
    for (int i = 0; i < 4; ++i) {
      const int cc = c + i;
      p.u[i] = (cc < 2730) ? f2bf(src[cc]) : (u16)0;
    }
    *(uint2*)(drow + c) = p.q;
  }
}

// ---------------------------------------------------------------------------
// Conditioning
// ---------------------------------------------------------------------------
__global__ __launch_bounds__(256) void cond_hc_kernel(
    const float* __restrict__ cfg_s, const float* __restrict__ w1,
    const float* __restrict__ b1, float* __restrict__ hc)
{
  const int b = blockIdx.x, c = threadIdx.x * 4;
  const float s = cfg_s[b];
  float4 w = *(const float4*)(w1 + c);
  float4 bb = *(const float4*)(b1 + c);
  float4 o;
  o.x = silu_f(s * w.x + bb.x);
  o.y = silu_f(s * w.y + bb.y);
  o.z = silu_f(s * w.z + bb.z);
  o.w = silu_f(s * w.w + bb.w);
  *(float4*)(hc + (size_t)b * 1024 + c) = o;
}

__global__ __launch_bounds__(64) void cond_sc_kernel(
    const float* __restrict__ hc, const float* __restrict__ w2,
    const float* __restrict__ b2, const float* __restrict__ ce,
    const int* __restrict__ y, float* __restrict__ sc)
{
  const int j = blockIdx.x, b = blockIdx.y, lane = threadIdx.x;
  const float4* wr = (const float4*)(w2 + (size_t)j * 1024);
  const float4* hr = (const float4*)(hc + (size_t)b * 1024);
  float acc = 0.f;
#pragma unroll
  for (int rep = 0; rep < 4; ++rep) {
    float4 w = wr[rep * 64 + lane];
    float4 h = hr[rep * 64 + lane];
    acc += w.x * h.x + w.y * h.y + w.z * h.z + w.w * h.w;
  }
  acc = waveAllSum(acc);
  if (lane == 0) {
    float v = ce[(size_t)y[b] * 1024 + j] + acc + b2[j];
    sc[(size_t)b * 1024 + j] = silu_f(v);
  }
}

__global__ __launch_bounds__(64) void modlin_kernel(
    const float* __restrict__ w, const float* __restrict__ bias,
    const float* __restrict__ sc, float* __restrict__ out, int ostride)
{
  const int j = blockIdx.x, lane = threadIdx.x;
  const float4* wr = (const float4*)(w + (size_t)j * 1024);
  float acc[8];
#pragma unroll
  for (int b = 0; b < 8; ++b) acc[b] = 0.f;
#pragma unroll
  for (int rep = 0; rep < 4; ++rep) {
    float4 wv = wr[rep * 64 + lane];
#pragma unroll
    for (int b = 0; b < 8; ++b) {
      float4 s = ((const float4*)(sc + (size_t)b * 1024))[rep * 64 + lane];
      acc[b] += wv.x * s.x + wv.y * s.y + wv.z * s.z + wv.w * s.w;
    }
  }
#pragma unroll
  for (int b = 0; b < 8; ++b) acc[b] = waveAllSum(acc[b]);
  if (lane == 0) {
    const float bb = bias[j];
#pragma unroll
    for (int b = 0; b < 8; ++b) out[(size_t)b * ostride + j] = acc[b] + bb;
  }
}

// ---------------------------------------------------------------------------
// Patch embed
// ---------------------------------------------------------------------------
__global__ __launch_bounds__(256) void patch_kernel(
    const float* __restrict__ x, const float* __restrict__ pw,
    const float* __restrict__ pb, const float* __restrict__ pos,
    float* __restrict__ xc)
{
  const int n = blockIdx.x, b = blockIdx.y, tid = threadIdx.x;
  __shared__ float pv[16];
  if (tid < 16) {
    const int ci = tid >> 2, pi = (tid >> 1) & 1, pj = tid & 1;
    const int i = n >> 4, j = n & 15;
    pv[tid] = x[((size_t)(b * 4 + ci) * 32 + i * 2 + pi) * 32 + j * 2 + pj];
  }
  __syncthreads();
#pragma unroll
  for (int qq = 0; qq < 4; ++qq) {
    const int c = qq * 256 + tid;
    const float4* wr = (const float4*)(pw + (size_t)c * 16);
    float acc = pb[c] + pos[(size_t)n * 1024 + c];
#pragma unroll
    for (int g = 0; g < 4; ++g) {
      float4 w = wr[g];
      acc += w.x * pv[g * 4] + w.y * pv[g * 4 + 1] + w.z * pv[g * 4 + 2] + w.w * pv[g * 4 + 3];
    }
    xc[((size_t)b * 256 + n) * 1024 + c] = acc;
  }
}

// ---------------------------------------------------------------------------
// RMSNorm + adaLN modulate -> bf16
// ---------------------------------------------------------------------------
__global__ __launch_bounds__(256) void normmod_kernel(
    const float* __restrict__ xc, const float* __restrict__ w,
    const float* __restrict__ mods, int mult_off, int shift_off, int mstride,
    u16* __restrict__ out)
{
  const int m = blockIdx.x, b = m >> 8, tid = threadIdx.x;
  const float* row = xc + (size_t)m * 1024;
  float4 v = *(const float4*)(row + tid * 4);
  float ss = v.x * v.x + v.y * v.y + v.z * v.z + v.w * v.w;
  ss = waveAllSum(ss);
  __shared__ float red[4];
  if ((tid & 63) == 0) red[tid >> 6] = ss;
  __syncthreads();
  const float tot = red[0] + red[1] + red[2] + red[3];
  const float r = rsqrtf(tot * (1.f / 1024.f) + 1e-6f);
  const float* mb = mods + (size_t)b * mstride;
  const int c = tid * 4;
  float4 wv = *(const float4*)(w + c);
  float4 mu = *(const float4*)(mb + mult_off + c);
  float4 sh = *(const float4*)(mb + shift_off + c);
  union { u16 u[4]; uint2 v2; } pk;
  pk.u[0] = f2bf(v.x * r * wv.x * (1.f + mu.x) + sh.x);
  pk.u[1] = f2bf(v.y * r * wv.y * (1.f + mu.y) + sh.y);
  pk.u[2] = f2bf(v.z * r * wv.z * (1.f + mu.z) + sh.z);
  pk.u[3] = f2bf(v.w * r * wv.w * (1.f + mu.w) + sh.w);
  *(uint2*)(out + (size_t)m * 1024 + c) = pk.v2;
}

// ---------------------------------------------------------------------------
// q/k RMSNorm + RoPE + v copy -> bf16 [bh, n, d]  (legacy path only)
// ---------------------------------------------------------------------------
__global__ __launch_bounds__(256) void rope_kernel(
    const float* __restrict__ qkv, const float* __restrict__ qnw,
    const float* __restrict__ knw, u16* __restrict__ qb,
    u16* __restrict__ kb, u16* __restrict__ vb)
{
  const int idx = blockIdx.x * 4 + (threadIdx.x >> 6);
  const int n = idx & 255;
  const int bh = idx >> 8;
  const int b = bh >> 4, h = bh & 15;
  const int d = threadIdx.x & 63;
  const size_t base = ((size_t)(b * 256 + n)) * 3072 + h * 64 + d;
  float qv = qkv[base];
  float kv = qkv[base + 1024];
  float vv = qkv[base + 2048];
  float qs = waveAllSum(qv * qv);
  float ks = waveAllSum(kv * kv);
  const float rq = rsqrtf(qs * (1.f / 64.f) + 1e-6f);
  const float rk = rsqrtf(ks * (1.f / 64.f) + 1e-6f);
  const float qn = qv * rq * qnw[d];
  const float kn = kv * rk * knw[d];
  const int i = d & 31;
  const float freq = __powf(10000.f, -(float)(2 * i) * (1.f / 64.f));
  const float ang = (float)n * freq;
  float sv, cv;
  sincosf(ang, &sv, &cv);
  const float qo = __shfl_xor(qn, 32, 64);
  const float ko = __shfl_xor(kn, 32, 64);
  const float rq2 = (d < 32) ? -qo : qo;
  const float rk2 = (d < 32) ? -ko : ko;
  const size_t ob = ((size_t)bh * 256 + n) * 64 + d;
  qb[ob] = f2bf(qn * cv + rq2 * sv);
  kb[ob] = f2bf(kn * cv + rk2 * sv);
  vb[ob] = f2bf(vv);
}

// ---------------------------------------------------------------------------
// MFMA attention
// ---------------------------------------------------------------------------
__global__ __launch_bounds__(256) void attn_kernel(
    const u16* __restrict__ qb, const u16* __restrict__ kb,
    const u16* __restrict__ vb, u16* __restrict__ o)
{
  __shared__ alignas(16) u16 Kt[128][72];
  __shared__ alignas(16) u16 Vtt[64][136];
  __shared__ alignas(16) u16 Pw[4][16][136];
  const int bh = blockIdx.x;
  const int qbase = blockIdx.y * 64;
  const int tid = threadIdx.x;
  const int lane = tid & 63;
  const int wave = tid >> 6;
  const int rl = lane & 15;
  const int kq = (lane >> 4) * 8;
  const int rowg = (lane >> 4) * 4;

  const int q0 = qbase + wave * 16;
  const u16* qsrc = qb + ((size_t)bh * 256 + q0 + rl) * 64 + kq;
  const bf16x8 a0 = *(const bf16x8*)(qsrc);
  const bf16x8 a1 = *(const bf16x8*)(qsrc + 32);

  float m[4], l[4];
  f32x4 oacc[4];
#pragma unroll
  for (int r = 0; r < 4; ++r) { m[r] = -1e30f; l[r] = 0.f; }
#pragma unroll
  for (int dt = 0; dt < 4; ++dt) oacc[dt] = (f32x4){0.f, 0.f, 0.f, 0.f};

  for (int kt = 0; kt < 2; ++kt) {
    __syncthreads();
#pragma unroll
    for (int c = 0; c < 4; ++c) {
      const int flat = c * 256 + tid;
      const int row = flat >> 3;
      const int col = (flat & 7) * 8;
      uint4 v = *(const uint4*)(kb + ((size_t)bh * 256 + kt * 128 + row) * 64 + col);
      *(uint4*)&Kt[row][col] = v;
    }
    {
      const int tt = tid & 63;
      const int dh = tid >> 6;
      const int r0 = tt * 2;
      const u16* s0 = vb + ((size_t)bh * 256 + kt * 128 + r0) * 64 + dh * 16;
      const u16* s1 = s0 + 64;
#pragma unroll
      for (int g = 0; g < 2; ++g) {
        uint4 A = *(const uint4*)(s0 + g * 8);
        uint4 B = *(const uint4*)(s1 + g * 8);
        const u32 aw[4] = {A.x, A.y, A.z, A.w};
        const u32 bw[4] = {B.x, B.y, B.z, B.w};
#pragma unroll
        for (int q = 0; q < 4; ++q) {
          const int d2 = dh * 16 + g * 8 + q * 2;
          const u32 lo = (aw[q] & 0xffffu) | (bw[q] << 16);
          const u32 hi = (aw[q] >> 16) | (bw[q] & 0xffff0000u);
          *(u32*)&Vtt[d2][r0] = lo;
          *(u32*)&Vtt[d2 + 1][r0] = hi;
        }
      }
    }
    __syncthreads();

    f32x4 sacc[8];
#pragma unroll
    for (int t = 0; t < 8; ++t) sacc[t] = (f32x4){0.f, 0.f, 0.f, 0.f};
#pragma unroll
    for (int t = 0; t < 8; ++t) {
      bf16x8 k0 = *(const bf16x8*)&Kt[t * 16 + rl][kq];
      bf16x8 k1 = *(const bf16x8*)&Kt[t * 16 + rl][32 + kq];
      sacc[t] = __builtin_amdgcn_mfma_f32_16x16x32_bf16(a0, k0, sacc[t], 0, 0, 0);
      sacc[t] = __builtin_amdgcn_mfma_f32_16x16x32_bf16(a1, k1, sacc[t], 0, 0, 0);
    }
    float cmax[4];
#pragma unroll
    for (int r = 0; r < 4; ++r) cmax[r] = sacc[0][r];
#pragma unroll
    for (int t = 1; t < 8; ++t)
#pragma unroll
      for (int r = 0; r < 4; ++r) cmax[r] = fmaxf(cmax[r], sacc[t][r]);
#pragma unroll
    for (int off = 1; off < 16; off <<= 1)
#pragma unroll
      for (int r = 0; r < 4; ++r) cmax[r] = fmaxf(cmax[r], __shfl_xor(cmax[r], off, 64));
#pragma unroll
    for (int r = 0; r < 4; ++r) {
      const float mn = fmaxf(m[r], cmax[r]);
      const float corr = __expf((m[r] - mn) * 0.125f);
      l[r] *= corr;
#pragma unroll
      for (int dt = 0; dt < 4; ++dt) oacc[dt][r] *= corr;
      m[r] = mn;
    }
    float lsum[4] = {0.f, 0.f, 0.f, 0.f};
#pragma unroll
    for (int t = 0; t < 8; ++t)
#pragma unroll
      for (int r = 0; r < 4; ++r) {
        const float p = __expf((sacc[t][r] - m[r]) * 0.125f);
        lsum[r] += p;
        Pw[wave][rowg + r][t * 16 + rl] = f2bf(p);
      }
#pragma unroll
    for (int off = 1; off < 16; off <<= 1)
#pragma unroll
      for (int r = 0; r < 4; ++r) lsum[r] += __shfl_xor(lsum[r], off, 64);
#pragma unroll
    for (int r = 0; r < 4; ++r) l[r] += lsum[r];
#pragma unroll
    for (int ks = 0; ks < 4; ++ks) {
      bf16x8 pa = *(const bf16x8*)&Pw[wave][rl][ks * 32 + kq];
#pragma unroll
      for (int dt = 0; dt < 4; ++dt) {
        bf16x8 vf = *(const bf16x8*)&Vtt[dt * 16 + rl][ks * 32 + kq];
        oacc[dt] = __builtin_amdgcn_mfma_f32_16x16x32_bf16(pa, vf, oacc[dt], 0, 0, 0);
      }
    }
  }
  const int b = bh >> 4, h = bh & 15;
#pragma unroll
  for (int r = 0; r < 4; ++r) {
    const float inv = 1.f / l[r];
    const int qrow = q0 + rowg + r;
    u16* dst = o + (((size_t)b * 256 + qrow) * 16 + h) * 64 + rl;
#pragma unroll
    for (int dt = 0; dt < 4; ++dt)
      dst[dt * 16] = f2bf(oacc[dt][r] * inv);
  }
}

// ---------------------------------------------------------------------------
// Residual / SwiGLU (legacy path only)
// ---------------------------------------------------------------------------
__global__ __launch_bounds__(256) void resid_kernel(
    float* __restrict__ xc, const float* __restrict__ gout,
    const float* __restrict__ bias, const float* __restrict__ mods,
    int g_off, int mstride)
{
  const int m = blockIdx.x, b = m >> 8;
  const int c = threadIdx.x * 4;
  float4 xv = *(float4*)(xc + (size_t)m * 1024 + c);
  float4 gv = *(const float4*)(gout + (size_t)m * 1024 + c);
  float4 mg = *(const float4*)(mods + (size_t)b * mstride + g_off + c);
  float bx = 0.f, by = 0.f, bz = 0.f, bw = 0.f;
  if (bias) {
    float4 bb = *(const float4*)(bias + c);
    bx = bb.x; by = bb.y; bz = bb.z; bw = bb.w;
  }
  xv.x += mg.x * (gv.x + bx);
  xv.y += mg.y * (gv.y + by);
  xv.z += mg.z * (gv.z + bz);
  xv.w += mg.w * (gv.w + bw);
  *(float4*)(xc + (size_t)m * 1024 + c) = xv;
}

__global__ __launch_bounds__(256) void swiglu_kernel(
    const float* __restrict__ a, const float* __restrict__ b,
    int stride, u16* __restrict__ h1)
{
  const int m = blockIdx.x;
  const size_t ra = (size_t)m * stride;
  const size_t rh = (size_t)m * 2752;
  for (int j0 = threadIdx.x * 4; j0 < 2752; j0 += 1024) {
    float4 av4 = *(const float4*)(a + ra + j0);
    float4 bv4 = *(const float4*)(b + ra + j0);
    float av[4] = {av4.x, av4.y, av4.z, av4.w};
    float bv[4] = {bv4.x, bv4.y, bv4.z, bv4.w};
    union { u16 u[4]; uint2 v; } pk;
#pragma unroll
    for (int i = 0; i < 4; ++i) {
      float val = 0.f;
      if (j0 + i < 2730) val = silu_f(av[i]) * bv[i];
      pk.u[i] = f2bf(val);
    }
    *(uint2*)(h1 + rh + j0) = pk.v;
  }
}

// ---------------------------------------------------------------------------
// Final LayerNorm + modulate -> bf16
// ---------------------------------------------------------------------------
__global__ __launch_bounds__(256) void lnmod_kernel(
    const float* __restrict__ xc, const float* __restrict__ fmods,
    u16* __restrict__ out)
{
  const int m = blockIdx.x, b = m >> 8, tid = threadIdx.x;
  const float* row = xc + (size_t)m * 1024;
  float4 v = *(const float4*)(row + tid * 4);
  float s1 = v.x + v.y + v.z + v.w;
  float s2 = v.x * v.x + v.y * v.y + v.z * v.z + v.w * v.w;
  s1 = waveAllSum(s1);
  s2 = waveAllSum(s2);
  __shared__ float r1[4], r2[4];
  if ((tid & 63) == 0) { r1[tid >> 6] = s1; r2[tid >> 6] = s2; }
  __syncthreads();
  const float t1 = r1[0] + r1[1] + r1[2] + r1[3];
  const float t2 = r2[0] + r2[1] + r2[2] + r2[3];
  const float mean = t1 * (1.f / 1024.f);
  const float var = t2 * (1.f / 1024.f) - mean * mean;
  const float rr = rsqrtf(var + 1e-5f);
  const float* mb = fmods + (size_t)b * 2048;
  const int c = tid * 4;
  float4 sh = *(const float4*)(mb + c);
  float4 sl = *(const float4*)(mb + 1024 + c);
  union { u16 u[4]; uint2 v2; } pk;
  pk.u[0] = f2bf((v.x - mean) * rr * (1.f + sl.x) + sh.x);
  pk.u[1] = f2bf((v.y - mean) * rr * (1.f + sl.y) + sh.y);
  pk.u[2] = f2bf((v.z - mean) * rr * (1.f + sl.z) + sh.z);
  pk.u[3] = f2bf((v.w - mean) * rr * (1.f + sl.w) + sh.w);
  *(uint2*)(out + (size_t)m * 1024 + c) = pk.v2;
}

// ---------------------------------------------------------------------------
// Final linear (16 outputs) + unpatchify
// ---------------------------------------------------------------------------
__global__ __launch_bounds__(256) void final_kernel(
    const u16* __restrict__ xfin, const float* __restrict__ w,
    const float* __restrict__ bias, float* __restrict__ out)
{
  const int tid = threadIdx.x;
  const int m = blockIdx.x * 16 + (tid >> 4);
  const int j = tid & 15;
  const u16* xr = xfin + (size_t)m * 1024;
  const float* wr = w + (size_t)j * 1024;
  float acc = 0.f;
  for (int k = 0; k < 1024; k += 8) {
    uint4 xv = *(const uint4*)(xr + k);
    const u16* xu = (const u16*)&xv;
    float4 w0 = *(const float4*)(wr + k);
    float4 w1 = *(const float4*)(wr + k + 4);
    acc += bf2f(xu[0]) * w0.x + bf2f(xu[1]) * w0.y + bf2f(xu[2]) * w0.z + bf2f(xu[3]) * w0.w;
    acc += bf2f(xu[4]) * w1.x + bf2f(xu[5]) * w1.y + bf2f(xu[6]) * w1.z + bf2f(xu[7]) * w1.w;
  }
  acc += bias[j];
  const int b = m >> 8, n = m & 255;
  const int i = n >> 4, jj = n & 15;
  const int pi = (j >> 3) & 1, pj = (j >> 2) & 1, oc = j & 3;
  out[((size_t)(b * 4 + oc) * 32 + i * 2 + pi) * 32 + jj * 2 + pj] = acc;
}

// ---------------------------------------------------------------------------
extern "C" void kernel_launch(void* const* d_in, const int* in_sizes, int n_in,
                              void* d_out, int out_size, void* d_ws, size_t ws_size,
                              hipStream_t stream) {
  const float* x       = (const float*)d_in[0];
  const int*   y       = (const int*)  d_in[1];
  const float* cfg_s   = (const float*)d_in[2];
  const float* patch_w = (const float*)d_in[3];
  const float* patch_b = (const float*)d_in[4];
  const float* pos_e   = (const float*)d_in[5];
  const float* class_e = (const float*)d_in[6];
  const float* cfg_w1  = (const float*)d_in[7];
  const float* cfg_b1  = (const float*)d_in[8];
  const float* cfg_w2  = (const float*)d_in[9];
  const float* cfg_b2  = (const float*)d_in[10];
  const float* n1w     = (const float*)d_in[11];
  const float* n2w     = (const float*)d_in[12];
  const float* qkvw    = (const float*)d_in[13];
  const float* projw   = (const float*)d_in[14];
  const float* projb   = (const float*)d_in[15];
  const float* qnw     = (const float*)d_in[16];
  const float* knw     = (const float*)d_in[17];
  const float* w1      = (const float*)d_in[18];
  const float* w2      = (const float*)d_in[19];
  const float* w3      = (const float*)d_in[20];
  const float* adaw    = (const float*)d_in[21];
  const float* adab    = (const float*)d_in[22];
  const float* finaw   = (const float*)d_in[23];
  const float* finab   = (const float*)d_in[24];
  const float* flw     = (const float*)d_in[25];
  const float* flb     = (const float*)d_in[26];
  (void)in_sizes; (void)n_in; (void)out_size;

  char* ws = (char*)d_ws;
  const size_t MB = 1024 * 1024;
  float* hc    = (float*)(ws);
  float* sc    = (float*)(ws + 32 * 1024);
  float* mods  = (float*)(ws + 64 * 1024);
  float* fmods = (float*)(ws + 64 * 1024 + 786432);
  float* xc    = (float*)(ws + 1 * MB);   // 8MB
  u16*   xm    = (u16*)  (ws + 9 * MB);   // 4MB (normmod out / attn out)

  cond_hc_kernel<<<8, 256, 0, stream>>>(cfg_s, cfg_w1, cfg_b1, hc);
  cond_sc_kernel<<<dim3(1024, 8), 64, 0, stream>>>(hc, cfg_w2, cfg_b2, class_e, y, sc);
  for (int d = 0; d < 4; ++d)
    modlin_kernel<<<6144, 64, 0, stream>>>(adaw + (size_t)d * 6144 * 1024,
                                           adab + (size_t)d * 6144, sc,
                                           mods + (size_t)d * 8 * 6144, 6144);
  modlin_kernel<<<2048, 64, 0, stream>>>(finaw, finab, sc, fmods, 2048);
  patch_kernel<<<dim3(256, 8), 256, 0, stream>>>(x, patch_w, patch_b, pos_e, xc);

  if (ws_size >= 140 * MB) {
    // ---- fused path ----
    u16* qbuf = (u16*)(ws + 13 * MB);     // 4MB
    u16* kbuf = (u16*)(ws + 17 * MB);     // 4MB
    u16* vbuf = (u16*)(ws + 21 * MB);     // 4MB
    u16* h1   = (u16*)(ws + 25 * MB);     // 11.3MB
    u16* WB   = (u16*)(ws + 37 * MB);     // 101.2MB (4 layers bf16)
    const size_t WSTRIDE = 12648448;      // elems per layer
    for (int d = 0; d < 4; ++d) {
      u16* WL = WB + (size_t)d * WSTRIDE;
      convA_kernel<<<2048, 256, 0, stream>>>(qkvw + (size_t)d * 3145728,
                                             projw + (size_t)d * 1048576, WL);
      convB_kernel<<<5504, 256, 0, stream>>>(w1 + (size_t)d * 2795520,
                                             w3 + (size_t)d * 2795520, WL + 4194304);
      convC_kernel<<<1024, 256, 0, stream>>>(w2 + (size_t)d * 2795520, WL + 9830400);
    }
    for (int d = 0; d < 4; ++d) {
      const float* md = mods + (size_t)d * 8 * 6144;
      u16* WL = WB + (size_t)d * WSTRIDE;
      normmod_kernel<<<2048, 256, 0, stream>>>(xc, n1w + d * 1024, md, 1024, 0, 6144, xm);
      gemm_t<64, 2><<<768, 256, 0, stream>>>(xm, 1024, WL, 1024, 16, 32,
                                             nullptr, nullptr, nullptr,
                                             qbuf, kbuf, vbuf, qnw + d * 64, knw + d * 64);
      attn_kernel<<<dim3(128, 4), 256, 0, stream>>>(qbuf, kbuf, vbuf, xm);
      gemm_t<64, 1><<<256, 256, 0, stream>>>(xm, 1024, WL + 3145728, 1024, 16, 32,
                                             xc, md + 2048, projb + d * 1024,
                                             nullptr, nullptr, nullptr, nullptr, nullptr);
      normmod_kernel<<<2048, 256, 0, stream>>>(xc, n2w + d * 1024, md, 4096, 3072, 6144, xm);
      gemm_t<128, 3><<<688, 256, 0, stream>>>(xm, 1024, WL + 4194304, 1024, 16, 16,
                                              nullptr, nullptr, nullptr,
                                              h1, nullptr, nullptr, nullptr, nullptr);
      gemm_t<64, 1><<<256, 256, 0, stream>>>(h1, 2752, WL + 9830400, 2752, 43, 32,
                                             xc, md + 5120, nullptr,
                                             nullptr, nullptr, nullptr, nullptr, nullptr);
    }
  } else {
    // ---- legacy fallback (f32 weights inline) ----
    if (ws_size < 73 * MB) return;
    float* zone  = (float*)(ws + 13 * MB);
    u16*   qbuf  = (u16*)  (ws + 58 * MB);
    u16*   kbuf  = (u16*)  (ws + 62 * MB);
    u16*   vbuf  = (u16*)  (ws + 66 * MB);
    u16*   h1    = (u16*)  (ws + 58 * MB);
    float* zone2 = zone + (size_t)2048 * 2752;
    for (int d = 0; d < 4; ++d) {
      const float* md = mods + (size_t)d * 8 * 6144;
      normmod_kernel<<<2048, 256, 0, stream>>>(xc, n1w + d * 1024, md, 1024, 0, 6144, xm);
      gemm_legacy_kernel<<<384, 256, 0, stream>>>(xm, 1024, qkvw + (size_t)d * 3145728, 1024,
                                                  zone, 3072, 3072, 16, 1024, 16);
      rope_kernel<<<8192, 256, 0, stream>>>(zone, qnw + d * 64, knw + d * 64, qbuf, kbuf, vbuf);
      attn_kernel<<<dim3(128, 4), 256, 0, stream>>>(qbuf, kbuf, vbuf, xm);
      gemm_legacy_kernel<<<128, 256, 0, stream>>>(xm, 1024, projw + (size_t)d * 1048576, 1024,
                                                  zone, 1024, 1024, 16, 1024, 16);
      resid_kernel<<<2048, 256, 0, stream>>>(xc, zone, projb + d * 1024, md, 2048, 6144);
      normmod_kernel<<<2048, 256, 0, stream>>>(xc, n2w + d * 1024, md, 4096, 3072, 6144, xm);
      gemm_legacy_kernel<<<352, 256, 0, stream>>>(xm, 1024, w1 + (size_t)d * 2795520, 1024,
                                                  zone, 2752, 2730, 16, 1024, 16);
      gemm_legacy_kernel<<<352, 256, 0, stream>>>(xm, 1024, w3 + (size_t)d * 2795520, 1024,
                                                  zone2, 2752, 2730, 16, 1024, 16);
      swiglu_kernel<<<2048, 256, 0, stream>>>(zone, zone2, 2752, h1);
      gemm_legacy_kernel<<<128, 256, 0, stream>>>(h1, 2752, w2 + (size_t)d * 2795520, 2730,
                                                  zone, 1024, 1024, 43, 2730, 16);
      resid_kernel<<<2048, 256, 0, stream>>>(xc, zone, nullptr, md, 5120, 6144);
    }
  }

  lnmod_kernel<<<2048, 256, 0, stream>>>(xc, fmods, xm);
  final_kernel<<<128, 256, 0, stream>>>(xm, flw, flb, (float*)d_out);
}

// Round 6
// 613.515 us; speedup vs baseline: 3.9413x; 1.2891x over previous
//
#include <hip/hip_runtime.h>

typedef unsigned char u8;
typedef unsigned short u16;
typedef unsigned int u32;
typedef float f32x4 __attribute__((ext_vector_type(4)));
typedef __bf16 bf16x8 __attribute__((ext_vector_type(8)));

#define DEV __device__ __forceinline__

DEV u16 f2bf(float f) {
  u32 u = __builtin_bit_cast(u32, f);
  u += 0x7fffu + ((u >> 16) & 1u);
  return (u16)(u >> 16);
}
DEV float bf2f(u16 u) { return __builtin_bit_cast(float, (u32)u << 16); }
// f32 -> OCP e4m3fn (RNE, saturating)
DEV u32 f2f8(float f) {
  u32 u = __builtin_bit_cast(u32, f);
  u32 s = (u >> 31) << 7;
  float a = __builtin_fabsf(f);
  if (a >= 448.f) return s | 0x7Eu;
  if (a < 0.015625f) {
    int m = (int)(a * 512.f + 0.5f);
    return s | (u32)m;
  }
  u32 b = __builtin_bit_cast(u32, a);
  b += 0x7FFFFu + ((b >> 20) & 1u);
  u32 E = (b >> 23) - 120u;
  if (E > 15u) return s | 0x7Eu;
  return s | (E << 3) | ((b >> 20) & 7u);
}
DEV u32 pk4f8(float x, float y, float z, float w) {
  return f2f8(x) | (f2f8(y) << 8) | (f2f8(z) << 16) | (f2f8(w) << 24);
}
DEV float waveAllSum(float x) {
#pragma unroll
  for (int off = 32; off > 0; off >>= 1) x += __shfl_xor(x, off, 64);
  return x;
}
DEV float silu_f(float x) { return x / (1.f + __expf(-x)); }

DEV void gll16(const void* g, void* l) {
  __builtin_amdgcn_global_load_lds(
      (const __attribute__((address_space(1))) void*)g,
      (__attribute__((address_space(3))) void*)l, 16, 0, 0);
}

// ---------------------------------------------------------------------------
// FP8 GEMM: C = A_fp8[m,k] * (16*W)_fp8[n,k]^T * (1/16); BM=64, BN=128,
// BK=128, 4 waves (2x2 of 32x64), dbuf global_load_lds + counted vmcnt.
// LDS held as long[16] per row (128B); 16B-chunk XOR swizzle by row&7 applied
// on the global SOURCE (linear LDS dest) and on the ds_read index.
// EPI: 1 = residual RX += gm*(acc*S+bias); 2 = qk-RMSNorm+RoPE+v -> bf16
// q/k/v; 3 = SwiGLU pair-fuse -> h1 fp8 (w1/w3 interleaved 16-unit groups).
// ---------------------------------------------------------------------------
template<int EPI>
__global__ __launch_bounds__(256, 3) void gemm8_t(
    const u8* __restrict__ A, int lda,
    const u8* __restrict__ W, int ldw,
    int Ksteps, int nbx,
    float* __restrict__ RX, const float* __restrict__ gmods,
    const float* __restrict__ bias,
    u16* __restrict__ ob0, u16* __restrict__ ob1, u16* __restrict__ ob2,
    u8* __restrict__ h1o,
    const float* __restrict__ nw_q, const float* __restrict__ nw_k)
{
  __shared__ long As[2][64][16];
  __shared__ long Ws[2][128][16];
  const int tid = threadIdx.x;
  const int lane = tid & 63;
  const int wave = tid >> 6;
  const int nwg = gridDim.x;
  const int cpx = nwg >> 3;
  const int fb = blockIdx.x;
  const int idx = (fb & 7) * cpx + (fb >> 3);
  const int m0 = (idx % nbx) * 64;
  const int n0 = (idx / nbx) * 128;
  const int wm = (wave >> 1) * 32;
  const int wn = (wave & 1) * 64;
  const int rl = lane & 15;
  const int qq = lane >> 4;            // 0..3
  const int lr = lane >> 3;            // 0..7 staging row-in-8
  const int ch = lane & 7;             // staging 16B chunk
  const int scol = (ch ^ lr) << 4;     // swizzled source byte col
  const u8* Abase = A + (size_t)m0 * lda;
  const u8* Wbase = W + (size_t)n0 * ldw;

  f32x4 acc[2][4];
#pragma unroll
  for (int i = 0; i < 2; ++i)
#pragma unroll
    for (int j = 0; j < 4; ++j) acc[i][j] = (f32x4){0.f, 0.f, 0.f, 0.f};

  auto STAGE = [&](int buf, int k0) {
#pragma unroll
    for (int c = 0; c < 2; ++c) {
      const int row = wave * 16 + c * 8 + lr;
      gll16(Abase + (size_t)row * lda + k0 + scol, &As[buf][row][ch * 2]);
    }
#pragma unroll
    for (int c = 0; c < 4; ++c) {
      const int row = wave * 32 + c * 8 + lr;
      gll16(Wbase + (size_t)row * ldw + k0 + scol, &Ws[buf][row][ch * 2]);
    }
  };

  STAGE(0, 0);
  for (int kt = 0; kt < Ksteps; ++kt) {
    const int buf = kt & 1;
    if (kt + 1 < Ksteps) {
      STAGE(buf ^ 1, (kt + 1) * 128);
      asm volatile("s_waitcnt vmcnt(6)" ::: "memory");
    } else {
      asm volatile("s_waitcnt vmcnt(0)" ::: "memory");
    }
    __builtin_amdgcn_s_barrier();
    __builtin_amdgcn_sched_barrier(0);
#pragma unroll
    for (int kk = 0; kk < 4; ++kk) {
      const int lo = (((kk * 2 + (qq >> 1)) ^ (rl & 7)) << 1) | (qq & 1);
      long af0 = As[buf][wm + rl][lo];
      long af1 = As[buf][wm + 16 + rl][lo];
      long bw[4];
#pragma unroll
      for (int j = 0; j < 4; ++j) bw[j] = Ws[buf][wn + j * 16 + rl][lo];
#pragma unroll
      for (int j = 0; j < 4; ++j) {
        acc[0][j] = __builtin_amdgcn_mfma_f32_16x16x32_fp8_fp8(af0, bw[j], acc[0][j], 0, 0, 0);
        acc[1][j] = __builtin_amdgcn_mfma_f32_16x16x32_fp8_fp8(af1, bw[j], acc[1][j], 0, 0, 0);
      }
    }
    __builtin_amdgcn_sched_barrier(0);
    __builtin_amdgcn_s_barrier();
  }

  constexpr float S = 0.0625f;  // 1/16 weight descale
  const int rq = qq * 4;
  if constexpr (EPI == 1) {
    const int b = m0 >> 8;
    const float* gm = gmods + (size_t)b * 6144;
#pragma unroll
    for (int j = 0; j < 4; ++j) {
      const int n = n0 + wn + j * 16 + rl;
      const float g = gm[n];
      const float bv = bias ? bias[n] : 0.f;
#pragma unroll
      for (int i = 0; i < 2; ++i) {
        const int mrow = m0 + wm + i * 16 + rq;
#pragma unroll
        for (int r = 0; r < 4; ++r) {
          float* p = RX + (size_t)(mrow + r) * 1024 + n;
          *p += g * (acc[i][j][r] * S + bv);
        }
      }
    }
  } else if constexpr (EPI == 2) {
    const int region = n0 >> 10;  // 0=q,1=k,2=v
    const int h = ((n0 + wn) >> 6) & 15;
    const int bh = (m0 >> 8) * 16 + h;
    if (region == 2) {
#pragma unroll
      for (int i = 0; i < 2; ++i)
#pragma unroll
        for (int r = 0; r < 4; ++r) {
          const int token = (m0 + wm + i * 16 + rq + r) & 255;
          u16* dst = ob2 + ((size_t)bh * 256 + token) * 64 + rl;
#pragma unroll
          for (int j = 0; j < 4; ++j) dst[j * 16] = f2bf(acc[i][j][r] * S);
        }
    } else {
      const float* nw = region ? nw_k : nw_q;
      u16* obuf = region ? ob1 : ob0;
      float wv[4];
#pragma unroll
      for (int j = 0; j < 4; ++j) wv[j] = nw[j * 16 + rl];
      const float f0 = __powf(10000.f, -(float)(2 * rl) * (1.f / 64.f));
      const float f1 = __powf(10000.f, -(float)(2 * (16 + rl)) * (1.f / 64.f));
#pragma unroll
      for (int i = 0; i < 2; ++i) {
        float va[4][4];
        float ss[4];
#pragma unroll
        for (int r = 0; r < 4; ++r) {
          ss[r] = 0.f;
#pragma unroll
          for (int j = 0; j < 4; ++j) {
            va[j][r] = acc[i][j][r] * S;
            ss[r] += va[j][r] * va[j][r];
          }
        }
#pragma unroll
        for (int off = 1; off < 16; off <<= 1)
#pragma unroll
          for (int r = 0; r < 4; ++r) ss[r] += __shfl_xor(ss[r], off, 64);
#pragma unroll
        for (int r = 0; r < 4; ++r) {
          const int token = (m0 + wm + i * 16 + rq + r) & 255;
          const float rms = rsqrtf(ss[r] * (1.f / 64.f) + 1e-6f);
          float nv[4];
#pragma unroll
          for (int j = 0; j < 4; ++j) nv[j] = va[j][r] * rms * wv[j];
          float s0, c0, s1, c1;
          __sincosf((float)token * f0, &s0, &c0);
          __sincosf((float)token * f1, &s1, &c1);
          u16* dst = obuf + ((size_t)bh * 256 + token) * 64 + rl;
          dst[0]  = f2bf(nv[0] * c0 - nv[2] * s0);
          dst[16] = f2bf(nv[1] * c1 - nv[3] * s1);
          dst[32] = f2bf(nv[2] * c0 + nv[0] * s0);
          dst[48] = f2bf(nv[3] * c1 + nv[1] * s1);
        }
      }
    }
  } else if constexpr (EPI == 3) {
    const int ubase = ((n0 + wn) >> 1) + rl;
#pragma unroll
    for (int i = 0; i < 2; ++i)
#pragma unroll
      for (int r = 0; r < 4; ++r) {
        const int row = m0 + wm + i * 16 + rq + r;
        u8* dst = h1o + (size_t)row * 2816 + ubase;
#pragma unroll
        for (int p = 0; p < 2; ++p) {
          const float a = acc[i][2 * p][r] * S;
          const float b3 = acc[i][2 * p + 1][r] * S;
          dst[p * 16] = (u8)f2f8(silu_f(a) * b3);
        }
      }
  }
}

// ---------------------------------------------------------------------------
// Weight conversion (all 4 layers per dispatch), f32 -> fp8 with x16 scale.
// Layer stride in WB: 12713984 B (qkv 3145728 | proj 1048576 | w13 5636096 |
// w2 2883584).
// ---------------------------------------------------------------------------
__global__ __launch_bounds__(256) void conv_qp8_kernel(
    const float* __restrict__ qkvw, const float* __restrict__ projw,
    u8* __restrict__ WB)
{
  for (int g = blockIdx.x * 256 + threadIdx.x; g < 4194304; g += gridDim.x * 256) {
    const int e4 = g * 4;
    const float* src;
    u8* dst;
    if (e4 < 12582912) {
      const int d = e4 / 3145728, off = e4 % 3145728;
      src = qkvw + e4;
      dst = WB + (size_t)d * 12713984 + off;
    } else {
      const int rel = e4 - 12582912;
      const int d = rel / 1048576, off = rel % 1048576;
      src = projw + rel;
      dst = WB + (size_t)d * 12713984 + 3145728 + off;
    }
    float4 v = *(const float4*)src;
    *(u32*)dst = pk4f8(v.x * 16.f, v.y * 16.f, v.z * 16.f, v.w * 16.f);
  }
}

__global__ __launch_bounds__(256) void conv_w138_kernel(
    const float* __restrict__ w1, const float* __restrict__ w3,
    u8* __restrict__ WB)
{
  const int blk = blockIdx.x;
  const int d = blk / 5504, rW = blk % 5504;
  const int t = rW >> 5, s = rW & 31;
  const int unit = 16 * t + (s & 15);
  u8* dst = WB + (size_t)d * 12713984 + 4194304 + (size_t)rW * 1024 + threadIdx.x * 4;
  if (unit < 2730) {
    const float* src = ((s < 16) ? w1 : w3) + (size_t)d * 2795520 + (size_t)unit * 1024;
    float4 v = *(const float4*)(src + threadIdx.x * 4);
    *(u32*)dst = pk4f8(v.x * 16.f, v.y * 16.f, v.z * 16.f, v.w * 16.f);
  } else {
    *(u32*)dst = 0;
  }
}

__global__ __launch_bounds__(256) void conv_w28_kernel(
    const float* __restrict__ w2, u8* __restrict__ WB)
{
  const int d = blockIdx.x >> 10, r = blockIdx.x & 1023;
  const float* src = w2 + (size_t)d * 2795520 + (size_t)r * 2730;
  u8* dst = WB + (size_t)d * 12713984 + 9830400 + (size_t)r * 2816;
  for (int c = threadIdx.x * 4; c < 2816; c += 1024) {
    float v[4];
#pragma unroll
    for (int i = 0; i < 4; ++i)
      v[i] = (c + i < 2730) ? src[c + i] * 16.f : 0.f;
    *(u32*)(dst + c) = pk4f8(v[0], v[1], v[2], v[3]);
  }
}

// zero h1 pad cols [2752,2816)
__global__ __launch_bounds__(256) void zt_kernel(u8* __restrict__ h1) {
  const int idx = blockIdx.x * 256 + threadIdx.x;  // 32768
  const int row = idx >> 4, c = idx & 15;
  *(u32*)(h1 + (size_t)row * 2816 + 2752 + c * 4) = 0;
}

// ---------------------------------------------------------------------------
// Conditioning: sc[b,j] = silu(ce[y[b],j] + sum_c w2[j,c]*silu(s*w1[c]+b1[c]) + b2[j])
// ---------------------------------------------------------------------------
__global__ __launch_bounds__(64) void cond_kernel(
    const float* __restrict__ cfg_s, const float* __restrict__ w1,
    const float* __restrict__ b1, const float* __restrict__ w2,
    const float* __restrict__ b2, const float* __restrict__ ce,
    const int* __restrict__ y, float* __restrict__ sc)
{
  const int j = blockIdx.x, b = blockIdx.y, lane = threadIdx.x;
  const float s = cfg_s[b];
  const float4* wr = (const float4*)(w2 + (size_t)j * 1024);
  const float4* w1r = (const float4*)w1;
  const float4* b1r = (const float4*)b1;
  float acc = 0.f;
#pragma unroll
  for (int rep = 0; rep < 4; ++rep) {
    const int c = rep * 64 + lane;
    float4 w = wr[c];
    float4 a = w1r[c];
    float4 bb = b1r[c];
    acc += w.x * silu_f(s * a.x + bb.x) + w.y * silu_f(s * a.y + bb.y) +
           w.z * silu_f(s * a.z + bb.z) + w.w * silu_f(s * a.w + bb.w);
  }
  acc = waveAllSum(acc);
  if (lane == 0) {
    float v = ce[(size_t)y[b] * 1024 + j] + acc + b2[j];
    sc[(size_t)b * 1024 + j] = silu_f(v);
  }
}

// ada modulations, all 4 layers in one dispatch (grid 24576)
__global__ __launch_bounds__(64) void modlin_ada_kernel(
    const float* __restrict__ adaw, const float* __restrict__ adab,
    const float* __restrict__ sc, float* __restrict__ mods)
{
  const int g = blockIdx.x;
  const int d = g / 6144, j = g % 6144;
  const int lane = threadIdx.x;
  const float4* wr = (const float4*)(adaw + ((size_t)d * 6144 + j) * 1024);
  float acc[8];
#pragma unroll
  for (int b = 0; b < 8; ++b) acc[b] = 0.f;
#pragma unroll
  for (int rep = 0; rep < 4; ++rep) {
    float4 wv = wr[rep * 64 + lane];
#pragma unroll
    for (int b = 0; b < 8; ++b) {
      float4 s = ((const float4*)(sc + (size_t)b * 1024))[rep * 64 + lane];
      acc[b] += wv.x * s.x + wv.y * s.y + wv.z * s.z + wv.w * s.w;
    }
  }
#pragma unroll
  for (int b = 0; b < 8; ++b) acc[b] = waveAllSum(acc[b]);
  if (lane == 0) {
    const float bb = adab[(size_t)d * 6144 + j];
    float* out = mods + (size_t)d * 49152 + j;
#pragma unroll
    for (int b = 0; b < 8; ++b) out[(size_t)b * 6144] = acc[b] + bb;
  }
}

__global__ __launch_bounds__(64) void modlin_kernel(
    const float* __restrict__ w, const float* __restrict__ bias,
    const float* __restrict__ sc, float* __restrict__ out, int ostride)
{
  const int j = blockIdx.x, lane = threadIdx.x;
  const float4* wr = (const float4*)(w + (size_t)j * 1024);
  float acc[8];
#pragma unroll
  for (int b = 0; b < 8; ++b) acc[b] = 0.f;
#pragma unroll
  for (int rep = 0; rep < 4; ++rep) {
    float4 wv = wr[rep * 64 + lane];
#pragma unroll
    for (int b = 0; b < 8; ++b) {
      float4 s = ((const float4*)(sc + (size_t)b * 1024))[rep * 64 + lane];
      acc[b] += wv.x * s.x + wv.y * s.y + wv.z * s.z + wv.w * s.w;
    }
  }
#pragma unroll
  for (int b = 0; b < 8; ++b) acc[b] = waveAllSum(acc[b]);
  if (lane == 0) {
    const float bb = bias[j];
#pragma unroll
    for (int b = 0; b < 8; ++b) out[(size_t)b * ostride + j] = acc[b] + bb;
  }
}

// ---------------------------------------------------------------------------
// Patch embed
// ---------------------------------------------------------------------------
__global__ __launch_bounds__(256) void patch_kernel(
    const float* __restrict__ x, const float* __restrict__ pw,
    const float* __restrict__ pb, const float* __restrict__ pos,
    float* __restrict__ xc)
{
  const int n = blockIdx.x, b = blockIdx.y, tid = threadIdx.x;
  __shared__ float pv[16];
  if (tid < 16) {
    const int ci = tid >> 2, pi = (tid >> 1) & 1, pj = tid & 1;
    const int i = n >> 4, j = n & 15;
    pv[tid] = x[((size_t)(b * 4 + ci) * 32 + i * 2 + pi) * 32 + j * 2 + pj];
  }
  __syncthreads();
#pragma unroll
  for (int qq = 0; qq < 4; ++qq) {
    const int c = qq * 256 + tid;
    const float4* wr = (const float4*)(pw + (size_t)c * 16);
    float acc = pb[c] + pos[(size_t)n * 1024 + c];
#pragma unroll
    for (int g = 0; g < 4; ++g) {
      float4 w = wr[g];
      acc += w.x * pv[g * 4] + w.y * pv[g * 4 + 1] + w.z * pv[g * 4 + 2] + w.w * pv[g * 4 + 3];
    }
    xc[((size_t)b * 256 + n) * 1024 + c] = acc;
  }
}

// ---------------------------------------------------------------------------
// RMSNorm + adaLN modulate -> fp8
// ---------------------------------------------------------------------------
__global__ __launch_bounds__(256) void normmod8_kernel(
    const float* __restrict__ xc, const float* __restrict__ w,
    const float* __restrict__ mods, int mult_off, int shift_off,
    u8* __restrict__ out)
{
  const int m = blockIdx.x, b = m >> 8, tid = threadIdx.x;
  const float* row = xc + (size_t)m * 1024;
  float4 v = *(const float4*)(row + tid * 4);
  float ss = v.x * v.x + v.y * v.y + v.z * v.z + v.w * v.w;
  ss = waveAllSum(ss);
  __shared__ float red[4];
  if ((tid & 63) == 0) red[tid >> 6] = ss;
  __syncthreads();
  const float tot = red[0] + red[1] + red[2] + red[3];
  const float r = rsqrtf(tot * (1.f / 1024.f) + 1e-6f);
  const float* mb = mods + (size_t)b * 6144;
  const int c = tid * 4;
  float4 wv = *(const float4*)(w + c);
  float4 mu = *(const float4*)(mb + mult_off + c);
  float4 sh = *(const float4*)(mb + shift_off + c);
  u32 p = pk4f8(v.x * r * wv.x * (1.f + mu.x) + sh.x,
                v.y * r * wv.y * (1.f + mu.y) + sh.y,
                v.z * r * wv.z * (1.f + mu.z) + sh.z,
                v.w * r * wv.w * (1.f + mu.w) + sh.w);
  *(u32*)(out + (size_t)m * 1024 + c) = p;
}

// ---------------------------------------------------------------------------
// MFMA attention (bf16 q/k/v in, fp8 out at o[b,n,h,d])
// ---------------------------------------------------------------------------
__global__ __launch_bounds__(256) void attn_kernel(
    const u16* __restrict__ qb, const u16* __restrict__ kb,
    const u16* __restrict__ vb, u8* __restrict__ o)
{
  __shared__ alignas(16) u16 Kt[128][72];
  __shared__ alignas(16) u16 Vtt[64][136];
  __shared__ alignas(16) u16 Pw[4][16][136];
  const int bh = blockIdx.x;
  const int qbase = blockIdx.y * 64;
  const int tid = threadIdx.x;
  const int lane = tid & 63;
  const int wave = tid >> 6;
  const int rl = lane & 15;
  const int kq = (lane >> 4) * 8;
  const int rowg = (lane >> 4) * 4;

  const int q0 = qbase + wave * 16;
  const u16* qsrc = qb + ((size_t)bh * 256 + q0 + rl) * 64 + kq;
  const bf16x8 a0 = *(const bf16x8*)(qsrc);
  const bf16x8 a1 = *(const bf16x8*)(qsrc + 32);

  float m[4], l[4];
  f32x4 oacc[4];
#pragma unroll
  for (int r = 0; r < 4; ++r) { m[r] = -1e30f; l[r] = 0.f; }
#pragma unroll
  for (int dt = 0; dt < 4; ++dt) oacc[dt] = (f32x4){0.f, 0.f, 0.f, 0.f};

  for (int kt = 0; kt < 2; ++kt) {
    __syncthreads();
#pragma unroll
    for (int c = 0; c < 4; ++c) {
      const int flat = c * 256 + tid;
      const int row = flat >> 3;
      const int col = (flat & 7) * 8;
      uint4 v = *(const uint4*)(kb + ((size_t)bh * 256 + kt * 128 + row) * 64 + col);
      *(uint4*)&Kt[row][col] = v;
    }
    {
      const int tt = tid & 63;
      const int dh = tid >> 6;
      const int r0 = tt * 2;
      const u16* s0 = vb + ((size_t)bh * 256 + kt * 128 + r0) * 64 + dh * 16;
      const u16* s1 = s0 + 64;
#pragma unroll
      for (int g = 0; g < 2; ++g) {
        uint4 A = *(const uint4*)(s0 + g * 8);
        uint4 B = *(const uint4*)(s1 + g * 8);
        const u32 aw[4] = {A.x, A.y, A.z, A.w};
        const u32 bw[4] = {B.x, B.y, B.z, B.w};
#pragma unroll
        for (int q = 0; q < 4; ++q) {
          const int d2 = dh * 16 + g * 8 + q * 2;
          const u32 lo = (aw[q] & 0xffffu) | (bw[q] << 16);
          const u32 hi = (aw[q] >> 16) | (bw[q] & 0xffff0000u);
          *(u32*)&Vtt[d2][r0] = lo;
          *(u32*)&Vtt[d2 + 1][r0] = hi;
        }
      }
    }
    __syncthreads();

    f32x4 sacc[8];
#pragma unroll
    for (int t = 0; t < 8; ++t) sacc[t] = (f32x4){0.f, 0.f, 0.f, 0.f};
#pragma unroll
    for (int t = 0; t < 8; ++t) {
      bf16x8 k0 = *(const bf16x8*)&Kt[t * 16 + rl][kq];
      bf16x8 k1 = *(const bf16x8*)&Kt[t * 16 + rl][32 + kq];
      sacc[t] = __builtin_amdgcn_mfma_f32_16x16x32_bf16(a0, k0, sacc[t], 0, 0, 0);
      sacc[t] = __builtin_amdgcn_mfma_f32_16x16x32_bf16(a1, k1, sacc[t], 0, 0, 0);
    }
    float cmax[4];
#pragma unroll
    for (int r = 0; r < 4; ++r) cmax[r] = sacc[0][r];
#pragma unroll
    for (int t = 1; t < 8; ++t)
#pragma unroll
      for (int r = 0; r < 4; ++r) cmax[r] = fmaxf(cmax[r], sacc[t][r]);
#pragma unroll
    for (int off = 1; off < 16; off <<= 1)
#pragma unroll
      for (int r = 0; r < 4; ++r) cmax[r] = fmaxf(cmax[r], __shfl_xor(cmax[r], off, 64));
#pragma unroll
    for (int r = 0; r < 4; ++r) {
      const float mn = fmaxf(m[r], cmax[r]);
      const float corr = __expf((m[r] - mn) * 0.125f);
      l[r] *= corr;
#pragma unroll
      for (int dt = 0; dt < 4; ++dt) oacc[dt][r] *= corr;
      m[r] = mn;
    }
    float lsum[4] = {0.f, 0.f, 0.f, 0.f};
#pragma unroll
    for (int t = 0; t < 8; ++t)
#pragma unroll
      for (int r = 0; r < 4; ++r) {
        const float p = __expf((sacc[t][r] - m[r]) * 0.125f);
        lsum[r] += p;
        Pw[wave][rowg + r][t * 16 + rl] = f2bf(p);
      }
#pragma unroll
    for (int off = 1; off < 16; off <<= 1)
#pragma unroll
      for (int r = 0; r < 4; ++r) lsum[r] += __shfl_xor(lsum[r], off, 64);
#pragma unroll
    for (int r = 0; r < 4; ++r) l[r] += lsum[r];
#pragma unroll
    for (int ks = 0; ks < 4; ++ks) {
      bf16x8 pa = *(const bf16x8*)&Pw[wave][rl][ks * 32 + kq];
#pragma unroll
      for (int dt = 0; dt < 4; ++dt) {
        bf16x8 vf = *(const bf16x8*)&Vtt[dt * 16 + rl][ks * 32 + kq];
        oacc[dt] = __builtin_amdgcn_mfma_f32_16x16x32_bf16(pa, vf, oacc[dt], 0, 0, 0);
      }
    }
  }
  const int b = bh >> 4, h = bh & 15;
#pragma unroll
  for (int r = 0; r < 4; ++r) {
    const float inv = 1.f / l[r];
    const int qrow = q0 + rowg + r;
    u8* dst = o + (((size_t)b * 256 + qrow) * 16 + h) * 64 + rl;
#pragma unroll
    for (int dt = 0; dt < 4; ++dt)
      dst[dt * 16] = (u8)f2f8(oacc[dt][r] * inv);
  }
}

// ---------------------------------------------------------------------------
// Final LayerNorm + modulate -> bf16
// ---------------------------------------------------------------------------
__global__ __launch_bounds__(256) void lnmod_kernel(
    const float* __restrict__ xc, const float* __restrict__ fmods,
    u16* __restrict__ out)
{
  const int m = blockIdx.x, b = m >> 8, tid = threadIdx.x;
  const float* row = xc + (size_t)m * 1024;
  float4 v = *(const float4*)(row + tid * 4);
  float s1 = v.x + v.y + v.z + v.w;
  float s2 = v.x * v.x + v.y * v.y + v.z * v.z + v.w * v.w;
  s1 = waveAllSum(s1);
  s2 = waveAllSum(s2);
  __shared__ float r1[4], r2[4];
  if ((tid & 63) == 0) { r1[tid >> 6] = s1; r2[tid >> 6] = s2; }
  __syncthreads();
  const float t1 = r1[0] + r1[1] + r1[2] + r1[3];
  const float t2 = r2[0] + r2[1] + r2[2] + r2[3];
  const float mean = t1 * (1.f / 1024.f);
  const float var = t2 * (1.f / 1024.f) - mean * mean;
  const float rr = rsqrtf(var + 1e-5f);
  const float* mb = fmods + (size_t)b * 2048;
  const int c = tid * 4;
  float4 sh = *(const float4*)(mb + c);
  float4 sl = *(const float4*)(mb + 1024 + c);
  union { u16 u[4]; uint2 v2; } pk;
  pk.u[0] = f2bf((v.x - mean) * rr * (1.f + sl.x) + sh.x);
  pk.u[1] = f2bf((v.y - mean) * rr * (1.f + sl.y) + sh.y);
  pk.u[2] = f2bf((v.z - mean) * rr * (1.f + sl.z) + sh.z);
  pk.u[3] = f2bf((v.w - mean) * rr * (1.f + sl.w) + sh.w);
  *(uint2*)(out + (size_t)m * 1024 + c) = pk.v2;
}

// ---------------------------------------------------------------------------
// Final linear (16 outputs) + unpatchify
// ---------------------------------------------------------------------------
__global__ __launch_bounds__(256) void final_kernel(
    const u16* __restrict__ xfin, const float* __restrict__ w,
    const float* __restrict__ bias, float* __restrict__ out)
{
  const int tid = threadIdx.x;
  const int m = blockIdx.x * 16 + (tid >> 4);
  const int j = tid & 15;
  const u16* xr = xfin + (size_t)m * 1024;
  const float* wr = w + (size_t)j * 1024;
  float acc = 0.f;
  for (int k = 0; k < 1024; k += 8) {
    uint4 xv = *(const uint4*)(xr + k);
    const u16* xu = (const u16*)&xv;
    float4 w0 = *(const float4*)(wr + k);
    float4 w1 = *(const float4*)(wr + k + 4);
    acc += bf2f(xu[0]) * w0.x + bf2f(xu[1]) * w0.y + bf2f(xu[2]) * w0.z + bf2f(xu[3]) * w0.w;
    acc += bf2f(xu[4]) * w1.x + bf2f(xu[5]) * w1.y + bf2f(xu[6]) * w1.z + bf2f(xu[7]) * w1.w;
  }
  acc += bias[j];
  const int b = m >> 8, n = m & 255;
  const int i = n >> 4, jj = n & 15;
  const int pi = (j >> 3) & 1, pj = (j >> 2) & 1, oc = j & 3;
  out[((size_t)(b * 4 + oc) * 32 + i * 2 + pi) * 32 + jj * 2 + pj] = acc;
}

// ---------------------------------------------------------------------------
extern "C" void kernel_launch(void* const* d_in, const int* in_sizes, int n_in,
                              void* d_out, int out_size, void* d_ws, size_t ws_size,
                              hipStream_t stream) {
  const float* x       = (const float*)d_in[0];
  const int*   y       = (const int*)  d_in[1];
  const float* cfg_s   = (const float*)d_in[2];
  const float* patch_w = (const float*)d_in[3];
  const float* patch_b = (const float*)d_in[4];
  const float* pos_e   = (const float*)d_in[5];
  const float* class_e = (const float*)d_in[6];
  const float* cfg_w1  = (const float*)d_in[7];
  const float* cfg_b1  = (const float*)d_in[8];
  const float* cfg_w2  = (const float*)d_in[9];
  const float* cfg_b2  = (const float*)d_in[10];
  const float* n1w     = (const float*)d_in[11];
  const float* n2w     = (const float*)d_in[12];
  const float* qkvw    = (const float*)d_in[13];
  const float* projw   = (const float*)d_in[14];
  const float* projb   = (const float*)d_in[15];
  const float* qnw     = (const float*)d_in[16];
  const float* knw     = (const float*)d_in[17];
  const float* w1      = (const float*)d_in[18];
  const float* w2      = (const float*)d_in[19];
  const float* w3      = (const float*)d_in[20];
  const float* adaw    = (const float*)d_in[21];
  const float* adab    = (const float*)d_in[22];
  const float* finaw   = (const float*)d_in[23];
  const float* finab   = (const float*)d_in[24];
  const float* flw     = (const float*)d_in[25];
  const float* flb     = (const float*)d_in[26];
  (void)in_sizes; (void)n_in; (void)out_size;

  char* ws = (char*)d_ws;
  const size_t MB = 1024 * 1024;
  if (ws_size < 96 * MB) return;
  float* sc    = (float*)(ws + 32 * 1024);             // 32KB
  float* mods  = (float*)(ws + 64 * 1024);             // 768KB (4 layers x 8 x 6144)
  float* fmods = (float*)(ws + 64 * 1024 + 786432);    // 64KB
  float* xc    = (float*)(ws + 1 * MB);                // 8MB
  u8*    xm8   = (u8*)   (ws + 9 * MB);                // 2MB (normmod out / attn out)
  u16*   qbuf  = (u16*)  (ws + 11 * MB);               // 4MB
  u16*   kbuf  = (u16*)  (ws + 15 * MB);               // 4MB
  u16*   vbuf  = (u16*)  (ws + 19 * MB);               // 4MB
  u8*    h18   = (u8*)   (ws + 23 * MB);               // 5.7MB (2048 x 2816 fp8)
  u16*   lnbuf = (u16*)  (ws + 29 * MB);               // 4MB bf16
  u8*    WB    = (u8*)   (ws + 33 * MB);               // 48.5MB fp8 weights
  const size_t LSTR = 12713984;

  cond_kernel<<<dim3(1024, 8), 64, 0, stream>>>(cfg_s, cfg_w1, cfg_b1, cfg_w2,
                                                cfg_b2, class_e, y, sc);
  modlin_ada_kernel<<<24576, 64, 0, stream>>>(adaw, adab, sc, mods);
  modlin_kernel<<<2048, 64, 0, stream>>>(finaw, finab, sc, fmods, 2048);
  patch_kernel<<<dim3(256, 8), 256, 0, stream>>>(x, patch_w, patch_b, pos_e, xc);
  conv_qp8_kernel<<<8192, 256, 0, stream>>>(qkvw, projw, WB);
  conv_w138_kernel<<<22016, 256, 0, stream>>>(w1, w3, WB);
  conv_w28_kernel<<<4096, 256, 0, stream>>>(w2, WB);
  zt_kernel<<<128, 256, 0, stream>>>(h18);

  for (int d = 0; d < 4; ++d) {
    const float* md = mods + (size_t)d * 49152;
    u8* WL = WB + (size_t)d * LSTR;
    normmod8_kernel<<<2048, 256, 0, stream>>>(xc, n1w + d * 1024, md, 1024, 0, xm8);
    gemm8_t<2><<<768, 256, 0, stream>>>(xm8, 1024, WL, 1024, 8, 32,
                                        nullptr, nullptr, nullptr,
                                        qbuf, kbuf, vbuf, nullptr,
                                        qnw + d * 64, knw + d * 64);
    attn_kernel<<<dim3(128, 4), 256, 0, stream>>>(qbuf, kbuf, vbuf, xm8);
    gemm8_t<1><<<256, 256, 0, stream>>>(xm8, 1024, WL + 3145728, 1024, 8, 32,
                                        xc, md + 2048, projb + d * 1024,
                                        nullptr, nullptr, nullptr, nullptr,
                                        nullptr, nullptr);
    normmod8_kernel<<<2048, 256, 0, stream>>>(xc, n2w + d * 1024, md, 4096, 3072, xm8);
    gemm8_t<3><<<1376, 256, 0, stream>>>(xm8, 1024, WL + 4194304, 1024, 8, 32,
                                         nullptr, nullptr, nullptr,
                                         nullptr, nullptr, nullptr, h18,
                                         nullptr, nullptr);
    gemm8_t<1><<<256, 256, 0, stream>>>(h18, 2816, WL + 9830400, 2816, 22, 32,
                                        xc, md + 5120, nullptr,
                                        nullptr, nullptr, nullptr, nullptr,
                                        nullptr, nullptr);
  }

  lnmod_kernel<<<2048, 256, 0, stream>>>(xc, fmods, lnbuf);
  final_kernel<<<128, 256, 0, stream>>>(lnbuf, flw, flb, (float*)d_out);
}

// Round 7
// 587.376 us; speedup vs baseline: 4.1167x; 1.0445x over previous
//
#include <hip/hip_runtime.h>

typedef unsigned char u8;
typedef unsigned short u16;
typedef unsigned int u32;
typedef float f32x4 __attribute__((ext_vector_type(4)));
typedef __bf16 bf16x8 __attribute__((ext_vector_type(8)));

#define DEV __device__ __forceinline__

DEV u16 f2bf(float f) {
  u32 u = __builtin_bit_cast(u32, f);
  u += 0x7fffu + ((u >> 16) & 1u);
  return (u16)(u >> 16);
}
DEV float bf2f(u16 u) { return __builtin_bit_cast(float, (u32)u << 16); }
// f32 -> OCP e4m3fn (RNE, saturating)
DEV u32 f2f8(float f) {
  u32 u = __builtin_bit_cast(u32, f);
  u32 s = (u >> 31) << 7;
  float a = __builtin_fabsf(f);
  if (a >= 448.f) return s | 0x7Eu;
  if (a < 0.015625f) {
    int m = (int)(a * 512.f + 0.5f);
    return s | (u32)m;
  }
  u32 b = __builtin_bit_cast(u32, a);
  b += 0x7FFFFu + ((b >> 20) & 1u);
  u32 E = (b >> 23) - 120u;
  if (E > 15u) return s | 0x7Eu;
  return s | (E << 3) | ((b >> 20) & 7u);
}
DEV u32 pk4f8(float x, float y, float z, float w) {
  return f2f8(x) | (f2f8(y) << 8) | (f2f8(z) << 16) | (f2f8(w) << 24);
}
DEV float waveAllSum(float x) {
#pragma unroll
  for (int off = 32; off > 0; off >>= 1) x += __shfl_xor(x, off, 64);
  return x;
}
DEV float silu_f(float x) { return x / (1.f + __expf(-x)); }

DEV void gll16(const void* g, void* l) {
  __builtin_amdgcn_global_load_lds(
      (const __attribute__((address_space(1))) void*)g,
      (__attribute__((address_space(3))) void*)l, 16, 0, 0);
}

// ---------------------------------------------------------------------------
// FP8 GEMM: C = A_fp8[m,k] * (16*W)_fp8[n,k]^T * (1/16); BM x BN tile,
// BK=128, 4 waves (2x2), dbuf global_load_lds + counted vmcnt.
// LDS rows 128B as long[16]; 16B-chunk XOR swizzle by row&7 on global SOURCE
// (linear LDS dest, rule #21) and on the ds_read index.
// EPI: 1 = residual RX += gm*(acc*S+bias); 2 = qk-RMSNorm+RoPE+v -> bf16
// q/k/v; 3 = SwiGLU pair-fuse -> h1 fp8 (w1/w3 interleaved 16-unit groups).
// ---------------------------------------------------------------------------
template<int BM, int BN, int EPI>
__global__ __launch_bounds__(256, 3) void gemm8_t(
    const u8* __restrict__ A, int lda,
    const u8* __restrict__ W, int ldw,
    int Ksteps, int nbx,
    float* __restrict__ RX, const float* __restrict__ gmods,
    const float* __restrict__ bias,
    u16* __restrict__ ob0, u16* __restrict__ ob1, u16* __restrict__ ob2,
    u8* __restrict__ h1o,
    const float* __restrict__ nw_q, const float* __restrict__ nw_k)
{
  constexpr int NJ = BN / 32;           // 16-col tiles per wave
  __shared__ long As[2][BM][16];
  __shared__ long Ws[2][BN][16];
  const int tid = threadIdx.x;
  const int lane = tid & 63;
  const int wave = tid >> 6;
  const int nwg = gridDim.x;
  const int cpx = nwg >> 3;
  const int fb = blockIdx.x;
  const int idx = (fb & 7) * cpx + (fb >> 3);
  const int m0 = (idx % nbx) * BM;
  const int n0 = (idx / nbx) * BN;
  const int wm = (wave >> 1) * 32;
  const int wn = (wave & 1) * (BN / 2);
  const int rl = lane & 15;
  const int qq = lane >> 4;            // 0..3
  const u8* Abase = A + (size_t)m0 * lda;
  const u8* Wbase = W + (size_t)n0 * ldw;

  f32x4 acc[2][NJ];
#pragma unroll
  for (int i = 0; i < 2; ++i)
#pragma unroll
    for (int j = 0; j < NJ; ++j) acc[i][j] = (f32x4){0.f, 0.f, 0.f, 0.f};

  auto STAGE = [&](int buf, int k0) {
#pragma unroll
    for (int c = 0; c < BM / 32; ++c) {
      const int flat = c * 256 + tid;
      const int row = flat >> 3;
      const int ch = flat & 7;
      gll16(Abase + (size_t)row * lda + k0 + ((ch ^ (row & 7)) << 4),
            &As[buf][row][ch * 2]);
    }
#pragma unroll
    for (int c = 0; c < BN / 32; ++c) {
      const int flat = c * 256 + tid;
      const int row = flat >> 3;
      const int ch = flat & 7;
      gll16(Wbase + (size_t)row * ldw + k0 + ((ch ^ (row & 7)) << 4),
            &Ws[buf][row][ch * 2]);
    }
  };

  STAGE(0, 0);
  for (int kt = 0; kt < Ksteps; ++kt) {
    const int buf = kt & 1;
    if (kt + 1 < Ksteps) {
      STAGE(buf ^ 1, (kt + 1) * 128);
      if constexpr (BM + BN == 192)
        asm volatile("s_waitcnt vmcnt(6)" ::: "memory");
      else
        asm volatile("s_waitcnt vmcnt(4)" ::: "memory");
    } else {
      asm volatile("s_waitcnt vmcnt(0)" ::: "memory");
    }
    __builtin_amdgcn_s_barrier();
    __builtin_amdgcn_sched_barrier(0);
#pragma unroll
    for (int kk = 0; kk < 4; ++kk) {
      const int lo = (((kk * 2 + (qq >> 1)) ^ (rl & 7)) << 1) | (qq & 1);
      long af0 = As[buf][wm + rl][lo];
      long af1 = As[buf][wm + 16 + rl][lo];
      long bw[NJ];
#pragma unroll
      for (int j = 0; j < NJ; ++j) bw[j] = Ws[buf][wn + j * 16 + rl][lo];
#pragma unroll
      for (int j = 0; j < NJ; ++j) {
        acc[0][j] = __builtin_amdgcn_mfma_f32_16x16x32_fp8_fp8(af0, bw[j], acc[0][j], 0, 0, 0);
        acc[1][j] = __builtin_amdgcn_mfma_f32_16x16x32_fp8_fp8(af1, bw[j], acc[1][j], 0, 0, 0);
      }
    }
    __builtin_amdgcn_sched_barrier(0);
    __builtin_amdgcn_s_barrier();
  }

  constexpr float S = 0.0625f;  // 1/16 weight descale
  const int rq = qq * 4;
  if constexpr (EPI == 1) {
    const int b = m0 >> 8;
    const float* gm = gmods + (size_t)b * 6144;
#pragma unroll
    for (int j = 0; j < NJ; ++j) {
      const int n = n0 + wn + j * 16 + rl;
      const float g = gm[n];
      const float bv = bias ? bias[n] : 0.f;
#pragma unroll
      for (int i = 0; i < 2; ++i) {
        const int mrow = m0 + wm + i * 16 + rq;
#pragma unroll
        for (int r = 0; r < 4; ++r) {
          float* p = RX + (size_t)(mrow + r) * 1024 + n;
          *p += g * (acc[i][j][r] * S + bv);
        }
      }
    }
  } else if constexpr (EPI == 2) {
    const int region = n0 >> 10;  // 0=q,1=k,2=v
    const int h = ((n0 + wn) >> 6) & 15;
    const int bh = (m0 >> 8) * 16 + h;
    if (region == 2) {
#pragma unroll
      for (int i = 0; i < 2; ++i)
#pragma unroll
        for (int r = 0; r < 4; ++r) {
          const int token = (m0 + wm + i * 16 + rq + r) & 255;
          u16* dst = ob2 + ((size_t)bh * 256 + token) * 64 + rl;
#pragma unroll
          for (int j = 0; j < 4; ++j) dst[j * 16] = f2bf(acc[i][j][r] * S);
        }
    } else {
      const float* nw = region ? nw_k : nw_q;
      u16* obuf = region ? ob1 : ob0;
      float wv[4];
#pragma unroll
      for (int j = 0; j < 4; ++j) wv[j] = nw[j * 16 + rl];
      const float f0 = __powf(10000.f, -(float)(2 * rl) * (1.f / 64.f));
      const float f1 = __powf(10000.f, -(float)(2 * (16 + rl)) * (1.f / 64.f));
#pragma unroll
      for (int i = 0; i < 2; ++i) {
        float va[4][4];
        float ss[4];
#pragma unroll
        for (int r = 0; r < 4; ++r) {
          ss[r] = 0.f;
#pragma unroll
          for (int j = 0; j < 4; ++j) {
            va[j][r] = acc[i][j][r] * S;
            ss[r] += va[j][r] * va[j][r];
          }
        }
#pragma unroll
        for (int off = 1; off < 16; off <<= 1)
#pragma unroll
          for (int r = 0; r < 4; ++r) ss[r] += __shfl_xor(ss[r], off, 64);
#pragma unroll
        for (int r = 0; r < 4; ++r) {
          const int token = (m0 + wm + i * 16 + rq + r) & 255;
          const float rms = rsqrtf(ss[r] * (1.f / 64.f) + 1e-6f);
          float nv[4];
#pragma unroll
          for (int j = 0; j < 4; ++j) nv[j] = va[j][r] * rms * wv[j];
          float s0, c0, s1, c1;
          __sincosf((float)token * f0, &s0, &c0);
          __sincosf((float)token * f1, &s1, &c1);
          u16* dst = obuf + ((size_t)bh * 256 + token) * 64 + rl;
          dst[0]  = f2bf(nv[0] * c0 - nv[2] * s0);
          dst[16] = f2bf(nv[1] * c1 - nv[3] * s1);
          dst[32] = f2bf(nv[2] * c0 + nv[0] * s0);
          dst[48] = f2bf(nv[3] * c1 + nv[1] * s1);
        }
      }
    }
  } else if constexpr (EPI == 3) {
    const int ubase = ((n0 + wn) >> 1) + rl;
#pragma unroll
    for (int i = 0; i < 2; ++i)
#pragma unroll
      for (int r = 0; r < 4; ++r) {
        const int row = m0 + wm + i * 16 + rq + r;
        u8* dst = h1o + (size_t)row * 2816 + ubase;
#pragma unroll
        for (int p = 0; p < 2; ++p) {
          const float a = acc[i][2 * p][r] * S;
          const float b3 = acc[i][2 * p + 1][r] * S;
          dst[p * 16] = (u8)f2f8(silu_f(a) * b3);
        }
      }
  }
}

// ---------------------------------------------------------------------------
// Weight conversion (all 4 layers per dispatch), f32 -> fp8 with x16 scale.
// Layer stride in WB: 12713984 B (qkv | proj | w13 | w2-padded).
// ---------------------------------------------------------------------------
__global__ __launch_bounds__(256) void conv_qp8_kernel(
    const float* __restrict__ qkvw, const float* __restrict__ projw,
    u8* __restrict__ WB)
{
  for (int g = blockIdx.x * 256 + threadIdx.x; g < 4194304; g += gridDim.x * 256) {
    const int e4 = g * 4;
    const float* src;
    u8* dst;
    if (e4 < 12582912) {
      const int d = e4 / 3145728, off = e4 % 3145728;
      src = qkvw + e4;
      dst = WB + (size_t)d * 12713984 + off;
    } else {
      const int rel = e4 - 12582912;
      const int d = rel / 1048576, off = rel % 1048576;
      src = projw + rel;
      dst = WB + (size_t)d * 12713984 + 3145728 + off;
    }
    float4 v = *(const float4*)src;
    *(u32*)dst = pk4f8(v.x * 16.f, v.y * 16.f, v.z * 16.f, v.w * 16.f);
  }
}

// w13 interleaved rows (32t..+15 = w1 units 16t.., +16..31 = w3), 4 rows/block
__global__ __launch_bounds__(256) void conv_w138_kernel(
    const float* __restrict__ w1, const float* __restrict__ w3,
    u8* __restrict__ WB)
{
  const int base = blockIdx.x * 4 + (threadIdx.x >> 6);  // global dst row
  const int d = base / 5504, rW = base % 5504;
  const int t = rW >> 5, s = rW & 31;
  const int unit = 16 * t + (s & 15);
  const int lane = threadIdx.x & 63;
  u8* dst = WB + (size_t)d * 12713984 + 4194304 + (size_t)rW * 1024;
  if (unit < 2730) {
    const float* src = ((s < 16) ? w1 : w3) + (size_t)d * 2795520 + (size_t)unit * 1024;
#pragma unroll
    for (int rep = 0; rep < 4; ++rep) {
      float4 v = *(const float4*)(src + rep * 256 + lane * 4);
      *(u32*)(dst + rep * 256 + lane * 4) = pk4f8(v.x * 16.f, v.y * 16.f, v.z * 16.f, v.w * 16.f);
    }
  } else {
#pragma unroll
    for (int rep = 0; rep < 4; ++rep)
      *(u32*)(dst + rep * 256 + lane * 4) = 0;
  }
}

__global__ __launch_bounds__(256) void conv_w28_kernel(
    const float* __restrict__ w2, u8* __restrict__ WB)
{
  const int d = blockIdx.x >> 10, r = blockIdx.x & 1023;
  const float* src = w2 + (size_t)d * 2795520 + (size_t)r * 2730;
  u8* dst = WB + (size_t)d * 12713984 + 9830400 + (size_t)r * 2816;
  for (int c = threadIdx.x * 4; c < 2816; c += 1024) {
    float v[4];
#pragma unroll
    for (int i = 0; i < 4; ++i)
      v[i] = (c + i < 2730) ? src[c + i] * 16.f : 0.f;
    *(u32*)(dst + c) = pk4f8(v[0], v[1], v[2], v[3]);
  }
}

// zero h1 pad cols [2752,2816)
__global__ __launch_bounds__(256) void zt_kernel(u8* __restrict__ h1) {
  const int idx = blockIdx.x * 256 + threadIdx.x;  // 32768
  const int row = idx >> 4, c = idx & 15;
  *(u32*)(h1 + (size_t)row * 2816 + 2752 + c * 4) = 0;
}

// ---------------------------------------------------------------------------
// Conditioning
// ---------------------------------------------------------------------------
__global__ __launch_bounds__(64) void cond_kernel(
    const float* __restrict__ cfg_s, const float* __restrict__ w1,
    const float* __restrict__ b1, const float* __restrict__ w2,
    const float* __restrict__ b2, const float* __restrict__ ce,
    const int* __restrict__ y, float* __restrict__ sc)
{
  const int j = blockIdx.x, b = blockIdx.y, lane = threadIdx.x;
  const float s = cfg_s[b];
  const float4* wr = (const float4*)(w2 + (size_t)j * 1024);
  const float4* w1r = (const float4*)w1;
  const float4* b1r = (const float4*)b1;
  float acc = 0.f;
#pragma unroll
  for (int rep = 0; rep < 4; ++rep) {
    const int c = rep * 64 + lane;
    float4 w = wr[c];
    float4 a = w1r[c];
    float4 bb = b1r[c];
    acc += w.x * silu_f(s * a.x + bb.x) + w.y * silu_f(s * a.y + bb.y) +
           w.z * silu_f(s * a.z + bb.z) + w.w * silu_f(s * a.w + bb.w);
  }
  acc = waveAllSum(acc);
  if (lane == 0) {
    float v = ce[(size_t)y[b] * 1024 + j] + acc + b2[j];
    sc[(size_t)b * 1024 + j] = silu_f(v);
  }
}

// ada modulations v2: 1536 blocks x 256 thr; wave = 4 rows; sc slice held in
// registers (loaded once per wave); 8 batch dots per row, shfl reduce.
__global__ __launch_bounds__(256, 2) void modlin_ada_kernel(
    const float* __restrict__ adaw, const float* __restrict__ adab,
    const float* __restrict__ sc, float* __restrict__ mods)
{
  const int tid = threadIdx.x;
  const int lane = tid & 63;
  const int wave = tid >> 6;
  const int j0 = blockIdx.x * 16 + wave * 4;
  float4 sreg[4][8];
#pragma unroll
  for (int rep = 0; rep < 4; ++rep)
#pragma unroll
    for (int b = 0; b < 8; ++b)
      sreg[rep][b] = *(const float4*)(sc + (size_t)b * 1024 + rep * 256 + lane * 4);
  const int d = j0 / 6144;           // block never spans layers (6144 % 16 == 0)
  float* outb = mods + (size_t)d * 49152;
#pragma unroll
  for (int r = 0; r < 4; ++r) {
    const int j = j0 + r;
    const float4* wr = (const float4*)(adaw + (size_t)j * 1024);
    float acc[8];
#pragma unroll
    for (int b = 0; b < 8; ++b) acc[b] = 0.f;
#pragma unroll
    for (int rep = 0; rep < 4; ++rep) {
      float4 wv = wr[rep * 64 + lane];
#pragma unroll
      for (int b = 0; b < 8; ++b) {
        float4 s4 = sreg[rep][b];
        acc[b] += wv.x * s4.x + wv.y * s4.y + wv.z * s4.z + wv.w * s4.w;
      }
    }
#pragma unroll
    for (int b = 0; b < 8; ++b) acc[b] = waveAllSum(acc[b]);
    if (lane == 0) {
      const int jj = j - d * 6144;
      const float bb = adab[j];
#pragma unroll
      for (int b = 0; b < 8; ++b) outb[(size_t)b * 6144 + jj] = acc[b] + bb;
    }
  }
}

__global__ __launch_bounds__(64) void modlin_kernel(
    const float* __restrict__ w, const float* __restrict__ bias,
    const float* __restrict__ sc, float* __restrict__ out, int ostride)
{
  const int j = blockIdx.x, lane = threadIdx.x;
  const float4* wr = (const float4*)(w + (size_t)j * 1024);
  float acc[8];
#pragma unroll
  for (int b = 0; b < 8; ++b) acc[b] = 0.f;
#pragma unroll
  for (int rep = 0; rep < 4; ++rep) {
    float4 wv = wr[rep * 64 + lane];
#pragma unroll
    for (int b = 0; b < 8; ++b) {
      float4 s = ((const float4*)(sc + (size_t)b * 1024))[rep * 64 + lane];
      acc[b] += wv.x * s.x + wv.y * s.y + wv.z * s.z + wv.w * s.w;
    }
  }
#pragma unroll
  for (int b = 0; b < 8; ++b) acc[b] = waveAllSum(acc[b]);
  if (lane == 0) {
    const float bb = bias[j];
#pragma unroll
    for (int b = 0; b < 8; ++b) out[(size_t)b * ostride + j] = acc[b] + bb;
  }
}

// ---------------------------------------------------------------------------
// Patch embed
// ---------------------------------------------------------------------------
__global__ __launch_bounds__(256) void patch_kernel(
    const float* __restrict__ x, const float* __restrict__ pw,
    const float* __restrict__ pb, const float* __restrict__ pos,
    float* __restrict__ xc)
{
  const int n = blockIdx.x, b = blockIdx.y, tid = threadIdx.x;
  __shared__ float pv[16];
  if (tid < 16) {
    const int ci = tid >> 2, pi = (tid >> 1) & 1, pj = tid & 1;
    const int i = n >> 4, j = n & 15;
    pv[tid] = x[((size_t)(b * 4 + ci) * 32 + i * 2 + pi) * 32 + j * 2 + pj];
  }
  __syncthreads();
#pragma unroll
  for (int qq = 0; qq < 4; ++qq) {
    const int c = qq * 256 + tid;
    const float4* wr = (const float4*)(pw + (size_t)c * 16);
    float acc = pb[c] + pos[(size_t)n * 1024 + c];
#pragma unroll
    for (int g = 0; g < 4; ++g) {
      float4 w = wr[g];
      acc += w.x * pv[g * 4] + w.y * pv[g * 4 + 1] + w.z * pv[g * 4 + 2] + w.w * pv[g * 4 + 3];
    }
    xc[((size_t)b * 256 + n) * 1024 + c] = acc;
  }
}

// ---------------------------------------------------------------------------
// RMSNorm + adaLN modulate -> fp8
// ---------------------------------------------------------------------------
__global__ __launch_bounds__(256) void normmod8_kernel(
    const float* __restrict__ xc, const float* __restrict__ w,
    const float* __restrict__ mods, int mult_off, int shift_off,
    u8* __restrict__ out)
{
  const int m = blockIdx.x, b = m >> 8, tid = threadIdx.x;
  const float* row = xc + (size_t)m * 1024;
  float4 v = *(const float4*)(row + tid * 4);
  float ss = v.x * v.x + v.y * v.y + v.z * v.z + v.w * v.w;
  ss = waveAllSum(ss);
  __shared__ float red[4];
  if ((tid & 63) == 0) red[tid >> 6] = ss;
  __syncthreads();
  const float tot = red[0] + red[1] + red[2] + red[3];
  const float r = rsqrtf(tot * (1.f / 1024.f) + 1e-6f);
  const float* mb = mods + (size_t)b * 6144;
  const int c = tid * 4;
  float4 wv = *(const float4*)(w + c);
  float4 mu = *(const float4*)(mb + mult_off + c);
  float4 sh = *(const float4*)(mb + shift_off + c);
  u32 p = pk4f8(v.x * r * wv.x * (1.f + mu.x) + sh.x,
                v.y * r * wv.y * (1.f + mu.y) + sh.y,
                v.z * r * wv.z * (1.f + mu.z) + sh.z,
                v.w * r * wv.w * (1.f + mu.w) + sh.w);
  *(u32*)(out + (size_t)m * 1024 + c) = p;
}

// ---------------------------------------------------------------------------
// MFMA attention (bf16 q/k/v in, fp8 out at o[b,n,h,d])
// ---------------------------------------------------------------------------
__global__ __launch_bounds__(256) void attn_kernel(
    const u16* __restrict__ qb, const u16* __restrict__ kb,
    const u16* __restrict__ vb, u8* __restrict__ o)
{
  __shared__ alignas(16) u16 Kt[128][72];
  __shared__ alignas(16) u16 Vtt[64][136];
  __shared__ alignas(16) u16 Pw[4][16][136];
  const int bh = blockIdx.x;
  const int qbase = blockIdx.y * 64;
  const int tid = threadIdx.x;
  const int lane = tid & 63;
  const int wave = tid >> 6;
  const int rl = lane & 15;
  const int kq = (lane >> 4) * 8;
  const int rowg = (lane >> 4) * 4;

  const int q0 = qbase + wave * 16;
  const u16* qsrc = qb + ((size_t)bh * 256 + q0 + rl) * 64 + kq;
  const bf16x8 a0 = *(const bf16x8*)(qsrc);
  const bf16x8 a1 = *(const bf16x8*)(qsrc + 32);

  float m[4], l[4];
  f32x4 oacc[4];
#pragma unroll
  for (int r = 0; r < 4; ++r) { m[r] = -1e30f; l[r] = 0.f; }
#pragma unroll
  for (int dt = 0; dt < 4; ++dt) oacc[dt] = (f32x4){0.f, 0.f, 0.f, 0.f};

  for (int kt = 0; kt < 2; ++kt) {
    __syncthreads();
#pragma unroll
    for (int c = 0; c < 4; ++c) {
      const int flat = c * 256 + tid;
      const int row = flat >> 3;
      const int col = (flat & 7) * 8;
      uint4 v = *(const uint4*)(kb + ((size_t)bh * 256 + kt * 128 + row) * 64 + col);
      *(uint4*)&Kt[row][col] = v;
    }
    {
      const int tt = tid & 63;
      const int dh = tid >> 6;
      const int r0 = tt * 2;
      const u16* s0 = vb + ((size_t)bh * 256 + kt * 128 + r0) * 64 + dh * 16;
      const u16* s1 = s0 + 64;
#pragma unroll
      for (int g = 0; g < 2; ++g) {
        uint4 A = *(const uint4*)(s0 + g * 8);
        uint4 B = *(const uint4*)(s1 + g * 8);
        const u32 aw[4] = {A.x, A.y, A.z, A.w};
        const u32 bw[4] = {B.x, B.y, B.z, B.w};
#pragma unroll
        for (int q = 0; q < 4; ++q) {
          const int d2 = dh * 16 + g * 8 + q * 2;
          const u32 lo = (aw[q] & 0xffffu) | (bw[q] << 16);
          const u32 hi = (aw[q] >> 16) | (bw[q] & 0xffff0000u);
          *(u32*)&Vtt[d2][r0] = lo;
          *(u32*)&Vtt[d2 + 1][r0] = hi;
        }
      }
    }
    __syncthreads();

    f32x4 sacc[8];
#pragma unroll
    for (int t = 0; t < 8; ++t) sacc[t] = (f32x4){0.f, 0.f, 0.f, 0.f};
#pragma unroll
    for (int t = 0; t < 8; ++t) {
      bf16x8 k0 = *(const bf16x8*)&Kt[t * 16 + rl][kq];
      bf16x8 k1 = *(const bf16x8*)&Kt[t * 16 + rl][32 + kq];
      sacc[t] = __builtin_amdgcn_mfma_f32_16x16x32_bf16(a0, k0, sacc[t], 0, 0, 0);
      sacc[t] = __builtin_amdgcn_mfma_f32_16x16x32_bf16(a1, k1, sacc[t], 0, 0, 0);
    }
    float cmax[4];
#pragma unroll
    for (int r = 0; r < 4; ++r) cmax[r] = sacc[0][r];
#pragma unroll
    for (int t = 1; t < 8; ++t)
#pragma unroll
      for (int r = 0; r < 4; ++r) cmax[r] = fmaxf(cmax[r], sacc[t][r]);
#pragma unroll
    for (int off = 1; off < 16; off <<= 1)
#pragma unroll
      for (int r = 0; r < 4; ++r) cmax[r] = fmaxf(cmax[r], __shfl_xor(cmax[r], off, 64));
#pragma unroll
    for (int r = 0; r < 4; ++r) {
      const float mn = fmaxf(m[r], cmax[r]);
      const float corr = __expf((m[r] - mn) * 0.125f);
      l[r] *= corr;
#pragma unroll
      for (int dt = 0; dt < 4; ++dt) oacc[dt][r] *= corr;
      m[r] = mn;
    }
    float lsum[4] = {0.f, 0.f, 0.f, 0.f};
#pragma unroll
    for (int t = 0; t < 8; ++t)
#pragma unroll
      for (int r = 0; r < 4; ++r) {
        const float p = __expf((sacc[t][r] - m[r]) * 0.125f);
        lsum[r] += p;
        Pw[wave][rowg + r][t * 16 + rl] = f2bf(p);
      }
#pragma unroll
    for (int off = 1; off < 16; off <<= 1)
#pragma unroll
      for (int r = 0; r < 4; ++r) lsum[r] += __shfl_xor(lsum[r], off, 64);
#pragma unroll
    for (int r = 0; r < 4; ++r) l[r] += lsum[r];
#pragma unroll
    for (int ks = 0; ks < 4; ++ks) {
      bf16x8 pa = *(const bf16x8*)&Pw[wave][rl][ks * 32 + kq];
#pragma unroll
      for (int dt = 0; dt < 4; ++dt) {
        bf16x8 vf = *(const bf16x8*)&Vtt[dt * 16 + rl][ks * 32 + kq];
        oacc[dt] = __builtin_amdgcn_mfma_f32_16x16x32_bf16(pa, vf, oacc[dt], 0, 0, 0);
      }
    }
  }
  const int b = bh >> 4, h = bh & 15;
#pragma unroll
  for (int r = 0; r < 4; ++r) {
    const float inv = 1.f / l[r];
    const int qrow = q0 + rowg + r;
    u8* dst = o + (((size_t)b * 256 + qrow) * 16 + h) * 64 + rl;
#pragma unroll
    for (int dt = 0; dt < 4; ++dt)
      dst[dt * 16] = (u8)f2f8(oacc[dt][r] * inv);
  }
}

// ---------------------------------------------------------------------------
// Final LayerNorm + modulate -> bf16
// ---------------------------------------------------------------------------
__global__ __launch_bounds__(256) void lnmod_kernel(
    const float* __restrict__ xc, const float* __restrict__ fmods,
    u16* __restrict__ out)
{
  const int m = blockIdx.x, b = m >> 8, tid = threadIdx.x;
  const float* row = xc + (size_t)m * 1024;
  float4 v = *(const float4*)(row + tid * 4);
  float s1 = v.x + v.y + v.z + v.w;
  float s2 = v.x * v.x + v.y * v.y + v.z * v.z + v.w * v.w;
  s1 = waveAllSum(s1);
  s2 = waveAllSum(s2);
  __shared__ float r1[4], r2[4];
  if ((tid & 63) == 0) { r1[tid >> 6] = s1; r2[tid >> 6] = s2; }
  __syncthreads();
  const float t1 = r1[0] + r1[1] + r1[2] + r1[3];
  const float t2 = r2[0] + r2[1] + r2[2] + r2[3];
  const float mean = t1 * (1.f / 1024.f);
  const float var = t2 * (1.f / 1024.f) - mean * mean;
  const float rr = rsqrtf(var + 1e-5f);
  const float* mb = fmods + (size_t)b * 2048;
  const int c = tid * 4;
  float4 sh = *(const float4*)(mb + c);
  float4 sl = *(const float4*)(mb + 1024 + c);
  union { u16 u[4]; uint2 v2; } pk;
  pk.u[0] = f2bf((v.x - mean) * rr * (1.f + sl.x) + sh.x);
  pk.u[1] = f2bf((v.y - mean) * rr * (1.f + sl.y) + sh.y);
  pk.u[2] = f2bf((v.z - mean) * rr * (1.f + sl.z) + sh.z);
  pk.u[3] = f2bf((v.w - mean) * rr * (1.f + sl.w) + sh.w);
  *(uint2*)(out + (size_t)m * 1024 + c) = pk.v2;
}

// ---------------------------------------------------------------------------
// Final linear (16 outputs) + unpatchify
// ---------------------------------------------------------------------------
__global__ __launch_bounds__(256) void final_kernel(
    const u16* __restrict__ xfin, const float* __restrict__ w,
    const float* __restrict__ bias, float* __restrict__ out)
{
  const int tid = threadIdx.x;
  const int m = blockIdx.x * 16 + (tid >> 4);
  const int j = tid & 15;
  const u16* xr = xfin + (size_t)m * 1024;
  const float* wr = w + (size_t)j * 1024;
  float acc = 0.f;
  for (int k = 0; k < 1024; k += 8) {
    uint4 xv = *(const uint4*)(xr + k);
    const u16* xu = (const u16*)&xv;
    float4 w0 = *(const float4*)(wr + k);
    float4 w1 = *(const float4*)(wr + k + 4);
    acc += bf2f(xu[0]) * w0.x + bf2f(xu[1]) * w0.y + bf2f(xu[2]) * w0.z + bf2f(xu[3]) * w0.w;
    acc += bf2f(xu[4]) * w1.x + bf2f(xu[5]) * w1.y + bf2f(xu[6]) * w1.z + bf2f(xu[7]) * w1.w;
  }
  acc += bias[j];
  const int b = m >> 8, n = m & 255;
  const int i = n >> 4, jj = n & 15;
  const int pi = (j >> 3) & 1, pj = (j >> 2) & 1, oc = j & 3;
  out[((size_t)(b * 4 + oc) * 32 + i * 2 + pi) * 32 + jj * 2 + pj] = acc;
}

// ---------------------------------------------------------------------------
extern "C" void kernel_launch(void* const* d_in, const int* in_sizes, int n_in,
                              void* d_out, int out_size, void* d_ws, size_t ws_size,
                              hipStream_t stream) {
  const float* x       = (const float*)d_in[0];
  const int*   y       = (const int*)  d_in[1];
  const float* cfg_s   = (const float*)d_in[2];
  const float* patch_w = (const float*)d_in[3];
  const float* patch_b = (const float*)d_in[4];
  const float* pos_e   = (const float*)d_in[5];
  const float* class_e = (const float*)d_in[6];
  const float* cfg_w1  = (const float*)d_in[7];
  const float* cfg_b1  = (const float*)d_in[8];
  const float* cfg_w2  = (const float*)d_in[9];
  const float* cfg_b2  = (const float*)d_in[10];
  const float* n1w     = (const float*)d_in[11];
  const float* n2w     = (const float*)d_in[12];
  const float* qkvw    = (const float*)d_in[13];
  const float* projw   = (const float*)d_in[14];
  const float* projb   = (const float*)d_in[15];
  const float* qnw     = (const float*)d_in[16];
  const float* knw     = (const float*)d_in[17];
  const float* w1      = (const float*)d_in[18];
  const float* w2      = (const float*)d_in[19];
  const float* w3      = (const float*)d_in[20];
  const float* adaw    = (const float*)d_in[21];
  const float* adab    = (const float*)d_in[22];
  const float* finaw   = (const float*)d_in[23];
  const float* finab   = (const float*)d_in[24];
  const float* flw     = (const float*)d_in[25];
  const float* flb     = (const float*)d_in[26];
  (void)in_sizes; (void)n_in; (void)out_size;

  char* ws = (char*)d_ws;
  const size_t MB = 1024 * 1024;
  if (ws_size < 96 * MB) return;
  float* sc    = (float*)(ws + 32 * 1024);             // 32KB
  float* mods  = (float*)(ws + 64 * 1024);             // 768KB
  float* fmods = (float*)(ws + 64 * 1024 + 786432);    // 64KB
  float* xc    = (float*)(ws + 1 * MB);                // 8MB
  u8*    xm8   = (u8*)   (ws + 9 * MB);                // 2MB
  u16*   qbuf  = (u16*)  (ws + 11 * MB);               // 4MB
  u16*   kbuf  = (u16*)  (ws + 15 * MB);               // 4MB
  u16*   vbuf  = (u16*)  (ws + 19 * MB);               // 4MB
  u8*    h18   = (u8*)   (ws + 23 * MB);               // 5.7MB
  u16*   lnbuf = (u16*)  (ws + 29 * MB);               // 4MB
  u8*    WB    = (u8*)   (ws + 33 * MB);               // 48.5MB fp8 weights
  const size_t LSTR = 12713984;

  cond_kernel<<<dim3(1024, 8), 64, 0, stream>>>(cfg_s, cfg_w1, cfg_b1, cfg_w2,
                                                cfg_b2, class_e, y, sc);
  modlin_ada_kernel<<<1536, 256, 0, stream>>>(adaw, adab, sc, mods);
  modlin_kernel<<<2048, 64, 0, stream>>>(finaw, finab, sc, fmods, 2048);
  patch_kernel<<<dim3(256, 8), 256, 0, stream>>>(x, patch_w, patch_b, pos_e, xc);
  conv_qp8_kernel<<<8192, 256, 0, stream>>>(qkvw, projw, WB);
  conv_w138_kernel<<<5504, 256, 0, stream>>>(w1, w3, WB);
  conv_w28_kernel<<<4096, 256, 0, stream>>>(w2, WB);
  zt_kernel<<<128, 256, 0, stream>>>(h18);

  for (int d = 0; d < 4; ++d) {
    const float* md = mods + (size_t)d * 49152;
    u8* WL = WB + (size_t)d * LSTR;
    normmod8_kernel<<<2048, 256, 0, stream>>>(xc, n1w + d * 1024, md, 1024, 0, xm8);
    gemm8_t<64, 128, 2><<<768, 256, 0, stream>>>(xm8, 1024, WL, 1024, 8, 32,
                                                 nullptr, nullptr, nullptr,
                                                 qbuf, kbuf, vbuf, nullptr,
                                                 qnw + d * 64, knw + d * 64);
    attn_kernel<<<dim3(128, 4), 256, 0, stream>>>(qbuf, kbuf, vbuf, xm8);
    gemm8_t<64, 64, 1><<<512, 256, 0, stream>>>(xm8, 1024, WL + 3145728, 1024, 8, 32,
                                                xc, md + 2048, projb + d * 1024,
                                                nullptr, nullptr, nullptr, nullptr,
                                                nullptr, nullptr);
    normmod8_kernel<<<2048, 256, 0, stream>>>(xc, n2w + d * 1024, md, 4096, 3072, xm8);
    gemm8_t<64, 128, 3><<<1376, 256, 0, stream>>>(xm8, 1024, WL + 4194304, 1024, 8, 32,
                                                  nullptr, nullptr, nullptr,
                                                  nullptr, nullptr, nullptr, h18,
                                                  nullptr, nullptr);
    gemm8_t<64, 64, 1><<<512, 256, 0, stream>>>(h18, 2816, WL + 9830400, 2816, 22, 32,
                                                xc, md + 5120, nullptr,
                                                nullptr, nullptr, nullptr, nullptr,
                                                nullptr, nullptr);
  }

  lnmod_kernel<<<2048, 256, 0, stream>>>(xc, fmods, lnbuf);
  final_kernel<<<128, 256, 0, stream>>>(lnbuf, flw, flb, (float*)d_out);
}